// Round 10
// baseline (474.202 us; speedup 1.0000x reference)
//
#include <hip/hip_runtime.h>

namespace {
constexpr int SD = 1024;           // D
constexpr int TD = 2048;           // 2D
constexpr int BATCH = 8;
constexpr int RH = 4;
constexpr float EPSc = 1e-5f;
constexpr float DXf = 2.0f / 31.0f;
constexpr float DXDYf = DXf * DXf;
constexpr float SCALEf = 0.125f;
constexpr float CFINAL = DXDYf * DXDYf * SCALEf;

// workspace offsets (floats)
constexpr size_t OFF_V   = 0;
constexpr size_t OFF_MID = OFF_V   + (size_t)BATCH * TD * 64;   // 1048576
constexpr size_t OFF_W   = OFF_MID + (size_t)BATCH * TD * 64;
constexpr size_t OFF_WF  = OFF_W   + (size_t)SD * SD;
constexpr size_t OFF_U1K = OFF_WF  + (size_t)SD * SD;
constexpr size_t OFF_U2K = OFF_U1K + SD * 32;
constexpr size_t OFF_U1F = OFF_U2K + SD * 32;
constexpr size_t OFF_U2F = OFF_U1F + SD * 32;
constexpr size_t OFF_GP  = OFF_U2F + SD * 32;                    // 8*32*4096
constexpr size_t OFF_SP  = OFF_GP  + (size_t)BATCH * 32 * 4096;  // 8*32*64
constexpr size_t OFF_A   = OFF_SP  + BATCH * 32 * 64;            // A matrix (8x4096)
constexpr size_t OFF_RV  = OFF_A   + BATCH * 4096;               // RV (8x64)
constexpr size_t OFF_LNP = OFF_RV  + BATCH * 64;                 // LNP; later STAT
constexpr size_t OFF_ZU  = OFF_LNP + BATCH * 32 * 2;             // Ep region; later P3
constexpr size_t OFF_ZF  = OFF_ZU  + (size_t)SD * 512;
constexpr size_t OFF_W1  = OFF_ZF  + (size_t)SD * 512;
constexpr size_t OFF_CS  = OFF_W1  + SD;
constexpr size_t WS_FLOATS = OFF_CS + 16 * SD;
// overlays:
//  Wbf->OFF_W lo, WTW->OFF_W+524288; Wfbf->OFF_WF lo, WTF->OFF_WF+524288
//  ZT->MID lo; P0->GP, P1->GP+524288, P2->MID+524288, P3->ZU
//  Ep/fp/gp/cp -> OFF_ZU (dead before P3 written); STAT->OFF_LNP
} // namespace

typedef __bf16 bf16x8 __attribute__((ext_vector_type(8)));
typedef float f32x4 __attribute__((ext_vector_type(4)));

__device__ __forceinline__ float leaky(float x) { return fmaxf(x, 0.01f * x); }
__device__ __forceinline__ float gxv(int i) { return -1.0f + (2.0f / 31.0f) * (float)i; }
__device__ __forceinline__ ushort f2bf(float x) { union { __bf16 b; ushort u; } v; v.b = (__bf16)x; return v.u; }
__device__ __forceinline__ float bf2f(ushort u) { return __uint_as_float(((uint)u) << 16); }

// ---- merged: blocks 0-3 = u-table precompute; blocks 4-15 = head-collapse precompute ----
__global__ __launch_bounds__(256) void k_prep(
    const float* __restrict__ kW1, const float* __restrict__ kb1,
    const float* __restrict__ fW1, const float* __restrict__ fb1,
    float* __restrict__ u1k, float* __restrict__ u2k,
    float* __restrict__ u1f, float* __restrict__ u2f,
    const float* __restrict__ Wq, const float* __restrict__ bq,
    const float* __restrict__ Wk, const float* __restrict__ bk,
    float* __restrict__ Ep, float* __restrict__ fp,
    float* __restrict__ gp, float* __restrict__ cp) {
  __shared__ __align__(16) float Wqs[4096];
  __shared__ float Wks[64 * 65];
  __shared__ float bqs[64], bks[64];
  int blk = blockIdx.x, t = threadIdx.x;
  if (blk < 4) {
    int n = blk * 256 + t;
    float ga = gxv(n >> 5), gb = gxv(n & 31);
    for (int j = 0; j < 32; j++) {
      u1k[n * 32 + j] = ga * kW1[j] + gb * kW1[32 + j] + kb1[j];
      u2k[n * 32 + j] = gb * kW1[64 + j] + ga * kW1[96 + j];
      u1f[n * 32 + j] = ga * fW1[j] + gb * fW1[32 + j] + fb1[j];
      u2f[n * 32 + j] = gb * fW1[64 + j] + ga * fW1[96 + j];
    }
    return;
  }
  int h = blk - 4;  // 0..11
  const float* wqb = Wq + (size_t)h * 4096;
  const float* wkb = Wk + (size_t)h * 4096;
  for (int idx = t; idx < 4096; idx += 256) {
    Wqs[idx] = wqb[idx];
    Wks[(idx >> 6) * 65 + (idx & 63)] = wkb[idx];
  }
  if (t < 64) { bqs[t] = bq[h * 64 + t]; bks[t] = bk[h * 64 + t]; }
  __syncthreads();
  int cpp = t & 63, cb = (t >> 6) * 16;
  float acc[16];
#pragma unroll
  for (int u = 0; u < 16; u++) acc[u] = 0.f;
  for (int k = 0; k < 64; k++) {
    float wkv = Wks[cpp * 65 + k];
#pragma unroll
    for (int u = 0; u < 16; u++) acc[u] += Wqs[(cb + u) * 64 + k] * wkv;
  }
  float* eo = Ep + (size_t)h * 4096;
#pragma unroll
  for (int u = 0; u < 16; u++) eo[(cb + u) * 64 + cpp] = acc[u];
  if (t < 64) {
    float f = 0.f, gg = 0.f;
    for (int k = 0; k < 64; k++) {
      f  += Wqs[t * 64 + k] * bks[k];
      gg += Wks[t * 65 + k] * bqs[k];
    }
    fp[h * 64 + t] = f;
    gp[h * 64 + t] = gg;
    float ca = bqs[t] * bks[t];
    ca += __shfl_xor(ca, 1, 64);
    ca += __shfl_xor(ca, 2, 64);
    ca += __shfl_xor(ca, 4, 64);
    ca += __shfl_xor(ca, 8, 64);
    ca += __shfl_xor(ca, 16, 64);
    ca += __shfl_xor(ca, 32, 64);
    if (t == 0) cp[h] = ca;
  }
}

// ---- MFMA edge-MLP: 2 n-rows x 512 m per block (u2 loads amortized over 2 n) ----
__global__ __launch_bounds__(256) void k_mlp2(
    const float* __restrict__ u1k, const float* __restrict__ u2k,
    const float* __restrict__ kW2, const float* __restrict__ kb2,
    const float* __restrict__ kW3, const float* __restrict__ kb3,
    const float* __restrict__ u1f, const float* __restrict__ u2f,
    const float* __restrict__ fW2, const float* __restrict__ fb2,
    const float* __restrict__ fW3, const float* __restrict__ fb3,
    ushort* __restrict__ outK, ushort* __restrict__ outF) {
  const int which = blockIdx.y;
  const float* u1 = which ? u1f : u1k;
  const float* u2 = which ? u2f : u2k;
  const float* W2 = which ? fW2 : kW2;
  const float* b2 = which ? fb2 : kb2;
  const float* W3 = which ? fW3 : kW3;
  const float* b3 = which ? fb3 : kb3;
  ushort* out = which ? outF : outK;

  const int t = threadIdx.x;
  const int lane = t & 63, wave = t >> 6;
  const int row = lane & 15, grp = lane >> 4;
  const int n0 = (blockIdx.x >> 1) * 2;
  const int mh = blockIdx.x & 1;

  bf16x8 wfrag[4];
  float4 b2q[4], w3q[4];
#pragma unroll
  for (int tt = 0; tt < 4; tt++) {
#pragma unroll
    for (int i = 0; i < 8; i++) wfrag[tt][i] = (__bf16)W2[(grp * 8 + i) * 64 + tt * 16 + row];
    b2q[tt] = *reinterpret_cast<const float4*>(b2 + tt * 16 + grp * 4);
    w3q[tt] = *reinterpret_cast<const float4*>(W3 + tt * 16 + grp * 4);
  }
  float u1j[2][8];
#pragma unroll
  for (int nn = 0; nn < 2; nn++)
#pragma unroll
    for (int i = 0; i < 8; i++) u1j[nn][i] = u1[(n0 + nn) * 32 + grp * 8 + i];
  const float b3v = b3[0];

#pragma unroll
  for (int chunk = 0; chunk < 2; chunk++) {
#pragma unroll
    for (int st = 0; st < 4; st++) {
      int mbase = mh * 512 + chunk * 256 + wave * 64 + st * 16;
      int m = mbase + row;
      const float4* u2p = reinterpret_cast<const float4*>(u2 + (size_t)m * 32 + grp * 8);
      float4 ua = u2p[0], ub = u2p[1];
      float hv[8] = {ua.x, ua.y, ua.z, ua.w, ub.x, ub.y, ub.z, ub.w};
#pragma unroll
      for (int nn = 0; nn < 2; nn++) {
        bf16x8 pfrag;
#pragma unroll
        for (int i = 0; i < 8; i++) pfrag[i] = (__bf16)leaky(u1j[nn][i] + hv[i]);
        float accv = 0.f;
#pragma unroll
        for (int tt = 0; tt < 4; tt++) {
          f32x4 ci = {b2q[tt].x, b2q[tt].y, b2q[tt].z, b2q[tt].w};
          f32x4 c = __builtin_amdgcn_mfma_f32_16x16x32_bf16(wfrag[tt], pfrag, ci, 0, 0, 0);
          accv += leaky(c[0]) * w3q[tt].x;
          accv += leaky(c[1]) * w3q[tt].y;
          accv += leaky(c[2]) * w3q[tt].z;
          accv += leaky(c[3]) * w3q[tt].w;
        }
        accv += __shfl_xor(accv, 16, 64);
        accv += __shfl_xor(accv, 32, 64);
        if (grp == 0) out[(size_t)(n0 + nn) * SD + mbase + row] = f2bf(accv + b3v);
      }
    }
  }
}

// ---- bf16 transpose ----
__global__ __launch_bounds__(256) void k_cvtTb(const ushort* __restrict__ srcA, const ushort* __restrict__ srcB,
                                               ushort* __restrict__ dstA, ushort* __restrict__ dstB) {
  __shared__ float T[64][65];
  const ushort* src = blockIdx.z ? srcB : srcA;
  ushort* dst = blockIdx.z ? dstB : dstA;
  int t = threadIdx.x;
  int c0 = blockIdx.x * 64, r0 = blockIdx.y * 64;
  int rr = t >> 2, cc = (t & 3) * 16;
  const uint4* s4 = reinterpret_cast<const uint4*>(src + (size_t)(r0 + rr) * 1024 + c0 + cc);
  uint4 q0 = s4[0], q1 = s4[1];
  uint qs[8] = {q0.x, q0.y, q0.z, q0.w, q1.x, q1.y, q1.z, q1.w};
#pragma unroll
  for (int j = 0; j < 8; j++) {
    T[rr][cc + 2 * j]     = bf2f((ushort)(qs[j] & 0xffffu));
    T[rr][cc + 2 * j + 1] = bf2f((ushort)(qs[j] >> 16));
  }
  __syncthreads();
  uint pk[8];
#pragma unroll
  for (int j = 0; j < 8; j++) {
    uint lo = (uint)f2bf(T[cc + 2 * j][rr]);
    uint hi = (uint)f2bf(T[cc + 2 * j + 1][rr]);
    pk[j] = lo | (hi << 16);
  }
  ushort* dp = dst + (size_t)(c0 + rr) * 1024 + r0 + cc;
  uint4* dp4 = reinterpret_cast<uint4*>(dp);
  dp4[0] = make_uint4(pk[0], pk[1], pk[2], pk[3]);
  dp4[1] = make_uint4(pk[4], pk[5], pk[6], pk[7]);
}

// ---- w1[n] = rowsum(WTW[n]) + rowsum(WTF[n]) ----
__global__ __launch_bounds__(256) void k_colsumT(const ushort* __restrict__ WTW, const ushort* __restrict__ WTF,
                                                 float* __restrict__ w1) {
  int t = threadIdx.x;
  int n = blockIdx.x * 16 + (t >> 4), seg = t & 15;
  const uint4* pa = reinterpret_cast<const uint4*>(WTW + (size_t)n * 1024 + seg * 64);
  const uint4* pf = reinterpret_cast<const uint4*>(WTF + (size_t)n * 1024 + seg * 64);
  float s = 0.f;
#pragma unroll
  for (int q = 0; q < 8; q++) {
    uint4 va = pa[q], vf = pf[q];
    uint u[8] = {va.x, va.y, va.z, va.w, vf.x, vf.y, vf.z, vf.w};
#pragma unroll
    for (int j = 0; j < 8; j++) s += bf2f((ushort)(u[j] & 0xffffu)) + bf2f((ushort)(u[j] >> 16));
  }
  s += __shfl_xor(s, 1, 64);
  s += __shfl_xor(s, 2, 64);
  s += __shfl_xor(s, 4, 64);
  s += __shfl_xor(s, 8, 64);
  if (seg == 0) w1[n] = s;
}

// ---- LN partial sums over xy ----
__global__ __launch_bounds__(256) void k_redsum(const float* __restrict__ X, float* __restrict__ part) {
  int b = blockIdx.y, c = blockIdx.x, t = threadIdx.x;
  const float4* X4 = reinterpret_cast<const float4*>(X + (size_t)b * 131072 + (size_t)c * 4096);
  float s = 0.f, q = 0.f;
#pragma unroll
  for (int k = 0; k < 4; k++) {
    float4 v = X4[t + k * 256];
    s += v.x + v.y + v.z + v.w;
    q += v.x * v.x + v.y * v.y + v.z * v.z + v.w * v.w;
  }
  for (int off = 32; off; off >>= 1) { s += __shfl_down(s, off); q += __shfl_down(q, off); }
  __shared__ float ss[4], qq[4];
  int lane = t & 63, wid = t >> 6;
  if (lane == 0) { ss[wid] = s; qq[wid] = q; }
  __syncthreads();
  if (t == 0) {
    part[(size_t)(b * 32 + c) * 2] = ss[0] + ss[1] + ss[2] + ss[3];
    part[(size_t)(b * 32 + c) * 2 + 1] = qq[0] + qq[1] + qq[2] + qq[3];
  }
}

// ---- initial LN-apply (stats from LNP) + XtY 4x4-tile partials ----
__global__ __launch_bounds__(256) void k_apply0(
    const float* __restrict__ src, const float* __restrict__ g,
    const float* __restrict__ bb, const float* __restrict__ lnp,
    float* __restrict__ Vout, float* __restrict__ Gp, float* __restrict__ sp) {
  int c = blockIdx.x, b = blockIdx.y, t = threadIdx.x;
  __shared__ float sm[2];
  __shared__ __align__(16) float Vs[4096];
  if (t == 0) {
    float s = 0.f, q = 0.f;
    for (int cc = 0; cc < 32; cc++) {
      s += lnp[(size_t)(b * 32 + cc) * 2];
      q += lnp[(size_t)(b * 32 + cc) * 2 + 1];
    }
    float mean = s / 131072.0f;
    sm[0] = mean;
    sm[1] = rsqrtf(q / 131072.0f - mean * mean + EPSc);
  }
  __syncthreads();
  float mean = sm[0], is = sm[1];
  size_t base4 = (size_t)b * 32768 + (size_t)c * 1024;
#pragma unroll
  for (int k = 0; k < 4; k++) {
    int idx = t + k * 256;
    float4 v = reinterpret_cast<const float4*>(src)[base4 + idx];
    float4 gg = reinterpret_cast<const float4*>(g)[c * 1024 + idx];
    float4 bv = reinterpret_cast<const float4*>(bb)[c * 1024 + idx];
    float4 r;
    r.x = (v.x - mean) * is * gg.x + bv.x;
    r.y = (v.y - mean) * is * gg.y + bv.y;
    r.z = (v.z - mean) * is * gg.z + bv.z;
    r.w = (v.w - mean) * is * gg.w + bv.w;
    reinterpret_cast<float4*>(Vout)[base4 + idx] = r;
    reinterpret_cast<float4*>(Vs)[idx] = r;
  }
  __syncthreads();
  int tp = t >> 4, tq = t & 15;
  float a2[4][4] = {};
  for (int k = 0; k < 64; k++) {
    float4 xv = *reinterpret_cast<const float4*>(&Vs[k * 64 + tp * 4]);
    float4 yv = *reinterpret_cast<const float4*>(&Vs[k * 64 + tq * 4]);
    a2[0][0] += xv.x * yv.x; a2[0][1] += xv.x * yv.y; a2[0][2] += xv.x * yv.z; a2[0][3] += xv.x * yv.w;
    a2[1][0] += xv.y * yv.x; a2[1][1] += xv.y * yv.y; a2[1][2] += xv.y * yv.z; a2[1][3] += xv.y * yv.w;
    a2[2][0] += xv.z * yv.x; a2[2][1] += xv.z * yv.y; a2[2][2] += xv.z * yv.z; a2[2][3] += xv.z * yv.w;
    a2[3][0] += xv.w * yv.x; a2[3][1] += xv.w * yv.y; a2[3][2] += xv.w * yv.z; a2[3][3] += xv.w * yv.w;
  }
  float* go = Gp + (size_t)(b * 32 + c) * 4096;
#pragma unroll
  for (int i = 0; i < 4; i++) {
    float4 w = {a2[i][0], a2[i][1], a2[i][2], a2[i][3]};
    *reinterpret_cast<float4*>(&go[(tp * 4 + i) * 64 + tq * 4]) = w;
  }
  if (t < 64) {
    float s = 0.f;
    for (int k = 0; k < 64; k++) s += Vs[k * 64 + t];
    sp[(size_t)(b * 32 + c) * 64 + t] = s;
  }
}

// ---- fused gred + heads collapse + analytic mid-LN stats ----
__global__ __launch_bounds__(256) void k_headsA3(
    const float* __restrict__ Gp, const float* __restrict__ sp, int nch,
    const float* __restrict__ Ep, const float* __restrict__ fp,
    const float* __restrict__ gp, const float* __restrict__ cp,
    int j, float scale, int doStats,
    float* __restrict__ A, float* __restrict__ RVo, float* __restrict__ STAT) {
  int b = blockIdx.x, t = threadIdx.x;
  __shared__ float Es[64 * 65];
  __shared__ __align__(16) float Gs[4096];
  __shared__ __align__(16) float As[4096];
  __shared__ float ss[64], fs[64], gs[64];
  __shared__ float cj;
  __shared__ float redbuf[8];
  const float* e0 = Ep + (size_t)(j * RH) * 4096;
  for (int idx = t; idx < 4096; idx += 256) {
    float e = e0[idx] + e0[idx + 4096] + e0[idx + 8192] + e0[idx + 12288];
    Es[(idx >> 6) * 65 + (idx & 63)] = e;
    const float* gpp = Gp + (size_t)b * nch * 4096 + idx;
    float a = 0.f;
    for (int c = 0; c < nch; c++) a += gpp[(size_t)c * 4096];
    Gs[idx] = a;
  }
  if (t < 64) {
    const float* spp = sp + (size_t)b * nch * 64 + t;
    float s = 0.f;
    for (int c = 0; c < nch; c++) s += spp[c * 64];
    ss[t] = s;
    int h0 = j * RH * 64;
    fs[t] = fp[h0 + t] + fp[h0 + 64 + t] + fp[h0 + 128 + t] + fp[h0 + 192 + t];
    gs[t] = gp[h0 + t] + gp[h0 + 64 + t] + gp[h0 + 128 + t] + gp[h0 + 192 + t];
  }
  if (t == 0) cj = cp[j * RH] + cp[j * RH + 1] + cp[j * RH + 2] + cp[j * RH + 3];
  __syncthreads();
  int c = t >> 2, qb = (t & 3) * 16;
  float fv = fs[c];
  float4 acc[4];
#pragma unroll
  for (int u = 0; u < 4; u++) {
    acc[u].x = fv * ss[qb + u * 4 + 0];
    acc[u].y = fv * ss[qb + u * 4 + 1];
    acc[u].z = fv * ss[qb + u * 4 + 2];
    acc[u].w = fv * ss[qb + u * 4 + 3];
  }
  for (int d = 0; d < 64; d++) {
    float ev = Es[c * 65 + d];
    const float4* gr = reinterpret_cast<const float4*>(&Gs[d * 64 + qb]);
#pragma unroll
    for (int u = 0; u < 4; u++) {
      float4 gv = gr[u];
      acc[u].x += ev * gv.x; acc[u].y += ev * gv.y; acc[u].z += ev * gv.z; acc[u].w += ev * gv.w;
    }
  }
  float* ao = A + (size_t)b * 4096 + c * 64 + qb;
#pragma unroll
  for (int u = 0; u < 4; u++) {
    float4 v = acc[u];
    v.x *= scale; v.y *= scale; v.z *= scale; v.w *= scale;
    reinterpret_cast<float4*>(ao)[u] = v;
    *reinterpret_cast<float4*>(&As[c * 64 + qb + u * 4]) = v;
  }
  float rv_t = 0.f;
  if (t < 64) {
    float r = cj * ss[t];
    for (int d = 0; d < 64; d++) r += gs[d] * Gs[d * 64 + t];
    r *= scale;
    RVo[b * 64 + t] = r;
    rv_t = r;
  }
  if (!doStats) return;
  __syncthreads();
  float4 h[4] = {};
  for (int d = 0; d < 64; d++) {
    float gvv = Gs[c * 64 + d];
    const float4* ar = reinterpret_cast<const float4*>(&As[d * 64 + qb]);
#pragma unroll
    for (int u = 0; u < 4; u++) {
      float4 av = ar[u];
      h[u].x += gvv * av.x; h[u].y += gvv * av.y; h[u].z += gvv * av.z; h[u].w += gvv * av.w;
    }
  }
  float tp_ = 0.f;
#pragma unroll
  for (int u = 0; u < 4; u++) {
    float4 a = *reinterpret_cast<const float4*>(&As[c * 64 + qb + u * 4]);
    tp_ += a.x * h[u].x + a.y * h[u].y + a.z * h[u].z + a.w * h[u].w;
  }
  tp_ += __shfl_xor(tp_, 1, 64);  tp_ += __shfl_xor(tp_, 2, 64);
  tp_ += __shfl_xor(tp_, 4, 64);  tp_ += __shfl_xor(tp_, 8, 64);
  tp_ += __shfl_xor(tp_, 16, 64); tp_ += __shfl_xor(tp_, 32, 64);
  if ((t & 63) == 0) redbuf[t >> 6] = tp_;
  if (t < 64) {
    float t1 = 0.f;
    for (int d = 0; d < 64; d++) t1 += ss[d] * As[d * 64 + t];
    float s1 = t1, sr = rv_t, sr2 = rv_t * rv_t, srt = rv_t * t1;
#pragma unroll
    for (int off = 1; off < 64; off <<= 1) {
      s1  += __shfl_xor(s1, off, 64);
      sr  += __shfl_xor(sr, off, 64);
      sr2 += __shfl_xor(sr2, off, 64);
      srt += __shfl_xor(srt, off, 64);
    }
    if (t == 0) { redbuf[4] = s1; redbuf[5] = sr; redbuf[6] = sr2; redbuf[7] = srt; }
  }
  __syncthreads();
  if (t == 0) {
    float tr = redbuf[0] + redbuf[1] + redbuf[2] + redbuf[3];
    float smid = redbuf[4] + 2048.0f * redbuf[5];
    float mu = smid / 131072.0f;
    float e2 = (tr + 2.0f * redbuf[7] + 2048.0f * redbuf[6]) / 131072.0f;
    STAT[b * 2] = mu;
    STAT[b * 2 + 1] = rsqrtf(e2 - mu * mu + EPSc);
  }
}

// ---- fused: mid = V A + 1 r^T; LN via analytic stats; +V residual; write V'; XtY partials ----
__global__ __launch_bounds__(256) void k_midapply(
    float* __restrict__ V, const float* __restrict__ A,
    const float* __restrict__ RVv, const float* __restrict__ STAT,
    const float* __restrict__ g, const float* __restrict__ bb,
    const float* __restrict__ Yext,
    float* __restrict__ Gp, float* __restrict__ sp, int nchG) {
  int blk = blockIdx.x, b = blockIdx.y, t = threadIdx.x;
  __shared__ __align__(16) float As[4096];
  __shared__ __align__(16) float Vs[4096];
  __shared__ __align__(16) float Ys[4096];
  __shared__ float rs[64];
  __shared__ float sm[2];
  const float4* A4 = reinterpret_cast<const float4*>(A + (size_t)b * 4096);
#pragma unroll
  for (int k = 0; k < 4; k++) reinterpret_cast<float4*>(As)[t + k * 256] = A4[t + k * 256];
  if (t < 64) rs[t] = RVv[b * 64 + t];
  if (t == 0) { sm[0] = STAT[b * 2]; sm[1] = STAT[b * 2 + 1]; }
  bool doG = (blk < nchG);
  if (Yext != nullptr && doG) {
    size_t yb = (size_t)b * 32768 + (size_t)blk * 1024;
#pragma unroll
    for (int k = 0; k < 4; k++)
      reinterpret_cast<float4*>(Ys)[t + k * 256] = reinterpret_cast<const float4*>(Yext)[yb + t + k * 256];
  }
  __syncthreads();
  float mu = sm[0], is = sm[1];
  int rl = t >> 2, qb = (t & 3) * 16;
  int row = blk * 64 + rl;
  float* vr = V + (size_t)b * 131072 + (size_t)row * 64;
  float4 acc[4];
#pragma unroll
  for (int u = 0; u < 4; u++) {
    acc[u].x = rs[qb + u * 4 + 0]; acc[u].y = rs[qb + u * 4 + 1];
    acc[u].z = rs[qb + u * 4 + 2]; acc[u].w = rs[qb + u * 4 + 3];
  }
  for (int c = 0; c < 64; c++) {
    float vv = vr[c];
    const float4* ar = reinterpret_cast<const float4*>(&As[c * 64 + qb]);
#pragma unroll
    for (int u = 0; u < 4; u++) {
      float4 av = ar[u];
      acc[u].x += vv * av.x; acc[u].y += vv * av.y; acc[u].z += vv * av.z; acc[u].w += vv * av.w;
    }
  }
  const float4* g4 = reinterpret_cast<const float4*>(g + (size_t)row * 64 + qb);
  const float4* b4 = reinterpret_cast<const float4*>(bb + (size_t)row * 64 + qb);
  const float4* vq = reinterpret_cast<const float4*>(vr + qb);
  float4* vo = reinterpret_cast<float4*>(vr + qb);
#pragma unroll
  for (int u = 0; u < 4; u++) {
    float4 gg = g4[u], bv = b4[u], av = vq[u];
    float4 r;
    r.x = (acc[u].x - mu) * is * gg.x + bv.x + av.x;
    r.y = (acc[u].y - mu) * is * gg.y + bv.y + av.y;
    r.z = (acc[u].z - mu) * is * gg.z + bv.z + av.z;
    r.w = (acc[u].w - mu) * is * gg.w + bv.w + av.w;
    vo[u] = r;
    *reinterpret_cast<float4*>(&Vs[rl * 64 + qb + u * 4]) = r;
  }
  __syncthreads();
  if (!doG) return;
  const float* Yp = (Yext != nullptr) ? Ys : Vs;
  int tp = t >> 4, tq = t & 15;
  float a2[4][4] = {};
  for (int k = 0; k < 64; k++) {
    float4 xv = *reinterpret_cast<const float4*>(&Vs[k * 64 + tp * 4]);
    float4 yv = *reinterpret_cast<const float4*>(&Yp[k * 64 + tq * 4]);
    a2[0][0] += xv.x * yv.x; a2[0][1] += xv.x * yv.y; a2[0][2] += xv.x * yv.z; a2[0][3] += xv.x * yv.w;
    a2[1][0] += xv.y * yv.x; a2[1][1] += xv.y * yv.y; a2[1][2] += xv.y * yv.z; a2[1][3] += xv.y * yv.w;
    a2[2][0] += xv.z * yv.x; a2[2][1] += xv.z * yv.y; a2[2][2] += xv.z * yv.z; a2[2][3] += xv.z * yv.w;
    a2[3][0] += xv.w * yv.x; a2[3][1] += xv.w * yv.y; a2[3][2] += xv.w * yv.z; a2[3][3] += xv.w * yv.w;
  }
  float* go = Gp + (size_t)(b * nchG + blk) * 4096;
#pragma unroll
  for (int i = 0; i < 4; i++) {
    float4 w = {a2[i][0], a2[i][1], a2[i][2], a2[i][3]};
    *reinterpret_cast<float4*>(&go[(tp * 4 + i) * 64 + tq * 4]) = w;
  }
  if (t < 64) {
    float s = 0.f;
    for (int k = 0; k < 64; k++) s += Yp[k * 64 + t];
    sp[(size_t)(b * nchG + blk) * 64 + t] = s;
  }
}

// ---- k_y: ZT[b*64+q][z*1024+m] = bf16(V A); LDS-staged coalesced uint4 stores ----
__global__ __launch_bounds__(256) void k_y(const float* __restrict__ V, const float* __restrict__ A,
                                           ushort* __restrict__ ZT) {
  int blk = blockIdx.x, b = blockIdx.y, z = blockIdx.z, t = threadIdx.x;
  __shared__ __align__(16) float As[4096];
  __shared__ ushort Zs[64][36];
  const float4* A4 = reinterpret_cast<const float4*>(A + (size_t)b * 4096);
#pragma unroll
  for (int k = 0; k < 4; k++) reinterpret_cast<float4*>(As)[t + k * 256] = A4[t + k * 256];
  __syncthreads();
  int ml = t >> 3, qb = (t & 7) * 8;
  int m = blk * 32 + ml;
  const float* vr = V + (size_t)b * 131072 + (size_t)(z * 1024 + m) * 64;
  float4 acc[2] = {};
  for (int c = 0; c < 64; c++) {
    float vv = vr[c];
    const float4* ar = reinterpret_cast<const float4*>(&As[c * 64 + qb]);
#pragma unroll
    for (int u = 0; u < 2; u++) {
      float4 av = ar[u];
      acc[u].x += vv * av.x; acc[u].y += vv * av.y; acc[u].z += vv * av.z; acc[u].w += vv * av.w;
    }
  }
  Zs[qb + 0][ml] = f2bf(acc[0].x); Zs[qb + 1][ml] = f2bf(acc[0].y);
  Zs[qb + 2][ml] = f2bf(acc[0].z); Zs[qb + 3][ml] = f2bf(acc[0].w);
  Zs[qb + 4][ml] = f2bf(acc[1].x); Zs[qb + 5][ml] = f2bf(acc[1].y);
  Zs[qb + 6][ml] = f2bf(acc[1].z); Zs[qb + 7][ml] = f2bf(acc[1].w);
  __syncthreads();
  int rowq = t >> 2, seg = t & 3;
  const ushort* srcp = &Zs[rowq][seg * 8];
  uint p0 = (uint)srcp[0] | ((uint)srcp[1] << 16);
  uint p1 = (uint)srcp[2] | ((uint)srcp[3] << 16);
  uint p2 = (uint)srcp[4] | ((uint)srcp[5] << 16);
  uint p3 = (uint)srcp[6] | ((uint)srcp[7] << 16);
  ushort* dp = ZT + (size_t)(b * 64 + rowq) * 2048 + (size_t)z * 1024 + blk * 32 + seg * 8;
  *reinterpret_cast<uint4*>(dp) = make_uint4(p0, p1, p2, p3);
}

// ---- MFMA final GEMM ----
__global__ __launch_bounds__(256) void k_final_mfma(const ushort* __restrict__ WTW,
                                                    const ushort* __restrict__ WTF,
                                                    const ushort* __restrict__ ZT,
                                                    float* __restrict__ P0, float* __restrict__ P1,
                                                    float* __restrict__ P2, float* __restrict__ P3) {
  int tn = blockIdx.x, tb = blockIdx.y, kz = blockIdx.z, t = threadIdx.x;
  int lane = t & 63, w = t >> 6;
  int wn = w & 1, wb = w >> 1;
  int r = lane & 15, g = lane >> 4;
  int nrow = tn * 32 + wn * 16 + r;
  int bi0 = tb * 64 + wb * 32 + r;
  const ushort* wbase = (kz < 2) ? WTW : WTF;
  const ushort* wp = wbase + (size_t)nrow * 1024 + (kz & 1) * 512 + g * 8;
  const ushort* zp0 = ZT + (size_t)bi0 * 2048 + kz * 512 + g * 8;
  const ushort* zp1 = zp0 + 16 * 2048;
  f32x4 a0 = {0.f, 0.f, 0.f, 0.f}, a1 = a0;
#pragma unroll 4
  for (int ks = 0; ks < 512; ks += 32) {
    bf16x8 fa  = *reinterpret_cast<const bf16x8*>(wp + ks);
    bf16x8 fb0 = *reinterpret_cast<const bf16x8*>(zp0 + ks);
    bf16x8 fb1 = *reinterpret_cast<const bf16x8*>(zp1 + ks);
    a0 = __builtin_amdgcn_mfma_f32_16x16x32_bf16(fa, fb0, a0, 0, 0, 0);
    a1 = __builtin_amdgcn_mfma_f32_16x16x32_bf16(fa, fb1, a1, 0, 0, 0);
  }
  float* P = kz == 0 ? P0 : kz == 1 ? P1 : kz == 2 ? P2 : P3;
  int nbase = tn * 32 + wn * 16 + g * 4;
  int bib = tb * 64 + wb * 32 + r;
#pragma unroll
  for (int rr = 0; rr < 4; rr++) {
    P[(size_t)(nbase + rr) * 512 + bib]      = a0[rr];
    P[(size_t)(nbase + rr) * 512 + bib + 16] = a1[rr];
  }
}

// ---- out = CFINAL * (P0+P1+P2+P3 + w1[n]*RV[b][i']) ----
__global__ __launch_bounds__(256) void k_final_red(const float* __restrict__ P0, const float* __restrict__ P1,
                                                   const float* __restrict__ P2, const float* __restrict__ P3,
                                                   const float* __restrict__ w1,
                                                   const float* __restrict__ RV, float* __restrict__ out) {
  int idx4 = blockIdx.x * 256 + threadIdx.x;
  int i4p = idx4 & 15;
  int n = (idx4 >> 4) & 1023;
  int b = idx4 >> 14;
  int pidx = n * 128 + b * 16 + i4p;
  float4 a0 = reinterpret_cast<const float4*>(P0)[pidx];
  float4 a1 = reinterpret_cast<const float4*>(P1)[pidx];
  float4 a2 = reinterpret_cast<const float4*>(P2)[pidx];
  float4 a3 = reinterpret_cast<const float4*>(P3)[pidx];
  float4 d = reinterpret_cast<const float4*>(RV + (size_t)b * 64)[i4p];
  float wv = w1[n];
  float4 r;
  r.x = CFINAL * (a0.x + a1.x + a2.x + a3.x + wv * d.x);
  r.y = CFINAL * (a0.y + a1.y + a2.y + a3.y + wv * d.y);
  r.z = CFINAL * (a0.z + a1.z + a2.z + a3.z + wv * d.z);
  r.w = CFINAL * (a0.w + a1.w + a2.w + a3.w + wv * d.w);
  reinterpret_cast<float4*>(out)[idx4] = r;
}

extern "C" void kernel_launch(void* const* d_in, const int* in_sizes, int n_in,
                              void* d_out, int out_size, void* d_ws, size_t ws_size,
                              hipStream_t stream) {
  (void)in_sizes; (void)n_in; (void)out_size;
  const float* xy  = (const float*)d_in[1];
  const float* kW1 = (const float*)d_in[3];
  const float* kb1 = (const float*)d_in[4];
  const float* kW2 = (const float*)d_in[5];
  const float* kb2 = (const float*)d_in[6];
  const float* kW3 = (const float*)d_in[7];
  const float* kb3 = (const float*)d_in[8];
  const float* fW1 = (const float*)d_in[9];
  const float* fb1 = (const float*)d_in[10];
  const float* fW2 = (const float*)d_in[11];
  const float* fb2 = (const float*)d_in[12];
  const float* fW3 = (const float*)d_in[13];
  const float* fb3 = (const float*)d_in[14];
  const float* Wq  = (const float*)d_in[15];
  const float* bq  = (const float*)d_in[16];
  const float* Wk  = (const float*)d_in[17];
  const float* bk  = (const float*)d_in[18];
  const float* lng = (const float*)d_in[19];
  const float* lnb = (const float*)d_in[20];
  float* ws = (float*)d_ws;
  float* out = (float*)d_out;
  if (ws_size < WS_FLOATS * sizeof(float)) return;  // visible failure, no OOB

  float* V   = ws + OFF_V;
  float* U1K = ws + OFF_U1K;
  float* U2K = ws + OFF_U2K;
  float* U1F = ws + OFF_U1F;
  float* U2F = ws + OFF_U2F;
  float* GPb = ws + OFF_GP;
  float* SPb = ws + OFF_SP;
  float* LNP = ws + OFF_LNP;
  float* W1v = ws + OFF_W1;
  // overlays
  float* A    = ws + OFF_A;
  float* RV   = ws + OFF_RV;
  float* STAT = ws + OFF_LNP;
  ushort* Wbf  = (ushort*)(ws + OFF_W);
  ushort* WTW  = (ushort*)(ws + OFF_W + 524288);
  ushort* Wfbf = (ushort*)(ws + OFF_WF);
  ushort* WTF  = (ushort*)(ws + OFF_WF + 524288);
  ushort* ZT   = (ushort*)(ws + OFF_MID);
  float* Ep   = ws + OFF_ZU;
  float* Fp   = ws + OFF_ZU + 49152;
  float* Gpp  = ws + OFF_ZU + 49920;
  float* Cp   = ws + OFF_ZU + 50688;
  float* P0   = ws + OFF_GP;
  float* P1   = ws + OFF_GP + 524288;
  float* P2   = ws + OFF_MID + 524288;
  float* P3   = ws + OFF_ZU;

  k_prep<<<dim3(16), dim3(256), 0, stream>>>(kW1, kb1, fW1, fb1, U1K, U2K, U1F, U2F,
                                             Wq, bq, Wk, bk, Ep, Fp, Gpp, Cp);
  k_mlp2<<<dim3(1024, 2), dim3(256), 0, stream>>>(U1K, U2K, kW2, kb2, kW3, kb3,
                                                  U1F, U2F, fW2, fb2, fW3, fb3, Wbf, Wfbf);
  k_cvtTb<<<dim3(16, 16, 2), dim3(256), 0, stream>>>(Wbf, Wfbf, WTW, WTF);
  k_colsumT<<<dim3(64), dim3(256), 0, stream>>>(WTW, WTF, W1v);

  k_redsum<<<dim3(32, 8), dim3(256), 0, stream>>>(xy, LNP);
  k_apply0<<<dim3(32, 8), dim3(256), 0, stream>>>(xy, lng, lnb, LNP, V, GPb, SPb);

  for (int j = 0; j < 2; j++) {
    k_headsA3<<<dim3(8), dim3(256), 0, stream>>>(GPb, SPb, 32, Ep, Fp, Gpp, Cp,
                                                 j, DXDYf * SCALEf, 1, A, RV, STAT);
    k_midapply<<<dim3(32, 8), dim3(256), 0, stream>>>(
        V, A, RV, STAT, lng + (size_t)(j + 1) * 131072, lnb + (size_t)(j + 1) * 131072,
        (j == 1) ? xy : nullptr, GPb, SPb, (j == 1) ? 16 : 32);
  }
  k_headsA3<<<dim3(8), dim3(256), 0, stream>>>(GPb, SPb, 16, Ep, Fp, Gpp, Cp,
                                               2, 1.0f, 0, A, RV, STAT);
  k_y<<<dim3(32, 8, 2), dim3(256), 0, stream>>>(V, A, ZT);
  k_final_mfma<<<dim3(32, 8, 4), dim3(256), 0, stream>>>(WTW, WTF, ZT, P0, P1, P2, P3);
  k_final_red<<<dim3(512), dim3(256), 0, stream>>>(P0, P1, P2, P3, W1v, RV, out);
}

// Round 11
// 195.271 us; speedup vs baseline: 2.4284x; 2.4284x over previous
//
#include <hip/hip_runtime.h>

namespace {
constexpr int SD = 1024;           // D
constexpr int TD = 2048;           // 2D
constexpr int BATCH = 8;
constexpr int RH = 4;
constexpr float EPSc = 1e-5f;
constexpr float DXf = 2.0f / 31.0f;
constexpr float DXDYf = DXf * DXf;
constexpr float SCALEf = 0.125f;
constexpr float CFINAL = DXDYf * DXDYf * SCALEf;

// workspace offsets (floats)
constexpr size_t OFF_V   = 0;
constexpr size_t OFF_MID = OFF_V   + (size_t)BATCH * TD * 64;   // 1048576
constexpr size_t OFF_W   = OFF_MID + (size_t)BATCH * TD * 64;
constexpr size_t OFF_WF  = OFF_W   + (size_t)SD * SD;
constexpr size_t OFF_U1K = OFF_WF  + (size_t)SD * SD;
constexpr size_t OFF_U2K = OFF_U1K + SD * 32;
constexpr size_t OFF_U1F = OFF_U2K + SD * 32;
constexpr size_t OFF_U2F = OFF_U1F + SD * 32;
constexpr size_t OFF_GP  = OFF_U2F + SD * 32;                    // 8*32*4096
constexpr size_t OFF_SP  = OFF_GP  + (size_t)BATCH * 32 * 4096;  // 8*32*64
constexpr size_t OFF_A   = OFF_SP  + BATCH * 32 * 64;            // A matrix (8x4096)
constexpr size_t OFF_RV  = OFF_A   + BATCH * 4096;               // RV (8x64)
constexpr size_t OFF_LNP = OFF_RV  + BATCH * 64;                 // LNP; later STAT
constexpr size_t OFF_ZU  = OFF_LNP + BATCH * 32 * 2;             // Ep region; later P3
constexpr size_t OFF_ZF  = OFF_ZU  + (size_t)SD * 512;
constexpr size_t OFF_W1  = OFF_ZF  + (size_t)SD * 512;
constexpr size_t OFF_CS  = OFF_W1  + SD;
constexpr size_t WS_FLOATS = OFF_CS + 16 * SD;
// overlays:
//  G->U1K, SV->U1F  (U tables dead after k_mlp2)
//  Wbf->OFF_W lo, WTW->OFF_W+524288; Wfbf->OFF_WF lo, WTF->OFF_WF+524288
//  ZT->MID lo; P0->GP, P1->GP+524288, P2->MID+524288, P3->ZU
//  Ep/fp/gp/cp -> OFF_ZU (dead before P3 written); STAT->OFF_LNP
} // namespace

typedef __bf16 bf16x8 __attribute__((ext_vector_type(8)));
typedef float f32x4 __attribute__((ext_vector_type(4)));

__device__ __forceinline__ float leaky(float x) { return fmaxf(x, 0.01f * x); }
__device__ __forceinline__ float gxv(int i) { return -1.0f + (2.0f / 31.0f) * (float)i; }
__device__ __forceinline__ ushort f2bf(float x) { union { __bf16 b; ushort u; } v; v.b = (__bf16)x; return v.u; }
__device__ __forceinline__ float bf2f(ushort u) { return __uint_as_float(((uint)u) << 16); }

// ---- merged: blocks 0-3 = u-table precompute; blocks 4-15 = head-collapse precompute ----
__global__ __launch_bounds__(256) void k_prep(
    const float* __restrict__ kW1, const float* __restrict__ kb1,
    const float* __restrict__ fW1, const float* __restrict__ fb1,
    float* __restrict__ u1k, float* __restrict__ u2k,
    float* __restrict__ u1f, float* __restrict__ u2f,
    const float* __restrict__ Wq, const float* __restrict__ bq,
    const float* __restrict__ Wk, const float* __restrict__ bk,
    float* __restrict__ Ep, float* __restrict__ fp,
    float* __restrict__ gp, float* __restrict__ cp) {
  __shared__ __align__(16) float Wqs[4096];
  __shared__ float Wks[64 * 65];
  __shared__ float bqs[64], bks[64];
  int blk = blockIdx.x, t = threadIdx.x;
  if (blk < 4) {
    int n = blk * 256 + t;
    float ga = gxv(n >> 5), gb = gxv(n & 31);
    for (int j = 0; j < 32; j++) {
      u1k[n * 32 + j] = ga * kW1[j] + gb * kW1[32 + j] + kb1[j];
      u2k[n * 32 + j] = gb * kW1[64 + j] + ga * kW1[96 + j];
      u1f[n * 32 + j] = ga * fW1[j] + gb * fW1[32 + j] + fb1[j];
      u2f[n * 32 + j] = gb * fW1[64 + j] + ga * fW1[96 + j];
    }
    return;
  }
  int h = blk - 4;  // 0..11
  const float* wqb = Wq + (size_t)h * 4096;
  const float* wkb = Wk + (size_t)h * 4096;
  for (int idx = t; idx < 4096; idx += 256) {
    Wqs[idx] = wqb[idx];
    Wks[(idx >> 6) * 65 + (idx & 63)] = wkb[idx];
  }
  if (t < 64) { bqs[t] = bq[h * 64 + t]; bks[t] = bk[h * 64 + t]; }
  __syncthreads();
  int cpp = t & 63, cb = (t >> 6) * 16;
  float acc[16];
#pragma unroll
  for (int u = 0; u < 16; u++) acc[u] = 0.f;
  for (int k = 0; k < 64; k++) {
    float wkv = Wks[cpp * 65 + k];
#pragma unroll
    for (int u = 0; u < 16; u++) acc[u] += Wqs[(cb + u) * 64 + k] * wkv;
  }
  float* eo = Ep + (size_t)h * 4096;
#pragma unroll
  for (int u = 0; u < 16; u++) eo[(cb + u) * 64 + cpp] = acc[u];
  if (t < 64) {
    float f = 0.f, gg = 0.f;
    for (int k = 0; k < 64; k++) {
      f  += Wqs[t * 64 + k] * bks[k];
      gg += Wks[t * 65 + k] * bqs[k];
    }
    fp[h * 64 + t] = f;
    gp[h * 64 + t] = gg;
    float ca = bqs[t] * bks[t];
    ca += __shfl_xor(ca, 1, 64);
    ca += __shfl_xor(ca, 2, 64);
    ca += __shfl_xor(ca, 4, 64);
    ca += __shfl_xor(ca, 8, 64);
    ca += __shfl_xor(ca, 16, 64);
    ca += __shfl_xor(ca, 32, 64);
    if (t == 0) cp[h] = ca;
  }
}

// ---- MFMA edge-MLP: 2 n-rows x 512 m per block (u2 loads amortized over 2 n) ----
__global__ __launch_bounds__(256) void k_mlp2(
    const float* __restrict__ u1k, const float* __restrict__ u2k,
    const float* __restrict__ kW2, const float* __restrict__ kb2,
    const float* __restrict__ kW3, const float* __restrict__ kb3,
    const float* __restrict__ u1f, const float* __restrict__ u2f,
    const float* __restrict__ fW2, const float* __restrict__ fb2,
    const float* __restrict__ fW3, const float* __restrict__ fb3,
    ushort* __restrict__ outK, ushort* __restrict__ outF) {
  const int which = blockIdx.y;
  const float* u1 = which ? u1f : u1k;
  const float* u2 = which ? u2f : u2k;
  const float* W2 = which ? fW2 : kW2;
  const float* b2 = which ? fb2 : kb2;
  const float* W3 = which ? fW3 : kW3;
  const float* b3 = which ? fb3 : kb3;
  ushort* out = which ? outF : outK;

  const int t = threadIdx.x;
  const int lane = t & 63, wave = t >> 6;
  const int row = lane & 15, grp = lane >> 4;
  const int n0 = (blockIdx.x >> 1) * 2;
  const int mh = blockIdx.x & 1;

  bf16x8 wfrag[4];
  float4 b2q[4], w3q[4];
#pragma unroll
  for (int tt = 0; tt < 4; tt++) {
#pragma unroll
    for (int i = 0; i < 8; i++) wfrag[tt][i] = (__bf16)W2[(grp * 8 + i) * 64 + tt * 16 + row];
    b2q[tt] = *reinterpret_cast<const float4*>(b2 + tt * 16 + grp * 4);
    w3q[tt] = *reinterpret_cast<const float4*>(W3 + tt * 16 + grp * 4);
  }
  float u1j[2][8];
#pragma unroll
  for (int nn = 0; nn < 2; nn++)
#pragma unroll
    for (int i = 0; i < 8; i++) u1j[nn][i] = u1[(n0 + nn) * 32 + grp * 8 + i];
  const float b3v = b3[0];

#pragma unroll
  for (int chunk = 0; chunk < 2; chunk++) {
#pragma unroll
    for (int st = 0; st < 4; st++) {
      int mbase = mh * 512 + chunk * 256 + wave * 64 + st * 16;
      int m = mbase + row;
      const float4* u2p = reinterpret_cast<const float4*>(u2 + (size_t)m * 32 + grp * 8);
      float4 ua = u2p[0], ub = u2p[1];
      float hv[8] = {ua.x, ua.y, ua.z, ua.w, ub.x, ub.y, ub.z, ub.w};
#pragma unroll
      for (int nn = 0; nn < 2; nn++) {
        bf16x8 pfrag;
#pragma unroll
        for (int i = 0; i < 8; i++) pfrag[i] = (__bf16)leaky(u1j[nn][i] + hv[i]);
        float accv = 0.f;
#pragma unroll
        for (int tt = 0; tt < 4; tt++) {
          f32x4 ci = {b2q[tt].x, b2q[tt].y, b2q[tt].z, b2q[tt].w};
          f32x4 c = __builtin_amdgcn_mfma_f32_16x16x32_bf16(wfrag[tt], pfrag, ci, 0, 0, 0);
          accv += leaky(c[0]) * w3q[tt].x;
          accv += leaky(c[1]) * w3q[tt].y;
          accv += leaky(c[2]) * w3q[tt].z;
          accv += leaky(c[3]) * w3q[tt].w;
        }
        accv += __shfl_xor(accv, 16, 64);
        accv += __shfl_xor(accv, 32, 64);
        if (grp == 0) out[(size_t)(n0 + nn) * SD + mbase + row] = f2bf(accv + b3v);
      }
    }
  }
}

// ---- bf16 transpose ----
__global__ __launch_bounds__(256) void k_cvtTb(const ushort* __restrict__ srcA, const ushort* __restrict__ srcB,
                                               ushort* __restrict__ dstA, ushort* __restrict__ dstB) {
  __shared__ float T[64][65];
  const ushort* src = blockIdx.z ? srcB : srcA;
  ushort* dst = blockIdx.z ? dstB : dstA;
  int t = threadIdx.x;
  int c0 = blockIdx.x * 64, r0 = blockIdx.y * 64;
  int rr = t >> 2, cc = (t & 3) * 16;
  const uint4* s4 = reinterpret_cast<const uint4*>(src + (size_t)(r0 + rr) * 1024 + c0 + cc);
  uint4 q0 = s4[0], q1 = s4[1];
  uint qs[8] = {q0.x, q0.y, q0.z, q0.w, q1.x, q1.y, q1.z, q1.w};
#pragma unroll
  for (int j = 0; j < 8; j++) {
    T[rr][cc + 2 * j]     = bf2f((ushort)(qs[j] & 0xffffu));
    T[rr][cc + 2 * j + 1] = bf2f((ushort)(qs[j] >> 16));
  }
  __syncthreads();
  uint pk[8];
#pragma unroll
  for (int j = 0; j < 8; j++) {
    uint lo = (uint)f2bf(T[cc + 2 * j][rr]);
    uint hi = (uint)f2bf(T[cc + 2 * j + 1][rr]);
    pk[j] = lo | (hi << 16);
  }
  ushort* dp = dst + (size_t)(c0 + rr) * 1024 + r0 + cc;
  uint4* dp4 = reinterpret_cast<uint4*>(dp);
  dp4[0] = make_uint4(pk[0], pk[1], pk[2], pk[3]);
  dp4[1] = make_uint4(pk[4], pk[5], pk[6], pk[7]);
}

// ---- w1[n] = rowsum(WTW[n]) + rowsum(WTF[n]) ----
__global__ __launch_bounds__(256) void k_colsumT(const ushort* __restrict__ WTW, const ushort* __restrict__ WTF,
                                                 float* __restrict__ w1) {
  int t = threadIdx.x;
  int n = blockIdx.x * 16 + (t >> 4), seg = t & 15;
  const uint4* pa = reinterpret_cast<const uint4*>(WTW + (size_t)n * 1024 + seg * 64);
  const uint4* pf = reinterpret_cast<const uint4*>(WTF + (size_t)n * 1024 + seg * 64);
  float s = 0.f;
#pragma unroll
  for (int q = 0; q < 8; q++) {
    uint4 va = pa[q], vf = pf[q];
    uint u[8] = {va.x, va.y, va.z, va.w, vf.x, vf.y, vf.z, vf.w};
#pragma unroll
    for (int j = 0; j < 8; j++) s += bf2f((ushort)(u[j] & 0xffffu)) + bf2f((ushort)(u[j] >> 16));
  }
  s += __shfl_xor(s, 1, 64);
  s += __shfl_xor(s, 2, 64);
  s += __shfl_xor(s, 4, 64);
  s += __shfl_xor(s, 8, 64);
  if (seg == 0) w1[n] = s;
}

// ---- LN partial sums over xy ----
__global__ __launch_bounds__(256) void k_redsum(const float* __restrict__ X, float* __restrict__ part) {
  int b = blockIdx.y, c = blockIdx.x, t = threadIdx.x;
  const float4* X4 = reinterpret_cast<const float4*>(X + (size_t)b * 131072 + (size_t)c * 4096);
  float s = 0.f, q = 0.f;
#pragma unroll
  for (int k = 0; k < 4; k++) {
    float4 v = X4[t + k * 256];
    s += v.x + v.y + v.z + v.w;
    q += v.x * v.x + v.y * v.y + v.z * v.z + v.w * v.w;
  }
  for (int off = 32; off; off >>= 1) { s += __shfl_down(s, off); q += __shfl_down(q, off); }
  __shared__ float ss[4], qq[4];
  int lane = t & 63, wid = t >> 6;
  if (lane == 0) { ss[wid] = s; qq[wid] = q; }
  __syncthreads();
  if (t == 0) {
    part[(size_t)(b * 32 + c) * 2] = ss[0] + ss[1] + ss[2] + ss[3];
    part[(size_t)(b * 32 + c) * 2 + 1] = qq[0] + qq[1] + qq[2] + qq[3];
  }
}

// ---- initial LN-apply (stats from LNP) + XtY 4x4-tile partials ----
__global__ __launch_bounds__(256) void k_apply0(
    const float* __restrict__ src, const float* __restrict__ g,
    const float* __restrict__ bb, const float* __restrict__ lnp,
    float* __restrict__ Vout, float* __restrict__ Gp, float* __restrict__ sp) {
  int c = blockIdx.x, b = blockIdx.y, t = threadIdx.x;
  __shared__ float sm[2];
  __shared__ __align__(16) float Vs[4096];
  if (t == 0) {
    float s = 0.f, q = 0.f;
    for (int cc = 0; cc < 32; cc++) {
      s += lnp[(size_t)(b * 32 + cc) * 2];
      q += lnp[(size_t)(b * 32 + cc) * 2 + 1];
    }
    float mean = s / 131072.0f;
    sm[0] = mean;
    sm[1] = rsqrtf(q / 131072.0f - mean * mean + EPSc);
  }
  __syncthreads();
  float mean = sm[0], is = sm[1];
  size_t base4 = (size_t)b * 32768 + (size_t)c * 1024;
#pragma unroll
  for (int k = 0; k < 4; k++) {
    int idx = t + k * 256;
    float4 v = reinterpret_cast<const float4*>(src)[base4 + idx];
    float4 gg = reinterpret_cast<const float4*>(g)[c * 1024 + idx];
    float4 bv = reinterpret_cast<const float4*>(bb)[c * 1024 + idx];
    float4 r;
    r.x = (v.x - mean) * is * gg.x + bv.x;
    r.y = (v.y - mean) * is * gg.y + bv.y;
    r.z = (v.z - mean) * is * gg.z + bv.z;
    r.w = (v.w - mean) * is * gg.w + bv.w;
    reinterpret_cast<float4*>(Vout)[base4 + idx] = r;
    reinterpret_cast<float4*>(Vs)[idx] = r;
  }
  __syncthreads();
  int tp = t >> 4, tq = t & 15;
  float a2[4][4] = {};
  for (int k = 0; k < 64; k++) {
    float4 xv = *reinterpret_cast<const float4*>(&Vs[k * 64 + tp * 4]);
    float4 yv = *reinterpret_cast<const float4*>(&Vs[k * 64 + tq * 4]);
    a2[0][0] += xv.x * yv.x; a2[0][1] += xv.x * yv.y; a2[0][2] += xv.x * yv.z; a2[0][3] += xv.x * yv.w;
    a2[1][0] += xv.y * yv.x; a2[1][1] += xv.y * yv.y; a2[1][2] += xv.y * yv.z; a2[1][3] += xv.y * yv.w;
    a2[2][0] += xv.z * yv.x; a2[2][1] += xv.z * yv.y; a2[2][2] += xv.z * yv.z; a2[2][3] += xv.z * yv.w;
    a2[3][0] += xv.w * yv.x; a2[3][1] += xv.w * yv.y; a2[3][2] += xv.w * yv.z; a2[3][3] += xv.w * yv.w;
  }
  float* go = Gp + (size_t)(b * 32 + c) * 4096;
#pragma unroll
  for (int i = 0; i < 4; i++) {
    float4 w = {a2[i][0], a2[i][1], a2[i][2], a2[i][3]};
    *reinterpret_cast<float4*>(&go[(tp * 4 + i) * 64 + tq * 4]) = w;
  }
  if (t < 64) {
    float s = 0.f;
    for (int k = 0; k < 64; k++) s += Vs[k * 64 + t];
    sp[(size_t)(b * 32 + c) * 64 + t] = s;
  }
}

// ---- coalesced partial reduction: G = sum_c Gp[c], sv = sum_c sp[c] (128 blocks) ----
__global__ __launch_bounds__(256) void k_gred(const float* __restrict__ Gp, const float* __restrict__ sp,
                                              float* __restrict__ G, float* __restrict__ sv, int nch) {
  int blk = blockIdx.x, b = blockIdx.y, t = threadIdx.x;
  int idx = blk * 256 + t;
  float a = 0.f;
  for (int c = 0; c < nch; c++) a += Gp[(size_t)(b * nch + c) * 4096 + idx];
  G[(size_t)b * 4096 + idx] = a;
  if (blk == 0 && t < 64) {
    float s = 0.f;
    for (int c = 0; c < nch; c++) s += sp[(size_t)(b * nch + c) * 64 + t];
    sv[b * 64 + t] = s;
  }
}

// ---- A = scale*(E_j G + f_j (x) s); r = scale*(g_j^T G + c_j s); analytic mid-LN stats ----
__global__ __launch_bounds__(256) void k_headsA2(
    const float* __restrict__ G, const float* __restrict__ sv,
    const float* __restrict__ Ep, const float* __restrict__ fp,
    const float* __restrict__ gp, const float* __restrict__ cp,
    int j, float scale, int doStats,
    float* __restrict__ A, float* __restrict__ RVo, float* __restrict__ STAT) {
  int b = blockIdx.x, t = threadIdx.x;
  __shared__ float Es[64 * 65];
  __shared__ __align__(16) float Gs[4096];
  __shared__ __align__(16) float As[4096];
  __shared__ float ss[64], fs[64], gs[64];
  __shared__ float cj;
  __shared__ float redbuf[8];
  const float* e0 = Ep + (size_t)(j * RH) * 4096;
  for (int idx = t; idx < 4096; idx += 256) {
    float e = e0[idx] + e0[idx + 4096] + e0[idx + 8192] + e0[idx + 12288];
    Es[(idx >> 6) * 65 + (idx & 63)] = e;
    Gs[idx] = G[(size_t)b * 4096 + idx];
  }
  if (t < 64) {
    ss[t] = sv[b * 64 + t];
    int h0 = j * RH * 64;
    fs[t] = fp[h0 + t] + fp[h0 + 64 + t] + fp[h0 + 128 + t] + fp[h0 + 192 + t];
    gs[t] = gp[h0 + t] + gp[h0 + 64 + t] + gp[h0 + 128 + t] + gp[h0 + 192 + t];
  }
  if (t == 0) cj = cp[j * RH] + cp[j * RH + 1] + cp[j * RH + 2] + cp[j * RH + 3];
  __syncthreads();
  int c = t >> 2, qb = (t & 3) * 16;
  float fv = fs[c];
  float4 acc[4];
#pragma unroll
  for (int u = 0; u < 4; u++) {
    acc[u].x = fv * ss[qb + u * 4 + 0];
    acc[u].y = fv * ss[qb + u * 4 + 1];
    acc[u].z = fv * ss[qb + u * 4 + 2];
    acc[u].w = fv * ss[qb + u * 4 + 3];
  }
  for (int d = 0; d < 64; d++) {
    float ev = Es[c * 65 + d];
    const float4* gr = reinterpret_cast<const float4*>(&Gs[d * 64 + qb]);
#pragma unroll
    for (int u = 0; u < 4; u++) {
      float4 gv = gr[u];
      acc[u].x += ev * gv.x; acc[u].y += ev * gv.y; acc[u].z += ev * gv.z; acc[u].w += ev * gv.w;
    }
  }
  float* ao = A + (size_t)b * 4096 + c * 64 + qb;
#pragma unroll
  for (int u = 0; u < 4; u++) {
    float4 v = acc[u];
    v.x *= scale; v.y *= scale; v.z *= scale; v.w *= scale;
    reinterpret_cast<float4*>(ao)[u] = v;
    *reinterpret_cast<float4*>(&As[c * 64 + qb + u * 4]) = v;
  }
  float rv_t = 0.f;
  if (t < 64) {
    float r = cj * ss[t];
    for (int d = 0; d < 64; d++) r += gs[d] * Gs[d * 64 + t];
    r *= scale;
    RVo[b * 64 + t] = r;
    rv_t = r;
  }
  if (!doStats) return;
  __syncthreads();
  float4 h[4] = {};
  for (int d = 0; d < 64; d++) {
    float gvv = Gs[c * 64 + d];
    const float4* ar = reinterpret_cast<const float4*>(&As[d * 64 + qb]);
#pragma unroll
    for (int u = 0; u < 4; u++) {
      float4 av = ar[u];
      h[u].x += gvv * av.x; h[u].y += gvv * av.y; h[u].z += gvv * av.z; h[u].w += gvv * av.w;
    }
  }
  float tp_ = 0.f;
#pragma unroll
  for (int u = 0; u < 4; u++) {
    float4 a = *reinterpret_cast<const float4*>(&As[c * 64 + qb + u * 4]);
    tp_ += a.x * h[u].x + a.y * h[u].y + a.z * h[u].z + a.w * h[u].w;
  }
  tp_ += __shfl_xor(tp_, 1, 64);  tp_ += __shfl_xor(tp_, 2, 64);
  tp_ += __shfl_xor(tp_, 4, 64);  tp_ += __shfl_xor(tp_, 8, 64);
  tp_ += __shfl_xor(tp_, 16, 64); tp_ += __shfl_xor(tp_, 32, 64);
  if ((t & 63) == 0) redbuf[t >> 6] = tp_;
  if (t < 64) {
    float t1 = 0.f;
    for (int d = 0; d < 64; d++) t1 += ss[d] * As[d * 64 + t];
    float s1 = t1, sr = rv_t, sr2 = rv_t * rv_t, srt = rv_t * t1;
#pragma unroll
    for (int off = 1; off < 64; off <<= 1) {
      s1  += __shfl_xor(s1, off, 64);
      sr  += __shfl_xor(sr, off, 64);
      sr2 += __shfl_xor(sr2, off, 64);
      srt += __shfl_xor(srt, off, 64);
    }
    if (t == 0) { redbuf[4] = s1; redbuf[5] = sr; redbuf[6] = sr2; redbuf[7] = srt; }
  }
  __syncthreads();
  if (t == 0) {
    float tr = redbuf[0] + redbuf[1] + redbuf[2] + redbuf[3];
    float smid = redbuf[4] + 2048.0f * redbuf[5];
    float mu = smid / 131072.0f;
    float e2 = (tr + 2.0f * redbuf[7] + 2048.0f * redbuf[6]) / 131072.0f;
    STAT[b * 2] = mu;
    STAT[b * 2 + 1] = rsqrtf(e2 - mu * mu + EPSc);
  }
}

// ---- fused: mid = V A + 1 r^T; LN via analytic stats; +V residual; write V'; XtY partials ----
__global__ __launch_bounds__(256) void k_midapply(
    float* __restrict__ V, const float* __restrict__ A,
    const float* __restrict__ RVv, const float* __restrict__ STAT,
    const float* __restrict__ g, const float* __restrict__ bb,
    const float* __restrict__ Yext,
    float* __restrict__ Gp, float* __restrict__ sp, int nchG) {
  int blk = blockIdx.x, b = blockIdx.y, t = threadIdx.x;
  __shared__ __align__(16) float As[4096];
  __shared__ __align__(16) float Vs[4096];
  __shared__ __align__(16) float Ys[4096];
  __shared__ float rs[64];
  __shared__ float sm[2];
  const float4* A4 = reinterpret_cast<const float4*>(A + (size_t)b * 4096);
#pragma unroll
  for (int k = 0; k < 4; k++) reinterpret_cast<float4*>(As)[t + k * 256] = A4[t + k * 256];
  if (t < 64) rs[t] = RVv[b * 64 + t];
  if (t == 0) { sm[0] = STAT[b * 2]; sm[1] = STAT[b * 2 + 1]; }
  bool doG = (blk < nchG);
  if (Yext != nullptr && doG) {
    size_t yb = (size_t)b * 32768 + (size_t)blk * 1024;
#pragma unroll
    for (int k = 0; k < 4; k++)
      reinterpret_cast<float4*>(Ys)[t + k * 256] = reinterpret_cast<const float4*>(Yext)[yb + t + k * 256];
  }
  __syncthreads();
  float mu = sm[0], is = sm[1];
  int rl = t >> 2, qb = (t & 3) * 16;
  int row = blk * 64 + rl;
  float* vr = V + (size_t)b * 131072 + (size_t)row * 64;
  float4 acc[4];
#pragma unroll
  for (int u = 0; u < 4; u++) {
    acc[u].x = rs[qb + u * 4 + 0]; acc[u].y = rs[qb + u * 4 + 1];
    acc[u].z = rs[qb + u * 4 + 2]; acc[u].w = rs[qb + u * 4 + 3];
  }
  for (int c = 0; c < 64; c++) {
    float vv = vr[c];
    const float4* ar = reinterpret_cast<const float4*>(&As[c * 64 + qb]);
#pragma unroll
    for (int u = 0; u < 4; u++) {
      float4 av = ar[u];
      acc[u].x += vv * av.x; acc[u].y += vv * av.y; acc[u].z += vv * av.z; acc[u].w += vv * av.w;
    }
  }
  const float4* g4 = reinterpret_cast<const float4*>(g + (size_t)row * 64 + qb);
  const float4* b4 = reinterpret_cast<const float4*>(bb + (size_t)row * 64 + qb);
  const float4* vq = reinterpret_cast<const float4*>(vr + qb);
  float4* vo = reinterpret_cast<float4*>(vr + qb);
#pragma unroll
  for (int u = 0; u < 4; u++) {
    float4 gg = g4[u], bv = b4[u], av = vq[u];
    float4 r;
    r.x = (acc[u].x - mu) * is * gg.x + bv.x + av.x;
    r.y = (acc[u].y - mu) * is * gg.y + bv.y + av.y;
    r.z = (acc[u].z - mu) * is * gg.z + bv.z + av.z;
    r.w = (acc[u].w - mu) * is * gg.w + bv.w + av.w;
    vo[u] = r;
    *reinterpret_cast<float4*>(&Vs[rl * 64 + qb + u * 4]) = r;
  }
  __syncthreads();
  if (!doG) return;
  const float* Yp = (Yext != nullptr) ? Ys : Vs;
  int tp = t >> 4, tq = t & 15;
  float a2[4][4] = {};
  for (int k = 0; k < 64; k++) {
    float4 xv = *reinterpret_cast<const float4*>(&Vs[k * 64 + tp * 4]);
    float4 yv = *reinterpret_cast<const float4*>(&Yp[k * 64 + tq * 4]);
    a2[0][0] += xv.x * yv.x; a2[0][1] += xv.x * yv.y; a2[0][2] += xv.x * yv.z; a2[0][3] += xv.x * yv.w;
    a2[1][0] += xv.y * yv.x; a2[1][1] += xv.y * yv.y; a2[1][2] += xv.y * yv.z; a2[1][3] += xv.y * yv.w;
    a2[2][0] += xv.z * yv.x; a2[2][1] += xv.z * yv.y; a2[2][2] += xv.z * yv.z; a2[2][3] += xv.z * yv.w;
    a2[3][0] += xv.w * yv.x; a2[3][1] += xv.w * yv.y; a2[3][2] += xv.w * yv.z; a2[3][3] += xv.w * yv.w;
  }
  float* go = Gp + (size_t)(b * nchG + blk) * 4096;
#pragma unroll
  for (int i = 0; i < 4; i++) {
    float4 w = {a2[i][0], a2[i][1], a2[i][2], a2[i][3]};
    *reinterpret_cast<float4*>(&go[(tp * 4 + i) * 64 + tq * 4]) = w;
  }
  if (t < 64) {
    float s = 0.f;
    for (int k = 0; k < 64; k++) s += Yp[k * 64 + t];
    sp[(size_t)(b * nchG + blk) * 64 + t] = s;
  }
}

// ---- k_y: ZT[b*64+q][z*1024+m] = bf16(V A); LDS-staged coalesced uint4 stores ----
__global__ __launch_bounds__(256) void k_y(const float* __restrict__ V, const float* __restrict__ A,
                                           ushort* __restrict__ ZT) {
  int blk = blockIdx.x, b = blockIdx.y, z = blockIdx.z, t = threadIdx.x;
  __shared__ __align__(16) float As[4096];
  __shared__ ushort Zs[64][36];
  const float4* A4 = reinterpret_cast<const float4*>(A + (size_t)b * 4096);
#pragma unroll
  for (int k = 0; k < 4; k++) reinterpret_cast<float4*>(As)[t + k * 256] = A4[t + k * 256];
  __syncthreads();
  int ml = t >> 3, qb = (t & 7) * 8;
  int m = blk * 32 + ml;
  const float* vr = V + (size_t)b * 131072 + (size_t)(z * 1024 + m) * 64;
  float4 acc[2] = {};
  for (int c = 0; c < 64; c++) {
    float vv = vr[c];
    const float4* ar = reinterpret_cast<const float4*>(&As[c * 64 + qb]);
#pragma unroll
    for (int u = 0; u < 2; u++) {
      float4 av = ar[u];
      acc[u].x += vv * av.x; acc[u].y += vv * av.y; acc[u].z += vv * av.z; acc[u].w += vv * av.w;
    }
  }
  Zs[qb + 0][ml] = f2bf(acc[0].x); Zs[qb + 1][ml] = f2bf(acc[0].y);
  Zs[qb + 2][ml] = f2bf(acc[0].z); Zs[qb + 3][ml] = f2bf(acc[0].w);
  Zs[qb + 4][ml] = f2bf(acc[1].x); Zs[qb + 5][ml] = f2bf(acc[1].y);
  Zs[qb + 6][ml] = f2bf(acc[1].z); Zs[qb + 7][ml] = f2bf(acc[1].w);
  __syncthreads();
  int rowq = t >> 2, seg = t & 3;
  const ushort* srcp = &Zs[rowq][seg * 8];
  uint p0 = (uint)srcp[0] | ((uint)srcp[1] << 16);
  uint p1 = (uint)srcp[2] | ((uint)srcp[3] << 16);
  uint p2 = (uint)srcp[4] | ((uint)srcp[5] << 16);
  uint p3 = (uint)srcp[6] | ((uint)srcp[7] << 16);
  ushort* dp = ZT + (size_t)(b * 64 + rowq) * 2048 + (size_t)z * 1024 + blk * 32 + seg * 8;
  *reinterpret_cast<uint4*>(dp) = make_uint4(p0, p1, p2, p3);
}

// ---- MFMA final GEMM ----
__global__ __launch_bounds__(256) void k_final_mfma(const ushort* __restrict__ WTW,
                                                    const ushort* __restrict__ WTF,
                                                    const ushort* __restrict__ ZT,
                                                    float* __restrict__ P0, float* __restrict__ P1,
                                                    float* __restrict__ P2, float* __restrict__ P3) {
  int tn = blockIdx.x, tb = blockIdx.y, kz = blockIdx.z, t = threadIdx.x;
  int lane = t & 63, w = t >> 6;
  int wn = w & 1, wb = w >> 1;
  int r = lane & 15, g = lane >> 4;
  int nrow = tn * 32 + wn * 16 + r;
  int bi0 = tb * 64 + wb * 32 + r;
  const ushort* wbase = (kz < 2) ? WTW : WTF;
  const ushort* wp = wbase + (size_t)nrow * 1024 + (kz & 1) * 512 + g * 8;
  const ushort* zp0 = ZT + (size_t)bi0 * 2048 + kz * 512 + g * 8;
  const ushort* zp1 = zp0 + 16 * 2048;
  f32x4 a0 = {0.f, 0.f, 0.f, 0.f}, a1 = a0;
#pragma unroll 4
  for (int ks = 0; ks < 512; ks += 32) {
    bf16x8 fa  = *reinterpret_cast<const bf16x8*>(wp + ks);
    bf16x8 fb0 = *reinterpret_cast<const bf16x8*>(zp0 + ks);
    bf16x8 fb1 = *reinterpret_cast<const bf16x8*>(zp1 + ks);
    a0 = __builtin_amdgcn_mfma_f32_16x16x32_bf16(fa, fb0, a0, 0, 0, 0);
    a1 = __builtin_amdgcn_mfma_f32_16x16x32_bf16(fa, fb1, a1, 0, 0, 0);
  }
  float* P = kz == 0 ? P0 : kz == 1 ? P1 : kz == 2 ? P2 : P3;
  int nbase = tn * 32 + wn * 16 + g * 4;
  int bib = tb * 64 + wb * 32 + r;
#pragma unroll
  for (int rr = 0; rr < 4; rr++) {
    P[(size_t)(nbase + rr) * 512 + bib]      = a0[rr];
    P[(size_t)(nbase + rr) * 512 + bib + 16] = a1[rr];
  }
}

// ---- out = CFINAL * (P0+P1+P2+P3 + w1[n]*RV[b][i']) ----
__global__ __launch_bounds__(256) void k_final_red(const float* __restrict__ P0, const float* __restrict__ P1,
                                                   const float* __restrict__ P2, const float* __restrict__ P3,
                                                   const float* __restrict__ w1,
                                                   const float* __restrict__ RV, float* __restrict__ out) {
  int idx4 = blockIdx.x * 256 + threadIdx.x;
  int i4p = idx4 & 15;
  int n = (idx4 >> 4) & 1023;
  int b = idx4 >> 14;
  int pidx = n * 128 + b * 16 + i4p;
  float4 a0 = reinterpret_cast<const float4*>(P0)[pidx];
  float4 a1 = reinterpret_cast<const float4*>(P1)[pidx];
  float4 a2 = reinterpret_cast<const float4*>(P2)[pidx];
  float4 a3 = reinterpret_cast<const float4*>(P3)[pidx];
  float4 d = reinterpret_cast<const float4*>(RV + (size_t)b * 64)[i4p];
  float wv = w1[n];
  float4 r;
  r.x = CFINAL * (a0.x + a1.x + a2.x + a3.x + wv * d.x);
  r.y = CFINAL * (a0.y + a1.y + a2.y + a3.y + wv * d.y);
  r.z = CFINAL * (a0.z + a1.z + a2.z + a3.z + wv * d.z);
  r.w = CFINAL * (a0.w + a1.w + a2.w + a3.w + wv * d.w);
  reinterpret_cast<float4*>(out)[idx4] = r;
}

extern "C" void kernel_launch(void* const* d_in, const int* in_sizes, int n_in,
                              void* d_out, int out_size, void* d_ws, size_t ws_size,
                              hipStream_t stream) {
  (void)in_sizes; (void)n_in; (void)out_size;
  const float* xy  = (const float*)d_in[1];
  const float* kW1 = (const float*)d_in[3];
  const float* kb1 = (const float*)d_in[4];
  const float* kW2 = (const float*)d_in[5];
  const float* kb2 = (const float*)d_in[6];
  const float* kW3 = (const float*)d_in[7];
  const float* kb3 = (const float*)d_in[8];
  const float* fW1 = (const float*)d_in[9];
  const float* fb1 = (const float*)d_in[10];
  const float* fW2 = (const float*)d_in[11];
  const float* fb2 = (const float*)d_in[12];
  const float* fW3 = (const float*)d_in[13];
  const float* fb3 = (const float*)d_in[14];
  const float* Wq  = (const float*)d_in[15];
  const float* bq  = (const float*)d_in[16];
  const float* Wk  = (const float*)d_in[17];
  const float* bk  = (const float*)d_in[18];
  const float* lng = (const float*)d_in[19];
  const float* lnb = (const float*)d_in[20];
  float* ws = (float*)d_ws;
  float* out = (float*)d_out;
  if (ws_size < WS_FLOATS * sizeof(float)) return;  // visible failure, no OOB

  float* V   = ws + OFF_V;
  float* U1K = ws + OFF_U1K;
  float* U2K = ws + OFF_U2K;
  float* U1F = ws + OFF_U1F;
  float* U2F = ws + OFF_U2F;
  float* GPb = ws + OFF_GP;
  float* SPb = ws + OFF_SP;
  float* LNP = ws + OFF_LNP;
  float* W1v = ws + OFF_W1;
  // overlays
  float* G    = ws + OFF_U1K;             // 32768 (U tables dead after k_mlp2)
  float* SV   = ws + OFF_U1F;             // 512
  float* A    = ws + OFF_A;
  float* RV   = ws + OFF_RV;
  float* STAT = ws + OFF_LNP;
  ushort* Wbf  = (ushort*)(ws + OFF_W);
  ushort* WTW  = (ushort*)(ws + OFF_W + 524288);
  ushort* Wfbf = (ushort*)(ws + OFF_WF);
  ushort* WTF  = (ushort*)(ws + OFF_WF + 524288);
  ushort* ZT   = (ushort*)(ws + OFF_MID);
  float* Ep   = ws + OFF_ZU;
  float* Fp   = ws + OFF_ZU + 49152;
  float* Gpp  = ws + OFF_ZU + 49920;
  float* Cp   = ws + OFF_ZU + 50688;
  float* P0   = ws + OFF_GP;
  float* P1   = ws + OFF_GP + 524288;
  float* P2   = ws + OFF_MID + 524288;
  float* P3   = ws + OFF_ZU;

  k_prep<<<dim3(16), dim3(256), 0, stream>>>(kW1, kb1, fW1, fb1, U1K, U2K, U1F, U2F,
                                             Wq, bq, Wk, bk, Ep, Fp, Gpp, Cp);
  k_mlp2<<<dim3(1024, 2), dim3(256), 0, stream>>>(U1K, U2K, kW2, kb2, kW3, kb3,
                                                  U1F, U2F, fW2, fb2, fW3, fb3, Wbf, Wfbf);
  k_cvtTb<<<dim3(16, 16, 2), dim3(256), 0, stream>>>(Wbf, Wfbf, WTW, WTF);
  k_colsumT<<<dim3(64), dim3(256), 0, stream>>>(WTW, WTF, W1v);

  k_redsum<<<dim3(32, 8), dim3(256), 0, stream>>>(xy, LNP);
  k_apply0<<<dim3(32, 8), dim3(256), 0, stream>>>(xy, lng, lnb, LNP, V, GPb, SPb);

  for (int j = 0; j < 2; j++) {
    k_gred<<<dim3(16, 8), dim3(256), 0, stream>>>(GPb, SPb, G, SV, 32);
    k_headsA2<<<dim3(8), dim3(256), 0, stream>>>(G, SV, Ep, Fp, Gpp, Cp, j, DXDYf * SCALEf, 1,
                                                 A, RV, STAT);
    k_midapply<<<dim3(32, 8), dim3(256), 0, stream>>>(
        V, A, RV, STAT, lng + (size_t)(j + 1) * 131072, lnb + (size_t)(j + 1) * 131072,
        (j == 1) ? xy : nullptr, GPb, SPb, (j == 1) ? 16 : 32);
  }
  k_gred<<<dim3(16, 8), dim3(256), 0, stream>>>(GPb, SPb, G, SV, 16);
  k_headsA2<<<dim3(8), dim3(256), 0, stream>>>(G, SV, Ep, Fp, Gpp, Cp, 2, 1.0f, 0, A, RV, STAT);
  k_y<<<dim3(32, 8, 2), dim3(256), 0, stream>>>(V, A, ZT);
  k_final_mfma<<<dim3(32, 8, 4), dim3(256), 0, stream>>>(WTW, WTF, ZT, P0, P1, P2, P3);
  k_final_red<<<dim3(512), dim3(256), 0, stream>>>(P0, P1, P2, P3, W1v, RV, out);
}

// Round 12
// 191.248 us; speedup vs baseline: 2.4795x; 1.0210x over previous
//
#include <hip/hip_runtime.h>

namespace {
constexpr int SD = 1024;           // D
constexpr int TD = 2048;           // 2D
constexpr int BATCH = 8;
constexpr int RH = 4;
constexpr float EPSc = 1e-5f;
constexpr float DXf = 2.0f / 31.0f;
constexpr float DXDYf = DXf * DXf;
constexpr float SCALEf = 0.125f;
constexpr float CFINAL = DXDYf * DXDYf * SCALEf;

// workspace offsets (floats)
constexpr size_t OFF_V   = 0;
constexpr size_t OFF_MID = OFF_V   + (size_t)BATCH * TD * 64;   // 1048576
constexpr size_t OFF_W   = OFF_MID + (size_t)BATCH * TD * 64;
constexpr size_t OFF_WF  = OFF_W   + (size_t)SD * SD;
constexpr size_t OFF_U1K = OFF_WF  + (size_t)SD * SD;
constexpr size_t OFF_U2K = OFF_U1K + SD * 32;
constexpr size_t OFF_U1F = OFF_U2K + SD * 32;
constexpr size_t OFF_U2F = OFF_U1F + SD * 32;
constexpr size_t OFF_GP  = OFF_U2F + SD * 32;                    // 8*32*4096
constexpr size_t OFF_SP  = OFF_GP  + (size_t)BATCH * 32 * 4096;  // 8*32*64
constexpr size_t OFF_A   = OFF_SP  + BATCH * 32 * 64;            // A matrix (8x4096)
constexpr size_t OFF_RV  = OFF_A   + BATCH * 4096;               // RV (8x64)
constexpr size_t OFF_LNP = OFF_RV  + BATCH * 64;                 // LNP; later STAT
constexpr size_t OFF_ZU  = OFF_LNP + BATCH * 32 * 2;             // Ep region; later P3
constexpr size_t OFF_ZF  = OFF_ZU  + (size_t)SD * 512;
constexpr size_t OFF_W1  = OFF_ZF  + (size_t)SD * 512;
constexpr size_t OFF_CS  = OFF_W1  + SD;
constexpr size_t WS_FLOATS = OFF_CS + 16 * SD;
// overlays:
//  G->U1K, SV->U1F  (U tables dead after k_mlp2)
//  Wbf->OFF_W lo, WTW->OFF_W+524288; Wfbf->OFF_WF lo, WTF->OFF_WF+524288
//  ZT->MID lo; P0->GP, P1->GP+524288, P2->MID+524288, P3->ZU
//  Ep/fp/gp/cp/LIN -> OFF_ZU (dead before P3 written); STAT->OFF_LNP
constexpr size_t LIN_OFF = 50704;  // within ZU region: LINK[32], LINF[32], CSTK, CSTF
} // namespace

typedef __bf16 bf16x8 __attribute__((ext_vector_type(8)));
typedef float f32x4 __attribute__((ext_vector_type(4)));

__device__ __forceinline__ float leaky(float x) { return fmaxf(x, 0.01f * x); }
__device__ __forceinline__ float gxv(int i) { return -1.0f + (2.0f / 31.0f) * (float)i; }
__device__ __forceinline__ ushort f2bf(float x) { union { __bf16 b; ushort u; } v; v.b = (__bf16)x; return v.u; }
__device__ __forceinline__ float bf2f(ushort u) { return __uint_as_float(((uint)u) << 16); }

// ---- merged: blocks 0-3 = u-tables (+lin/cst on 0/1); blocks 4-15 = head-collapse ----
__global__ __launch_bounds__(256) void k_prep(
    const float* __restrict__ kW1, const float* __restrict__ kb1,
    const float* __restrict__ fW1, const float* __restrict__ fb1,
    float* __restrict__ u1k, float* __restrict__ u2k,
    float* __restrict__ u1f, float* __restrict__ u2f,
    const float* __restrict__ kW2, const float* __restrict__ kW3, const float* __restrict__ kb2,
    const float* __restrict__ fW2, const float* __restrict__ fW3, const float* __restrict__ fb2,
    float* __restrict__ LIN,
    const float* __restrict__ Wq, const float* __restrict__ bq,
    const float* __restrict__ Wk, const float* __restrict__ bk,
    float* __restrict__ Ep, float* __restrict__ fp,
    float* __restrict__ gp, float* __restrict__ cp) {
  __shared__ __align__(16) float Wqs[4096];
  __shared__ float Wks[64 * 65];
  __shared__ float bqs[64], bks[64];
  int blk = blockIdx.x, t = threadIdx.x;
  if (blk < 4) {
    int n = blk * 256 + t;
    float ga = gxv(n >> 5), gb = gxv(n & 31);
    for (int j = 0; j < 32; j++) {
      u1k[n * 32 + j] = ga * kW1[j] + gb * kW1[32 + j] + kb1[j];
      u2k[n * 32 + j] = gb * kW1[64 + j] + ga * kW1[96 + j];
      u1f[n * 32 + j] = ga * fW1[j] + gb * fW1[32 + j] + fb1[j];
      u2f[n * 32 + j] = gb * fW1[64 + j] + ga * fW1[96 + j];
    }
    // lin/cst precompute: block 0 -> k-net, block 1 -> f-net
    if (blk < 2 && t < 33) {
      const float* W2 = blk ? fW2 : kW2;
      const float* W3 = blk ? fW3 : kW3;
      const float* b2 = blk ? fb2 : kb2;
      if (t < 32) {
        float s = 0.f;
        for (int o = 0; o < 64; o++) s += W2[t * 64 + o] * W3[o];
        LIN[blk * 32 + t] = s;
      } else {
        float s = 0.f;
        for (int o = 0; o < 64; o++) s += b2[o] * W3[o];
        LIN[64 + blk] = s;   // cstraw
      }
    }
    return;
  }
  int h = blk - 4;  // 0..11
  const float* wqb = Wq + (size_t)h * 4096;
  const float* wkb = Wk + (size_t)h * 4096;
  for (int idx = t; idx < 4096; idx += 256) {
    Wqs[idx] = wqb[idx];
    Wks[(idx >> 6) * 65 + (idx & 63)] = wkb[idx];
  }
  if (t < 64) { bqs[t] = bq[h * 64 + t]; bks[t] = bk[h * 64 + t]; }
  __syncthreads();
  int cpp = t & 63, cb = (t >> 6) * 16;
  float acc[16];
#pragma unroll
  for (int u = 0; u < 16; u++) acc[u] = 0.f;
  for (int k = 0; k < 64; k++) {
    float wkv = Wks[cpp * 65 + k];
#pragma unroll
    for (int u = 0; u < 16; u++) acc[u] += Wqs[(cb + u) * 64 + k] * wkv;
  }
  float* eo = Ep + (size_t)h * 4096;
#pragma unroll
  for (int u = 0; u < 16; u++) eo[(cb + u) * 64 + cpp] = acc[u];
  if (t < 64) {
    float f = 0.f, gg = 0.f;
    for (int k = 0; k < 64; k++) {
      f  += Wqs[t * 64 + k] * bks[k];
      gg += Wks[t * 65 + k] * bqs[k];
    }
    fp[h * 64 + t] = f;
    gp[h * 64 + t] = gg;
    float ca = bqs[t] * bks[t];
    ca += __shfl_xor(ca, 1, 64);
    ca += __shfl_xor(ca, 2, 64);
    ca += __shfl_xor(ca, 4, 64);
    ca += __shfl_xor(ca, 8, 64);
    ca += __shfl_xor(ca, 16, 64);
    ca += __shfl_xor(ca, 32, 64);
    if (t == 0) cp[h] = ca;
  }
}

// ---- MFMA edge-MLP: 2 n-rows x 512 m per block; exact leaky split epilogue ----
// w3^T leaky(c) = 0.505*(cstraw + lin^T h1) + 0.495*sum_o w3[o]*|c[o]|
__global__ __launch_bounds__(256) void k_mlp2(
    const float* __restrict__ u1k, const float* __restrict__ u2k,
    const float* __restrict__ kW2, const float* __restrict__ kb2,
    const float* __restrict__ kW3, const float* __restrict__ kb3,
    const float* __restrict__ u1f, const float* __restrict__ u2f,
    const float* __restrict__ fW2, const float* __restrict__ fb2,
    const float* __restrict__ fW3, const float* __restrict__ fb3,
    const float* __restrict__ LIN,
    ushort* __restrict__ outK, ushort* __restrict__ outF) {
  const int which = blockIdx.y;
  const float* u1 = which ? u1f : u1k;
  const float* u2 = which ? u2f : u2k;
  const float* W2 = which ? fW2 : kW2;
  const float* b2 = which ? fb2 : kb2;
  const float* W3 = which ? fW3 : kW3;
  const float* b3 = which ? fb3 : kb3;
  ushort* out = which ? outF : outK;

  const int t = threadIdx.x;
  const int lane = t & 63, wave = t >> 6;
  const int row = lane & 15, grp = lane >> 4;
  const int n0 = (blockIdx.x >> 1) * 2;
  const int mh = blockIdx.x & 1;

  bf16x8 wfrag[4];
  float4 b2q[4], w3q[4];
#pragma unroll
  for (int tt = 0; tt < 4; tt++) {
#pragma unroll
    for (int i = 0; i < 8; i++) wfrag[tt][i] = (__bf16)W2[(grp * 8 + i) * 64 + tt * 16 + row];
    b2q[tt] = *reinterpret_cast<const float4*>(b2 + tt * 16 + grp * 4);
    w3q[tt] = *reinterpret_cast<const float4*>(W3 + tt * 16 + grp * 4);
  }
  // lin fragment for this lane's k = grp*8 + i
  float4 l0 = *reinterpret_cast<const float4*>(LIN + which * 32 + grp * 8);
  float4 l1 = *reinterpret_cast<const float4*>(LIN + which * 32 + grp * 8 + 4);
  float linp[8] = {l0.x, l0.y, l0.z, l0.w, l1.x, l1.y, l1.z, l1.w};
  const float cst = 0.505f * LIN[64 + which] + b3[0];

  float u1j[2][8];
#pragma unroll
  for (int nn = 0; nn < 2; nn++)
#pragma unroll
    for (int i = 0; i < 8; i++) u1j[nn][i] = u1[(n0 + nn) * 32 + grp * 8 + i];

#pragma unroll
  for (int chunk = 0; chunk < 2; chunk++) {
#pragma unroll
    for (int st = 0; st < 4; st++) {
      int mbase = mh * 512 + chunk * 256 + wave * 64 + st * 16;
      int m = mbase + row;
      const float4* u2p = reinterpret_cast<const float4*>(u2 + (size_t)m * 32 + grp * 8);
      float4 ua = u2p[0], ub = u2p[1];
      float hv[8] = {ua.x, ua.y, ua.z, ua.w, ub.x, ub.y, ub.z, ub.w};
#pragma unroll
      for (int nn = 0; nn < 2; nn++) {
        float h1f[8];
#pragma unroll
        for (int i = 0; i < 8; i++) h1f[i] = leaky(u1j[nn][i] + hv[i]);
        float accLin = 0.f;
#pragma unroll
        for (int i = 0; i < 8; i++) accLin = fmaf(linp[i], h1f[i], accLin);
        bf16x8 pfrag;
#pragma unroll
        for (int i = 0; i < 8; i++) pfrag[i] = (__bf16)h1f[i];
        float accAbs = 0.f;
#pragma unroll
        for (int tt = 0; tt < 4; tt++) {
          f32x4 ci = {b2q[tt].x, b2q[tt].y, b2q[tt].z, b2q[tt].w};
          f32x4 c = __builtin_amdgcn_mfma_f32_16x16x32_bf16(wfrag[tt], pfrag, ci, 0, 0, 0);
          accAbs = fmaf(fabsf(c[0]), w3q[tt].x, accAbs);
          accAbs = fmaf(fabsf(c[1]), w3q[tt].y, accAbs);
          accAbs = fmaf(fabsf(c[2]), w3q[tt].z, accAbs);
          accAbs = fmaf(fabsf(c[3]), w3q[tt].w, accAbs);
        }
        float red = fmaf(0.495f, accAbs, 0.505f * accLin);
        red += __shfl_xor(red, 16, 64);
        red += __shfl_xor(red, 32, 64);
        if (grp == 0) out[(size_t)(n0 + nn) * SD + mbase + row] = f2bf(red + cst);
      }
    }
  }
}

// ---- bf16 transpose ----
__global__ __launch_bounds__(256) void k_cvtTb(const ushort* __restrict__ srcA, const ushort* __restrict__ srcB,
                                               ushort* __restrict__ dstA, ushort* __restrict__ dstB) {
  __shared__ float T[64][65];
  const ushort* src = blockIdx.z ? srcB : srcA;
  ushort* dst = blockIdx.z ? dstB : dstA;
  int t = threadIdx.x;
  int c0 = blockIdx.x * 64, r0 = blockIdx.y * 64;
  int rr = t >> 2, cc = (t & 3) * 16;
  const uint4* s4 = reinterpret_cast<const uint4*>(src + (size_t)(r0 + rr) * 1024 + c0 + cc);
  uint4 q0 = s4[0], q1 = s4[1];
  uint qs[8] = {q0.x, q0.y, q0.z, q0.w, q1.x, q1.y, q1.z, q1.w};
#pragma unroll
  for (int j = 0; j < 8; j++) {
    T[rr][cc + 2 * j]     = bf2f((ushort)(qs[j] & 0xffffu));
    T[rr][cc + 2 * j + 1] = bf2f((ushort)(qs[j] >> 16));
  }
  __syncthreads();
  uint pk[8];
#pragma unroll
  for (int j = 0; j < 8; j++) {
    uint lo = (uint)f2bf(T[cc + 2 * j][rr]);
    uint hi = (uint)f2bf(T[cc + 2 * j + 1][rr]);
    pk[j] = lo | (hi << 16);
  }
  ushort* dp = dst + (size_t)(c0 + rr) * 1024 + r0 + cc;
  uint4* dp4 = reinterpret_cast<uint4*>(dp);
  dp4[0] = make_uint4(pk[0], pk[1], pk[2], pk[3]);
  dp4[1] = make_uint4(pk[4], pk[5], pk[6], pk[7]);
}

// ---- w1[n] = rowsum(WTW[n]) + rowsum(WTF[n]) ----
__global__ __launch_bounds__(256) void k_colsumT(const ushort* __restrict__ WTW, const ushort* __restrict__ WTF,
                                                 float* __restrict__ w1) {
  int t = threadIdx.x;
  int n = blockIdx.x * 16 + (t >> 4), seg = t & 15;
  const uint4* pa = reinterpret_cast<const uint4*>(WTW + (size_t)n * 1024 + seg * 64);
  const uint4* pf = reinterpret_cast<const uint4*>(WTF + (size_t)n * 1024 + seg * 64);
  float s = 0.f;
#pragma unroll
  for (int q = 0; q < 8; q++) {
    uint4 va = pa[q], vf = pf[q];
    uint u[8] = {va.x, va.y, va.z, va.w, vf.x, vf.y, vf.z, vf.w};
#pragma unroll
    for (int j = 0; j < 8; j++) s += bf2f((ushort)(u[j] & 0xffffu)) + bf2f((ushort)(u[j] >> 16));
  }
  s += __shfl_xor(s, 1, 64);
  s += __shfl_xor(s, 2, 64);
  s += __shfl_xor(s, 4, 64);
  s += __shfl_xor(s, 8, 64);
  if (seg == 0) w1[n] = s;
}

// ---- LN partial sums over xy ----
__global__ __launch_bounds__(256) void k_redsum(const float* __restrict__ X, float* __restrict__ part) {
  int b = blockIdx.y, c = blockIdx.x, t = threadIdx.x;
  const float4* X4 = reinterpret_cast<const float4*>(X + (size_t)b * 131072 + (size_t)c * 4096);
  float s = 0.f, q = 0.f;
#pragma unroll
  for (int k = 0; k < 4; k++) {
    float4 v = X4[t + k * 256];
    s += v.x + v.y + v.z + v.w;
    q += v.x * v.x + v.y * v.y + v.z * v.z + v.w * v.w;
  }
  for (int off = 32; off; off >>= 1) { s += __shfl_down(s, off); q += __shfl_down(q, off); }
  __shared__ float ss[4], qq[4];
  int lane = t & 63, wid = t >> 6;
  if (lane == 0) { ss[wid] = s; qq[wid] = q; }
  __syncthreads();
  if (t == 0) {
    part[(size_t)(b * 32 + c) * 2] = ss[0] + ss[1] + ss[2] + ss[3];
    part[(size_t)(b * 32 + c) * 2 + 1] = qq[0] + qq[1] + qq[2] + qq[3];
  }
}

// ---- initial LN-apply (stats from LNP) + XtY 4x4-tile partials ----
__global__ __launch_bounds__(256) void k_apply0(
    const float* __restrict__ src, const float* __restrict__ g,
    const float* __restrict__ bb, const float* __restrict__ lnp,
    float* __restrict__ Vout, float* __restrict__ Gp, float* __restrict__ sp) {
  int c = blockIdx.x, b = blockIdx.y, t = threadIdx.x;
  __shared__ float sm[2];
  __shared__ __align__(16) float Vs[4096];
  if (t == 0) {
    float s = 0.f, q = 0.f;
    for (int cc = 0; cc < 32; cc++) {
      s += lnp[(size_t)(b * 32 + cc) * 2];
      q += lnp[(size_t)(b * 32 + cc) * 2 + 1];
    }
    float mean = s / 131072.0f;
    sm[0] = mean;
    sm[1] = rsqrtf(q / 131072.0f - mean * mean + EPSc);
  }
  __syncthreads();
  float mean = sm[0], is = sm[1];
  size_t base4 = (size_t)b * 32768 + (size_t)c * 1024;
#pragma unroll
  for (int k = 0; k < 4; k++) {
    int idx = t + k * 256;
    float4 v = reinterpret_cast<const float4*>(src)[base4 + idx];
    float4 gg = reinterpret_cast<const float4*>(g)[c * 1024 + idx];
    float4 bv = reinterpret_cast<const float4*>(bb)[c * 1024 + idx];
    float4 r;
    r.x = (v.x - mean) * is * gg.x + bv.x;
    r.y = (v.y - mean) * is * gg.y + bv.y;
    r.z = (v.z - mean) * is * gg.z + bv.z;
    r.w = (v.w - mean) * is * gg.w + bv.w;
    reinterpret_cast<float4*>(Vout)[base4 + idx] = r;
    reinterpret_cast<float4*>(Vs)[idx] = r;
  }
  __syncthreads();
  int tp = t >> 4, tq = t & 15;
  float a2[4][4] = {};
  for (int k = 0; k < 64; k++) {
    float4 xv = *reinterpret_cast<const float4*>(&Vs[k * 64 + tp * 4]);
    float4 yv = *reinterpret_cast<const float4*>(&Vs[k * 64 + tq * 4]);
    a2[0][0] += xv.x * yv.x; a2[0][1] += xv.x * yv.y; a2[0][2] += xv.x * yv.z; a2[0][3] += xv.x * yv.w;
    a2[1][0] += xv.y * yv.x; a2[1][1] += xv.y * yv.y; a2[1][2] += xv.y * yv.z; a2[1][3] += xv.y * yv.w;
    a2[2][0] += xv.z * yv.x; a2[2][1] += xv.z * yv.y; a2[2][2] += xv.z * yv.z; a2[2][3] += xv.z * yv.w;
    a2[3][0] += xv.w * yv.x; a2[3][1] += xv.w * yv.y; a2[3][2] += xv.w * yv.z; a2[3][3] += xv.w * yv.w;
  }
  float* go = Gp + (size_t)(b * 32 + c) * 4096;
#pragma unroll
  for (int i = 0; i < 4; i++) {
    float4 w = {a2[i][0], a2[i][1], a2[i][2], a2[i][3]};
    *reinterpret_cast<float4*>(&go[(tp * 4 + i) * 64 + tq * 4]) = w;
  }
  if (t < 64) {
    float s = 0.f;
    for (int k = 0; k < 64; k++) s += Vs[k * 64 + t];
    sp[(size_t)(b * 32 + c) * 64 + t] = s;
  }
}

// ---- coalesced partial reduction: G = sum_c Gp[c], sv = sum_c sp[c] (128 blocks) ----
__global__ __launch_bounds__(256) void k_gred(const float* __restrict__ Gp, const float* __restrict__ sp,
                                              float* __restrict__ G, float* __restrict__ sv, int nch) {
  int blk = blockIdx.x, b = blockIdx.y, t = threadIdx.x;
  int idx = blk * 256 + t;
  float a = 0.f;
  for (int c = 0; c < nch; c++) a += Gp[(size_t)(b * nch + c) * 4096 + idx];
  G[(size_t)b * 4096 + idx] = a;
  if (blk == 0 && t < 64) {
    float s = 0.f;
    for (int c = 0; c < nch; c++) s += sp[(size_t)(b * nch + c) * 64 + t];
    sv[b * 64 + t] = s;
  }
}

// ---- A = scale*(E_j G + f_j (x) s); r = scale*(g_j^T G + c_j s); analytic mid-LN stats ----
__global__ __launch_bounds__(256) void k_headsA2(
    const float* __restrict__ G, const float* __restrict__ sv,
    const float* __restrict__ Ep, const float* __restrict__ fp,
    const float* __restrict__ gp, const float* __restrict__ cp,
    int j, float scale, int doStats,
    float* __restrict__ A, float* __restrict__ RVo, float* __restrict__ STAT) {
  int b = blockIdx.x, t = threadIdx.x;
  __shared__ float Es[64 * 65];
  __shared__ __align__(16) float Gs[4096];
  __shared__ __align__(16) float As[4096];
  __shared__ float ss[64], fs[64], gs[64];
  __shared__ float cj;
  __shared__ float redbuf[8];
  const float* e0 = Ep + (size_t)(j * RH) * 4096;
  for (int idx = t; idx < 4096; idx += 256) {
    float e = e0[idx] + e0[idx + 4096] + e0[idx + 8192] + e0[idx + 12288];
    Es[(idx >> 6) * 65 + (idx & 63)] = e;
    Gs[idx] = G[(size_t)b * 4096 + idx];
  }
  if (t < 64) {
    ss[t] = sv[b * 64 + t];
    int h0 = j * RH * 64;
    fs[t] = fp[h0 + t] + fp[h0 + 64 + t] + fp[h0 + 128 + t] + fp[h0 + 192 + t];
    gs[t] = gp[h0 + t] + gp[h0 + 64 + t] + gp[h0 + 128 + t] + gp[h0 + 192 + t];
  }
  if (t == 0) cj = cp[j * RH] + cp[j * RH + 1] + cp[j * RH + 2] + cp[j * RH + 3];
  __syncthreads();
  int c = t >> 2, qb = (t & 3) * 16;
  float fv = fs[c];
  float4 acc[4];
#pragma unroll
  for (int u = 0; u < 4; u++) {
    acc[u].x = fv * ss[qb + u * 4 + 0];
    acc[u].y = fv * ss[qb + u * 4 + 1];
    acc[u].z = fv * ss[qb + u * 4 + 2];
    acc[u].w = fv * ss[qb + u * 4 + 3];
  }
  for (int d = 0; d < 64; d++) {
    float ev = Es[c * 65 + d];
    const float4* gr = reinterpret_cast<const float4*>(&Gs[d * 64 + qb]);
#pragma unroll
    for (int u = 0; u < 4; u++) {
      float4 gv = gr[u];
      acc[u].x += ev * gv.x; acc[u].y += ev * gv.y; acc[u].z += ev * gv.z; acc[u].w += ev * gv.w;
    }
  }
  float* ao = A + (size_t)b * 4096 + c * 64 + qb;
#pragma unroll
  for (int u = 0; u < 4; u++) {
    float4 v = acc[u];
    v.x *= scale; v.y *= scale; v.z *= scale; v.w *= scale;
    reinterpret_cast<float4*>(ao)[u] = v;
    *reinterpret_cast<float4*>(&As[c * 64 + qb + u * 4]) = v;
  }
  float rv_t = 0.f;
  if (t < 64) {
    float r = cj * ss[t];
    for (int d = 0; d < 64; d++) r += gs[d] * Gs[d * 64 + t];
    r *= scale;
    RVo[b * 64 + t] = r;
    rv_t = r;
  }
  if (!doStats) return;
  __syncthreads();
  float4 h[4] = {};
  for (int d = 0; d < 64; d++) {
    float gvv = Gs[c * 64 + d];
    const float4* ar = reinterpret_cast<const float4*>(&As[d * 64 + qb]);
#pragma unroll
    for (int u = 0; u < 4; u++) {
      float4 av = ar[u];
      h[u].x += gvv * av.x; h[u].y += gvv * av.y; h[u].z += gvv * av.z; h[u].w += gvv * av.w;
    }
  }
  float tp_ = 0.f;
#pragma unroll
  for (int u = 0; u < 4; u++) {
    float4 a = *reinterpret_cast<const float4*>(&As[c * 64 + qb + u * 4]);
    tp_ += a.x * h[u].x + a.y * h[u].y + a.z * h[u].z + a.w * h[u].w;
  }
  tp_ += __shfl_xor(tp_, 1, 64);  tp_ += __shfl_xor(tp_, 2, 64);
  tp_ += __shfl_xor(tp_, 4, 64);  tp_ += __shfl_xor(tp_, 8, 64);
  tp_ += __shfl_xor(tp_, 16, 64); tp_ += __shfl_xor(tp_, 32, 64);
  if ((t & 63) == 0) redbuf[t >> 6] = tp_;
  if (t < 64) {
    float t1 = 0.f;
    for (int d = 0; d < 64; d++) t1 += ss[d] * As[d * 64 + t];
    float s1 = t1, sr = rv_t, sr2 = rv_t * rv_t, srt = rv_t * t1;
#pragma unroll
    for (int off = 1; off < 64; off <<= 1) {
      s1  += __shfl_xor(s1, off, 64);
      sr  += __shfl_xor(sr, off, 64);
      sr2 += __shfl_xor(sr2, off, 64);
      srt += __shfl_xor(srt, off, 64);
    }
    if (t == 0) { redbuf[4] = s1; redbuf[5] = sr; redbuf[6] = sr2; redbuf[7] = srt; }
  }
  __syncthreads();
  if (t == 0) {
    float tr = redbuf[0] + redbuf[1] + redbuf[2] + redbuf[3];
    float smid = redbuf[4] + 2048.0f * redbuf[5];
    float mu = smid / 131072.0f;
    float e2 = (tr + 2.0f * redbuf[7] + 2048.0f * redbuf[6]) / 131072.0f;
    STAT[b * 2] = mu;
    STAT[b * 2 + 1] = rsqrtf(e2 - mu * mu + EPSc);
  }
}

// ---- fused: mid = V A + 1 r^T; LN via analytic stats; +V residual; write V'; XtY partials ----
__global__ __launch_bounds__(256) void k_midapply(
    float* __restrict__ V, const float* __restrict__ A,
    const float* __restrict__ RVv, const float* __restrict__ STAT,
    const float* __restrict__ g, const float* __restrict__ bb,
    const float* __restrict__ Yext,
    float* __restrict__ Gp, float* __restrict__ sp, int nchG) {
  int blk = blockIdx.x, b = blockIdx.y, t = threadIdx.x;
  __shared__ __align__(16) float As[4096];
  __shared__ __align__(16) float Vs[4096];
  __shared__ __align__(16) float Ys[4096];
  __shared__ float rs[64];
  __shared__ float sm[2];
  const float4* A4 = reinterpret_cast<const float4*>(A + (size_t)b * 4096);
#pragma unroll
  for (int k = 0; k < 4; k++) reinterpret_cast<float4*>(As)[t + k * 256] = A4[t + k * 256];
  if (t < 64) rs[t] = RVv[b * 64 + t];
  if (t == 0) { sm[0] = STAT[b * 2]; sm[1] = STAT[b * 2 + 1]; }
  bool doG = (blk < nchG);
  if (Yext != nullptr && doG) {
    size_t yb = (size_t)b * 32768 + (size_t)blk * 1024;
#pragma unroll
    for (int k = 0; k < 4; k++)
      reinterpret_cast<float4*>(Ys)[t + k * 256] = reinterpret_cast<const float4*>(Yext)[yb + t + k * 256];
  }
  __syncthreads();
  float mu = sm[0], is = sm[1];
  int rl = t >> 2, qb = (t & 3) * 16;
  int row = blk * 64 + rl;
  float* vr = V + (size_t)b * 131072 + (size_t)row * 64;
  float4 acc[4];
#pragma unroll
  for (int u = 0; u < 4; u++) {
    acc[u].x = rs[qb + u * 4 + 0]; acc[u].y = rs[qb + u * 4 + 1];
    acc[u].z = rs[qb + u * 4 + 2]; acc[u].w = rs[qb + u * 4 + 3];
  }
  for (int c = 0; c < 64; c++) {
    float vv = vr[c];
    const float4* ar = reinterpret_cast<const float4*>(&As[c * 64 + qb]);
#pragma unroll
    for (int u = 0; u < 4; u++) {
      float4 av = ar[u];
      acc[u].x += vv * av.x; acc[u].y += vv * av.y; acc[u].z += vv * av.z; acc[u].w += vv * av.w;
    }
  }
  const float4* g4 = reinterpret_cast<const float4*>(g + (size_t)row * 64 + qb);
  const float4* b4 = reinterpret_cast<const float4*>(bb + (size_t)row * 64 + qb);
  const float4* vq = reinterpret_cast<const float4*>(vr + qb);
  float4* vo = reinterpret_cast<float4*>(vr + qb);
#pragma unroll
  for (int u = 0; u < 4; u++) {
    float4 gg = g4[u], bv = b4[u], av = vq[u];
    float4 r;
    r.x = (acc[u].x - mu) * is * gg.x + bv.x + av.x;
    r.y = (acc[u].y - mu) * is * gg.y + bv.y + av.y;
    r.z = (acc[u].z - mu) * is * gg.z + bv.z + av.z;
    r.w = (acc[u].w - mu) * is * gg.w + bv.w + av.w;
    vo[u] = r;
    *reinterpret_cast<float4*>(&Vs[rl * 64 + qb + u * 4]) = r;
  }
  __syncthreads();
  if (!doG) return;
  const float* Yp = (Yext != nullptr) ? Ys : Vs;
  int tp = t >> 4, tq = t & 15;
  float a2[4][4] = {};
  for (int k = 0; k < 64; k++) {
    float4 xv = *reinterpret_cast<const float4*>(&Vs[k * 64 + tp * 4]);
    float4 yv = *reinterpret_cast<const float4*>(&Yp[k * 64 + tq * 4]);
    a2[0][0] += xv.x * yv.x; a2[0][1] += xv.x * yv.y; a2[0][2] += xv.x * yv.z; a2[0][3] += xv.x * yv.w;
    a2[1][0] += xv.y * yv.x; a2[1][1] += xv.y * yv.y; a2[1][2] += xv.y * yv.z; a2[1][3] += xv.y * yv.w;
    a2[2][0] += xv.z * yv.x; a2[2][1] += xv.z * yv.y; a2[2][2] += xv.z * yv.z; a2[2][3] += xv.z * yv.w;
    a2[3][0] += xv.w * yv.x; a2[3][1] += xv.w * yv.y; a2[3][2] += xv.w * yv.z; a2[3][3] += xv.w * yv.w;
  }
  float* go = Gp + (size_t)(b * nchG + blk) * 4096;
#pragma unroll
  for (int i = 0; i < 4; i++) {
    float4 w = {a2[i][0], a2[i][1], a2[i][2], a2[i][3]};
    *reinterpret_cast<float4*>(&go[(tp * 4 + i) * 64 + tq * 4]) = w;
  }
  if (t < 64) {
    float s = 0.f;
    for (int k = 0; k < 64; k++) s += Yp[k * 64 + t];
    sp[(size_t)(b * nchG + blk) * 64 + t] = s;
  }
}

// ---- k_y: ZT[b*64+q][z*1024+m] = bf16(V A); LDS-staged coalesced uint4 stores ----
__global__ __launch_bounds__(256) void k_y(const float* __restrict__ V, const float* __restrict__ A,
                                           ushort* __restrict__ ZT) {
  int blk = blockIdx.x, b = blockIdx.y, z = blockIdx.z, t = threadIdx.x;
  __shared__ __align__(16) float As[4096];
  __shared__ ushort Zs[64][36];
  const float4* A4 = reinterpret_cast<const float4*>(A + (size_t)b * 4096);
#pragma unroll
  for (int k = 0; k < 4; k++) reinterpret_cast<float4*>(As)[t + k * 256] = A4[t + k * 256];
  __syncthreads();
  int ml = t >> 3, qb = (t & 7) * 8;
  int m = blk * 32 + ml;
  const float* vr = V + (size_t)b * 131072 + (size_t)(z * 1024 + m) * 64;
  float4 acc[2] = {};
  for (int c = 0; c < 64; c++) {
    float vv = vr[c];
    const float4* ar = reinterpret_cast<const float4*>(&As[c * 64 + qb]);
#pragma unroll
    for (int u = 0; u < 2; u++) {
      float4 av = ar[u];
      acc[u].x += vv * av.x; acc[u].y += vv * av.y; acc[u].z += vv * av.z; acc[u].w += vv * av.w;
    }
  }
  Zs[qb + 0][ml] = f2bf(acc[0].x); Zs[qb + 1][ml] = f2bf(acc[0].y);
  Zs[qb + 2][ml] = f2bf(acc[0].z); Zs[qb + 3][ml] = f2bf(acc[0].w);
  Zs[qb + 4][ml] = f2bf(acc[1].x); Zs[qb + 5][ml] = f2bf(acc[1].y);
  Zs[qb + 6][ml] = f2bf(acc[1].z); Zs[qb + 7][ml] = f2bf(acc[1].w);
  __syncthreads();
  int rowq = t >> 2, seg = t & 3;
  const ushort* srcp = &Zs[rowq][seg * 8];
  uint p0 = (uint)srcp[0] | ((uint)srcp[1] << 16);
  uint p1 = (uint)srcp[2] | ((uint)srcp[3] << 16);
  uint p2 = (uint)srcp[4] | ((uint)srcp[5] << 16);
  uint p3 = (uint)srcp[6] | ((uint)srcp[7] << 16);
  ushort* dp = ZT + (size_t)(b * 64 + rowq) * 2048 + (size_t)z * 1024 + blk * 32 + seg * 8;
  *reinterpret_cast<uint4*>(dp) = make_uint4(p0, p1, p2, p3);
}

// ---- MFMA final GEMM ----
__global__ __launch_bounds__(256) void k_final_mfma(const ushort* __restrict__ WTW,
                                                    const ushort* __restrict__ WTF,
                                                    const ushort* __restrict__ ZT,
                                                    float* __restrict__ P0, float* __restrict__ P1,
                                                    float* __restrict__ P2, float* __restrict__ P3) {
  int tn = blockIdx.x, tb = blockIdx.y, kz = blockIdx.z, t = threadIdx.x;
  int lane = t & 63, w = t >> 6;
  int wn = w & 1, wb = w >> 1;
  int r = lane & 15, g = lane >> 4;
  int nrow = tn * 32 + wn * 16 + r;
  int bi0 = tb * 64 + wb * 32 + r;
  const ushort* wbase = (kz < 2) ? WTW : WTF;
  const ushort* wp = wbase + (size_t)nrow * 1024 + (kz & 1) * 512 + g * 8;
  const ushort* zp0 = ZT + (size_t)bi0 * 2048 + kz * 512 + g * 8;
  const ushort* zp1 = zp0 + 16 * 2048;
  f32x4 a0 = {0.f, 0.f, 0.f, 0.f}, a1 = a0;
#pragma unroll 4
  for (int ks = 0; ks < 512; ks += 32) {
    bf16x8 fa  = *reinterpret_cast<const bf16x8*>(wp + ks);
    bf16x8 fb0 = *reinterpret_cast<const bf16x8*>(zp0 + ks);
    bf16x8 fb1 = *reinterpret_cast<const bf16x8*>(zp1 + ks);
    a0 = __builtin_amdgcn_mfma_f32_16x16x32_bf16(fa, fb0, a0, 0, 0, 0);
    a1 = __builtin_amdgcn_mfma_f32_16x16x32_bf16(fa, fb1, a1, 0, 0, 0);
  }
  float* P = kz == 0 ? P0 : kz == 1 ? P1 : kz == 2 ? P2 : P3;
  int nbase = tn * 32 + wn * 16 + g * 4;
  int bib = tb * 64 + wb * 32 + r;
#pragma unroll
  for (int rr = 0; rr < 4; rr++) {
    P[(size_t)(nbase + rr) * 512 + bib]      = a0[rr];
    P[(size_t)(nbase + rr) * 512 + bib + 16] = a1[rr];
  }
}

// ---- out = CFINAL * (P0+P1+P2+P3 + w1[n]*RV[b][i']) ----
__global__ __launch_bounds__(256) void k_final_red(const float* __restrict__ P0, const float* __restrict__ P1,
                                                   const float* __restrict__ P2, const float* __restrict__ P3,
                                                   const float* __restrict__ w1,
                                                   const float* __restrict__ RV, float* __restrict__ out) {
  int idx4 = blockIdx.x * 256 + threadIdx.x;
  int i4p = idx4 & 15;
  int n = (idx4 >> 4) & 1023;
  int b = idx4 >> 14;
  int pidx = n * 128 + b * 16 + i4p;
  float4 a0 = reinterpret_cast<const float4*>(P0)[pidx];
  float4 a1 = reinterpret_cast<const float4*>(P1)[pidx];
  float4 a2 = reinterpret_cast<const float4*>(P2)[pidx];
  float4 a3 = reinterpret_cast<const float4*>(P3)[pidx];
  float4 d = reinterpret_cast<const float4*>(RV + (size_t)b * 64)[i4p];
  float wv = w1[n];
  float4 r;
  r.x = CFINAL * (a0.x + a1.x + a2.x + a3.x + wv * d.x);
  r.y = CFINAL * (a0.y + a1.y + a2.y + a3.y + wv * d.y);
  r.z = CFINAL * (a0.z + a1.z + a2.z + a3.z + wv * d.z);
  r.w = CFINAL * (a0.w + a1.w + a2.w + a3.w + wv * d.w);
  reinterpret_cast<float4*>(out)[idx4] = r;
}

extern "C" void kernel_launch(void* const* d_in, const int* in_sizes, int n_in,
                              void* d_out, int out_size, void* d_ws, size_t ws_size,
                              hipStream_t stream) {
  (void)in_sizes; (void)n_in; (void)out_size;
  const float* xy  = (const float*)d_in[1];
  const float* kW1 = (const float*)d_in[3];
  const float* kb1 = (const float*)d_in[4];
  const float* kW2 = (const float*)d_in[5];
  const float* kb2 = (const float*)d_in[6];
  const float* kW3 = (const float*)d_in[7];
  const float* kb3 = (const float*)d_in[8];
  const float* fW1 = (const float*)d_in[9];
  const float* fb1 = (const float*)d_in[10];
  const float* fW2 = (const float*)d_in[11];
  const float* fb2 = (const float*)d_in[12];
  const float* fW3 = (const float*)d_in[13];
  const float* fb3 = (const float*)d_in[14];
  const float* Wq  = (const float*)d_in[15];
  const float* bq  = (const float*)d_in[16];
  const float* Wk  = (const float*)d_in[17];
  const float* bk  = (const float*)d_in[18];
  const float* lng = (const float*)d_in[19];
  const float* lnb = (const float*)d_in[20];
  float* ws = (float*)d_ws;
  float* out = (float*)d_out;
  if (ws_size < WS_FLOATS * sizeof(float)) return;  // visible failure, no OOB

  float* V   = ws + OFF_V;
  float* U1K = ws + OFF_U1K;
  float* U2K = ws + OFF_U2K;
  float* U1F = ws + OFF_U1F;
  float* U2F = ws + OFF_U2F;
  float* GPb = ws + OFF_GP;
  float* SPb = ws + OFF_SP;
  float* LNP = ws + OFF_LNP;
  float* W1v = ws + OFF_W1;
  // overlays
  float* G    = ws + OFF_U1K;             // 32768 (U tables dead after k_mlp2)
  float* SV   = ws + OFF_U1F;             // 512
  float* A    = ws + OFF_A;
  float* RV   = ws + OFF_RV;
  float* STAT = ws + OFF_LNP;
  ushort* Wbf  = (ushort*)(ws + OFF_W);
  ushort* WTW  = (ushort*)(ws + OFF_W + 524288);
  ushort* Wfbf = (ushort*)(ws + OFF_WF);
  ushort* WTF  = (ushort*)(ws + OFF_WF + 524288);
  ushort* ZT   = (ushort*)(ws + OFF_MID);
  float* Ep   = ws + OFF_ZU;
  float* Fp   = ws + OFF_ZU + 49152;
  float* Gpp  = ws + OFF_ZU + 49920;
  float* Cp   = ws + OFF_ZU + 50688;
  float* LIN  = ws + OFF_ZU + LIN_OFF;    // LINK[32], LINF[32], CSTK, CSTF
  float* P0   = ws + OFF_GP;
  float* P1   = ws + OFF_GP + 524288;
  float* P2   = ws + OFF_MID + 524288;
  float* P3   = ws + OFF_ZU;

  k_prep<<<dim3(16), dim3(256), 0, stream>>>(kW1, kb1, fW1, fb1, U1K, U2K, U1F, U2F,
                                             kW2, kW3, kb2, fW2, fW3, fb2, LIN,
                                             Wq, bq, Wk, bk, Ep, Fp, Gpp, Cp);
  k_mlp2<<<dim3(1024, 2), dim3(256), 0, stream>>>(U1K, U2K, kW2, kb2, kW3, kb3,
                                                  U1F, U2F, fW2, fb2, fW3, fb3, LIN, Wbf, Wfbf);
  k_cvtTb<<<dim3(16, 16, 2), dim3(256), 0, stream>>>(Wbf, Wfbf, WTW, WTF);
  k_colsumT<<<dim3(64), dim3(256), 0, stream>>>(WTW, WTF, W1v);

  k_redsum<<<dim3(32, 8), dim3(256), 0, stream>>>(xy, LNP);
  k_apply0<<<dim3(32, 8), dim3(256), 0, stream>>>(xy, lng, lnb, LNP, V, GPb, SPb);

  for (int j = 0; j < 2; j++) {
    k_gred<<<dim3(16, 8), dim3(256), 0, stream>>>(GPb, SPb, G, SV, 32);
    k_headsA2<<<dim3(8), dim3(256), 0, stream>>>(G, SV, Ep, Fp, Gpp, Cp, j, DXDYf * SCALEf, 1,
                                                 A, RV, STAT);
    k_midapply<<<dim3(32, 8), dim3(256), 0, stream>>>(
        V, A, RV, STAT, lng + (size_t)(j + 1) * 131072, lnb + (size_t)(j + 1) * 131072,
        (j == 1) ? xy : nullptr, GPb, SPb, (j == 1) ? 16 : 32);
  }
  k_gred<<<dim3(16, 8), dim3(256), 0, stream>>>(GPb, SPb, G, SV, 16);
  k_headsA2<<<dim3(8), dim3(256), 0, stream>>>(G, SV, Ep, Fp, Gpp, Cp, 2, 1.0f, 0, A, RV, STAT);
  k_y<<<dim3(32, 8, 2), dim3(256), 0, stream>>>(V, A, ZT);
  k_final_mfma<<<dim3(32, 8, 4), dim3(256), 0, stream>>>(WTW, WTF, ZT, P0, P1, P2, P3);
  k_final_red<<<dim3(512), dim3(256), 0, stream>>>(P0, P1, P2, P3, W1v, RV, out);
}

// Round 13
// 181.403 us; speedup vs baseline: 2.6141x; 1.0543x over previous
//
#include <hip/hip_runtime.h>

namespace {
constexpr int SD = 1024;           // D
constexpr int TD = 2048;           // 2D
constexpr int BATCH = 8;
constexpr int RH = 4;
constexpr float EPSc = 1e-5f;
constexpr float DXf = 2.0f / 31.0f;
constexpr float DXDYf = DXf * DXf;
constexpr float SCALEf = 0.125f;
constexpr float CFINAL = DXDYf * DXDYf * SCALEf;

// workspace offsets (floats)
constexpr size_t OFF_V   = 0;
constexpr size_t OFF_MID = OFF_V   + (size_t)BATCH * TD * 64;   // 1048576
constexpr size_t OFF_W   = OFF_MID + (size_t)BATCH * TD * 64;
constexpr size_t OFF_WF  = OFF_W   + (size_t)SD * SD;
constexpr size_t OFF_U1K = OFF_WF  + (size_t)SD * SD;
constexpr size_t OFF_U2K = OFF_U1K + SD * 32;
constexpr size_t OFF_U1F = OFF_U2K + SD * 32;
constexpr size_t OFF_U2F = OFF_U1F + SD * 32;
constexpr size_t OFF_GP  = OFF_U2F + SD * 32;                    // 8*32*4096
constexpr size_t OFF_SP  = OFF_GP  + (size_t)BATCH * 32 * 4096;  // 8*32*64
constexpr size_t OFF_A   = OFF_SP  + BATCH * 32 * 64;            // A matrix (8x4096)
constexpr size_t OFF_RV  = OFF_A   + BATCH * 4096;               // RV (8x64)
constexpr size_t OFF_LNP = OFF_RV  + BATCH * 64;                 // LNP; later STAT
constexpr size_t OFF_ZU  = OFF_LNP + BATCH * 32 * 2;             // Ep region
constexpr size_t OFF_ZF  = OFF_ZU  + (size_t)SD * 512;
constexpr size_t OFF_W1  = OFF_ZF  + (size_t)SD * 512;
constexpr size_t OFF_CS  = OFF_W1  + SD;
constexpr size_t WS_FLOATS = OFF_CS + 16 * SD;
// overlays:
//  G->U1K, SV->U1F  (U tables dead after k_mlp2)
//  Wbf->OFF_W lo, WTW->OFF_W+524288; Wfbf->OFF_WF lo, WTF->OFF_WF+524288
//  ZT->MID lo
//  Ep/fp/gp/cp/LIN -> OFF_ZU; STAT->OFF_LNP
constexpr size_t LIN_OFF = 50704;  // within ZU region: LINK[32], LINF[32], CSTK, CSTF
} // namespace

typedef __bf16 bf16x8 __attribute__((ext_vector_type(8)));
typedef float f32x4 __attribute__((ext_vector_type(4)));

__device__ __forceinline__ float leaky(float x) { return fmaxf(x, 0.01f * x); }
__device__ __forceinline__ float gxv(int i) { return -1.0f + (2.0f / 31.0f) * (float)i; }
__device__ __forceinline__ ushort f2bf(float x) { union { __bf16 b; ushort u; } v; v.b = (__bf16)x; return v.u; }
__device__ __forceinline__ float bf2f(ushort u) { return __uint_as_float(((uint)u) << 16); }

// ---- merged: blocks 0-3 u-tables(+lin/cst); 4-15 head-collapse; 16-271 xy LN redsum ----
__global__ __launch_bounds__(256) void k_prep(
    const float* __restrict__ kW1, const float* __restrict__ kb1,
    const float* __restrict__ fW1, const float* __restrict__ fb1,
    float* __restrict__ u1k, float* __restrict__ u2k,
    float* __restrict__ u1f, float* __restrict__ u2f,
    const float* __restrict__ kW2, const float* __restrict__ kW3, const float* __restrict__ kb2,
    const float* __restrict__ fW2, const float* __restrict__ fW3, const float* __restrict__ fb2,
    float* __restrict__ LIN,
    const float* __restrict__ Wq, const float* __restrict__ bq,
    const float* __restrict__ Wk, const float* __restrict__ bk,
    float* __restrict__ Ep, float* __restrict__ fp,
    float* __restrict__ gp, float* __restrict__ cp,
    const float* __restrict__ xy, float* __restrict__ part) {
  __shared__ __align__(16) float Wqs[4096];
  __shared__ float Wks[64 * 65];
  __shared__ float bqs[64], bks[64];
  __shared__ float ss4[4], qq4[4];
  int blk = blockIdx.x, t = threadIdx.x;
  if (blk >= 16) {
    // LN partial sums over xy: 256 blocks = (b,c)
    int idx = blk - 16;
    int b = idx >> 5, c = idx & 31;
    const float4* X4 = reinterpret_cast<const float4*>(xy + (size_t)b * 131072 + (size_t)c * 4096);
    float s = 0.f, q = 0.f;
#pragma unroll
    for (int k = 0; k < 4; k++) {
      float4 v = X4[t + k * 256];
      s += v.x + v.y + v.z + v.w;
      q += v.x * v.x + v.y * v.y + v.z * v.z + v.w * v.w;
    }
    for (int off = 32; off; off >>= 1) { s += __shfl_down(s, off); q += __shfl_down(q, off); }
    int lane = t & 63, wid = t >> 6;
    if (lane == 0) { ss4[wid] = s; qq4[wid] = q; }
    __syncthreads();
    if (t == 0) {
      part[(size_t)(b * 32 + c) * 2] = ss4[0] + ss4[1] + ss4[2] + ss4[3];
      part[(size_t)(b * 32 + c) * 2 + 1] = qq4[0] + qq4[1] + qq4[2] + qq4[3];
    }
    return;
  }
  if (blk < 4) {
    int n = blk * 256 + t;
    float ga = gxv(n >> 5), gb = gxv(n & 31);
    for (int j = 0; j < 32; j++) {
      u1k[n * 32 + j] = ga * kW1[j] + gb * kW1[32 + j] + kb1[j];
      u2k[n * 32 + j] = gb * kW1[64 + j] + ga * kW1[96 + j];
      u1f[n * 32 + j] = ga * fW1[j] + gb * fW1[32 + j] + fb1[j];
      u2f[n * 32 + j] = gb * fW1[64 + j] + ga * fW1[96 + j];
    }
    if (blk < 2 && t < 33) {
      const float* W2 = blk ? fW2 : kW2;
      const float* W3 = blk ? fW3 : kW3;
      const float* b2 = blk ? fb2 : kb2;
      if (t < 32) {
        float s = 0.f;
        for (int o = 0; o < 64; o++) s += W2[t * 64 + o] * W3[o];
        LIN[blk * 32 + t] = s;
      } else {
        float s = 0.f;
        for (int o = 0; o < 64; o++) s += b2[o] * W3[o];
        LIN[64 + blk] = s;   // cstraw
      }
    }
    return;
  }
  int h = blk - 4;  // 0..11
  const float* wqb = Wq + (size_t)h * 4096;
  const float* wkb = Wk + (size_t)h * 4096;
  for (int idx = t; idx < 4096; idx += 256) {
    Wqs[idx] = wqb[idx];
    Wks[(idx >> 6) * 65 + (idx & 63)] = wkb[idx];
  }
  if (t < 64) { bqs[t] = bq[h * 64 + t]; bks[t] = bk[h * 64 + t]; }
  __syncthreads();
  int cpp = t & 63, cb = (t >> 6) * 16;
  float acc[16];
#pragma unroll
  for (int u = 0; u < 16; u++) acc[u] = 0.f;
  for (int k = 0; k < 64; k++) {
    float wkv = Wks[cpp * 65 + k];
#pragma unroll
    for (int u = 0; u < 16; u++) acc[u] += Wqs[(cb + u) * 64 + k] * wkv;
  }
  float* eo = Ep + (size_t)h * 4096;
#pragma unroll
  for (int u = 0; u < 16; u++) eo[(cb + u) * 64 + cpp] = acc[u];
  if (t < 64) {
    float f = 0.f, gg = 0.f;
    for (int k = 0; k < 64; k++) {
      f  += Wqs[t * 64 + k] * bks[k];
      gg += Wks[t * 65 + k] * bqs[k];
    }
    fp[h * 64 + t] = f;
    gp[h * 64 + t] = gg;
    float ca = bqs[t] * bks[t];
    ca += __shfl_xor(ca, 1, 64);
    ca += __shfl_xor(ca, 2, 64);
    ca += __shfl_xor(ca, 4, 64);
    ca += __shfl_xor(ca, 8, 64);
    ca += __shfl_xor(ca, 16, 64);
    ca += __shfl_xor(ca, 32, 64);
    if (t == 0) cp[h] = ca;
  }
}

// ---- MFMA edge-MLP: 2 n-rows x 512 m per block; exact leaky split epilogue ----
__global__ __launch_bounds__(256) void k_mlp2(
    const float* __restrict__ u1k, const float* __restrict__ u2k,
    const float* __restrict__ kW2, const float* __restrict__ kb2,
    const float* __restrict__ kW3, const float* __restrict__ kb3,
    const float* __restrict__ u1f, const float* __restrict__ u2f,
    const float* __restrict__ fW2, const float* __restrict__ fb2,
    const float* __restrict__ fW3, const float* __restrict__ fb3,
    const float* __restrict__ LIN,
    ushort* __restrict__ outK, ushort* __restrict__ outF) {
  const int which = blockIdx.y;
  const float* u1 = which ? u1f : u1k;
  const float* u2 = which ? u2f : u2k;
  const float* W2 = which ? fW2 : kW2;
  const float* b2 = which ? fb2 : kb2;
  const float* W3 = which ? fW3 : kW3;
  const float* b3 = which ? fb3 : kb3;
  ushort* out = which ? outF : outK;

  const int t = threadIdx.x;
  const int lane = t & 63, wave = t >> 6;
  const int row = lane & 15, grp = lane >> 4;
  const int n0 = (blockIdx.x >> 1) * 2;
  const int mh = blockIdx.x & 1;

  bf16x8 wfrag[4];
  float4 b2q[4], w3q[4];
#pragma unroll
  for (int tt = 0; tt < 4; tt++) {
#pragma unroll
    for (int i = 0; i < 8; i++) wfrag[tt][i] = (__bf16)W2[(grp * 8 + i) * 64 + tt * 16 + row];
    b2q[tt] = *reinterpret_cast<const float4*>(b2 + tt * 16 + grp * 4);
    w3q[tt] = *reinterpret_cast<const float4*>(W3 + tt * 16 + grp * 4);
  }
  float4 l0 = *reinterpret_cast<const float4*>(LIN + which * 32 + grp * 8);
  float4 l1 = *reinterpret_cast<const float4*>(LIN + which * 32 + grp * 8 + 4);
  float linp[8] = {l0.x, l0.y, l0.z, l0.w, l1.x, l1.y, l1.z, l1.w};
  const float cst = 0.505f * LIN[64 + which] + b3[0];

  float u1j[2][8];
#pragma unroll
  for (int nn = 0; nn < 2; nn++)
#pragma unroll
    for (int i = 0; i < 8; i++) u1j[nn][i] = u1[(n0 + nn) * 32 + grp * 8 + i];

#pragma unroll
  for (int chunk = 0; chunk < 2; chunk++) {
#pragma unroll
    for (int st = 0; st < 4; st++) {
      int mbase = mh * 512 + chunk * 256 + wave * 64 + st * 16;
      int m = mbase + row;
      const float4* u2p = reinterpret_cast<const float4*>(u2 + (size_t)m * 32 + grp * 8);
      float4 ua = u2p[0], ub = u2p[1];
      float hv[8] = {ua.x, ua.y, ua.z, ua.w, ub.x, ub.y, ub.z, ub.w};
#pragma unroll
      for (int nn = 0; nn < 2; nn++) {
        float h1f[8];
#pragma unroll
        for (int i = 0; i < 8; i++) h1f[i] = leaky(u1j[nn][i] + hv[i]);
        float accLin = 0.f;
#pragma unroll
        for (int i = 0; i < 8; i++) accLin = fmaf(linp[i], h1f[i], accLin);
        bf16x8 pfrag;
#pragma unroll
        for (int i = 0; i < 8; i++) pfrag[i] = (__bf16)h1f[i];
        float accAbs = 0.f;
#pragma unroll
        for (int tt = 0; tt < 4; tt++) {
          f32x4 ci = {b2q[tt].x, b2q[tt].y, b2q[tt].z, b2q[tt].w};
          f32x4 c = __builtin_amdgcn_mfma_f32_16x16x32_bf16(wfrag[tt], pfrag, ci, 0, 0, 0);
          accAbs = fmaf(fabsf(c[0]), w3q[tt].x, accAbs);
          accAbs = fmaf(fabsf(c[1]), w3q[tt].y, accAbs);
          accAbs = fmaf(fabsf(c[2]), w3q[tt].z, accAbs);
          accAbs = fmaf(fabsf(c[3]), w3q[tt].w, accAbs);
        }
        float red = fmaf(0.495f, accAbs, 0.505f * accLin);
        red += __shfl_xor(red, 16, 64);
        red += __shfl_xor(red, 32, 64);
        if (grp == 0) out[(size_t)(n0 + nn) * SD + mbase + row] = f2bf(red + cst);
      }
    }
  }
}

// ---- merged: blocks 0-511 bf16 transpose; 512-767 LN-apply + XtY partials ----
__global__ __launch_bounds__(256) void k_cvtapply(
    const ushort* __restrict__ srcA, const ushort* __restrict__ srcB,
    ushort* __restrict__ dstA, ushort* __restrict__ dstB,
    const float* __restrict__ src, const float* __restrict__ g,
    const float* __restrict__ bb, const float* __restrict__ lnp,
    float* __restrict__ Vout, float* __restrict__ Gp, float* __restrict__ sp) {
  __shared__ float T[64][65];
  __shared__ __align__(16) float Vs[4096];
  __shared__ float sm[2];
  int blk = blockIdx.x, t = threadIdx.x;
  if (blk < 512) {
    int bx = blk & 15, by = (blk >> 4) & 15, bz = blk >> 8;
    const ushort* srcp = bz ? srcB : srcA;
    ushort* dst = bz ? dstB : dstA;
    int c0 = bx * 64, r0 = by * 64;
    int rr = t >> 2, cc = (t & 3) * 16;
    const uint4* s4 = reinterpret_cast<const uint4*>(srcp + (size_t)(r0 + rr) * 1024 + c0 + cc);
    uint4 q0 = s4[0], q1 = s4[1];
    uint qs[8] = {q0.x, q0.y, q0.z, q0.w, q1.x, q1.y, q1.z, q1.w};
#pragma unroll
    for (int j = 0; j < 8; j++) {
      T[rr][cc + 2 * j]     = bf2f((ushort)(qs[j] & 0xffffu));
      T[rr][cc + 2 * j + 1] = bf2f((ushort)(qs[j] >> 16));
    }
    __syncthreads();
    uint pk[8];
#pragma unroll
    for (int j = 0; j < 8; j++) {
      uint lo = (uint)f2bf(T[cc + 2 * j][rr]);
      uint hi = (uint)f2bf(T[cc + 2 * j + 1][rr]);
      pk[j] = lo | (hi << 16);
    }
    ushort* dp = dst + (size_t)(c0 + rr) * 1024 + r0 + cc;
    uint4* dp4 = reinterpret_cast<uint4*>(dp);
    dp4[0] = make_uint4(pk[0], pk[1], pk[2], pk[3]);
    dp4[1] = make_uint4(pk[4], pk[5], pk[6], pk[7]);
    return;
  }
  int idx2 = blk - 512;
  int c = idx2 & 31, b = idx2 >> 5;
  if (t == 0) {
    float s = 0.f, q = 0.f;
    for (int cc = 0; cc < 32; cc++) {
      s += lnp[(size_t)(b * 32 + cc) * 2];
      q += lnp[(size_t)(b * 32 + cc) * 2 + 1];
    }
    float mean = s / 131072.0f;
    sm[0] = mean;
    sm[1] = rsqrtf(q / 131072.0f - mean * mean + EPSc);
  }
  __syncthreads();
  float mean = sm[0], is = sm[1];
  size_t base4 = (size_t)b * 32768 + (size_t)c * 1024;
#pragma unroll
  for (int k = 0; k < 4; k++) {
    int idx = t + k * 256;
    float4 v = reinterpret_cast<const float4*>(src)[base4 + idx];
    float4 gg = reinterpret_cast<const float4*>(g)[c * 1024 + idx];
    float4 bv = reinterpret_cast<const float4*>(bb)[c * 1024 + idx];
    float4 r;
    r.x = (v.x - mean) * is * gg.x + bv.x;
    r.y = (v.y - mean) * is * gg.y + bv.y;
    r.z = (v.z - mean) * is * gg.z + bv.z;
    r.w = (v.w - mean) * is * gg.w + bv.w;
    reinterpret_cast<float4*>(Vout)[base4 + idx] = r;
    reinterpret_cast<float4*>(Vs)[idx] = r;
  }
  __syncthreads();
  int tp = t >> 4, tq = t & 15;
  float a2[4][4] = {};
  for (int k = 0; k < 64; k++) {
    float4 xv = *reinterpret_cast<const float4*>(&Vs[k * 64 + tp * 4]);
    float4 yv = *reinterpret_cast<const float4*>(&Vs[k * 64 + tq * 4]);
    a2[0][0] += xv.x * yv.x; a2[0][1] += xv.x * yv.y; a2[0][2] += xv.x * yv.z; a2[0][3] += xv.x * yv.w;
    a2[1][0] += xv.y * yv.x; a2[1][1] += xv.y * yv.y; a2[1][2] += xv.y * yv.z; a2[1][3] += xv.y * yv.w;
    a2[2][0] += xv.z * yv.x; a2[2][1] += xv.z * yv.y; a2[2][2] += xv.z * yv.z; a2[2][3] += xv.z * yv.w;
    a2[3][0] += xv.w * yv.x; a2[3][1] += xv.w * yv.y; a2[3][2] += xv.w * yv.z; a2[3][3] += xv.w * yv.w;
  }
  float* go = Gp + (size_t)(b * 32 + c) * 4096;
#pragma unroll
  for (int i = 0; i < 4; i++) {
    float4 w = {a2[i][0], a2[i][1], a2[i][2], a2[i][3]};
    *reinterpret_cast<float4*>(&go[(tp * 4 + i) * 64 + tq * 4]) = w;
  }
  if (t < 64) {
    float s = 0.f;
    for (int k = 0; k < 64; k++) s += Vs[k * 64 + t];
    sp[(size_t)(b * 32 + c) * 64 + t] = s;
  }
}

// ---- coalesced partial reduction: G = sum_c Gp[c], sv = sum_c sp[c] (128 blocks) ----
__global__ __launch_bounds__(256) void k_gred(const float* __restrict__ Gp, const float* __restrict__ sp,
                                              float* __restrict__ G, float* __restrict__ sv, int nch) {
  int blk = blockIdx.x, b = blockIdx.y, t = threadIdx.x;
  int idx = blk * 256 + t;
  float a = 0.f;
  for (int c = 0; c < nch; c++) a += Gp[(size_t)(b * nch + c) * 4096 + idx];
  G[(size_t)b * 4096 + idx] = a;
  if (blk == 0 && t < 64) {
    float s = 0.f;
    for (int c = 0; c < nch; c++) s += sp[(size_t)(b * nch + c) * 64 + t];
    sv[b * 64 + t] = s;
  }
}

// ---- A = scale*(E_j G + f_j (x) s); r = scale*(g_j^T G + c_j s); analytic mid-LN stats ----
__global__ __launch_bounds__(256) void k_headsA2(
    const float* __restrict__ G, const float* __restrict__ sv,
    const float* __restrict__ Ep, const float* __restrict__ fp,
    const float* __restrict__ gp, const float* __restrict__ cp,
    int j, float scale, int doStats,
    float* __restrict__ A, float* __restrict__ RVo, float* __restrict__ STAT) {
  int b = blockIdx.x, t = threadIdx.x;
  __shared__ float Es[64 * 65];
  __shared__ __align__(16) float Gs[4096];
  __shared__ __align__(16) float As[4096];
  __shared__ float ss[64], fs[64], gs[64];
  __shared__ float cj;
  __shared__ float redbuf[8];
  const float* e0 = Ep + (size_t)(j * RH) * 4096;
  for (int idx = t; idx < 4096; idx += 256) {
    float e = e0[idx] + e0[idx + 4096] + e0[idx + 8192] + e0[idx + 12288];
    Es[(idx >> 6) * 65 + (idx & 63)] = e;
    Gs[idx] = G[(size_t)b * 4096 + idx];
  }
  if (t < 64) {
    ss[t] = sv[b * 64 + t];
    int h0 = j * RH * 64;
    fs[t] = fp[h0 + t] + fp[h0 + 64 + t] + fp[h0 + 128 + t] + fp[h0 + 192 + t];
    gs[t] = gp[h0 + t] + gp[h0 + 64 + t] + gp[h0 + 128 + t] + gp[h0 + 192 + t];
  }
  if (t == 0) cj = cp[j * RH] + cp[j * RH + 1] + cp[j * RH + 2] + cp[j * RH + 3];
  __syncthreads();
  int c = t >> 2, qb = (t & 3) * 16;
  float fv = fs[c];
  float4 acc[4];
#pragma unroll
  for (int u = 0; u < 4; u++) {
    acc[u].x = fv * ss[qb + u * 4 + 0];
    acc[u].y = fv * ss[qb + u * 4 + 1];
    acc[u].z = fv * ss[qb + u * 4 + 2];
    acc[u].w = fv * ss[qb + u * 4 + 3];
  }
  for (int d = 0; d < 64; d++) {
    float ev = Es[c * 65 + d];
    const float4* gr = reinterpret_cast<const float4*>(&Gs[d * 64 + qb]);
#pragma unroll
    for (int u = 0; u < 4; u++) {
      float4 gv = gr[u];
      acc[u].x += ev * gv.x; acc[u].y += ev * gv.y; acc[u].z += ev * gv.z; acc[u].w += ev * gv.w;
    }
  }
  float* ao = A + (size_t)b * 4096 + c * 64 + qb;
#pragma unroll
  for (int u = 0; u < 4; u++) {
    float4 v = acc[u];
    v.x *= scale; v.y *= scale; v.z *= scale; v.w *= scale;
    reinterpret_cast<float4*>(ao)[u] = v;
    *reinterpret_cast<float4*>(&As[c * 64 + qb + u * 4]) = v;
  }
  float rv_t = 0.f;
  if (t < 64) {
    float r = cj * ss[t];
    for (int d = 0; d < 64; d++) r += gs[d] * Gs[d * 64 + t];
    r *= scale;
    RVo[b * 64 + t] = r;
    rv_t = r;
  }
  if (!doStats) return;
  __syncthreads();
  float4 h[4] = {};
  for (int d = 0; d < 64; d++) {
    float gvv = Gs[c * 64 + d];
    const float4* ar = reinterpret_cast<const float4*>(&As[d * 64 + qb]);
#pragma unroll
    for (int u = 0; u < 4; u++) {
      float4 av = ar[u];
      h[u].x += gvv * av.x; h[u].y += gvv * av.y; h[u].z += gvv * av.z; h[u].w += gvv * av.w;
    }
  }
  float tp_ = 0.f;
#pragma unroll
  for (int u = 0; u < 4; u++) {
    float4 a = *reinterpret_cast<const float4*>(&As[c * 64 + qb + u * 4]);
    tp_ += a.x * h[u].x + a.y * h[u].y + a.z * h[u].z + a.w * h[u].w;
  }
  tp_ += __shfl_xor(tp_, 1, 64);  tp_ += __shfl_xor(tp_, 2, 64);
  tp_ += __shfl_xor(tp_, 4, 64);  tp_ += __shfl_xor(tp_, 8, 64);
  tp_ += __shfl_xor(tp_, 16, 64); tp_ += __shfl_xor(tp_, 32, 64);
  if ((t & 63) == 0) redbuf[t >> 6] = tp_;
  if (t < 64) {
    float t1 = 0.f;
    for (int d = 0; d < 64; d++) t1 += ss[d] * As[d * 64 + t];
    float s1 = t1, sr = rv_t, sr2 = rv_t * rv_t, srt = rv_t * t1;
#pragma unroll
    for (int off = 1; off < 64; off <<= 1) {
      s1  += __shfl_xor(s1, off, 64);
      sr  += __shfl_xor(sr, off, 64);
      sr2 += __shfl_xor(sr2, off, 64);
      srt += __shfl_xor(srt, off, 64);
    }
    if (t == 0) { redbuf[4] = s1; redbuf[5] = sr; redbuf[6] = sr2; redbuf[7] = srt; }
  }
  __syncthreads();
  if (t == 0) {
    float tr = redbuf[0] + redbuf[1] + redbuf[2] + redbuf[3];
    float smid = redbuf[4] + 2048.0f * redbuf[5];
    float mu = smid / 131072.0f;
    float e2 = (tr + 2.0f * redbuf[7] + 2048.0f * redbuf[6]) / 131072.0f;
    STAT[b * 2] = mu;
    STAT[b * 2 + 1] = rsqrtf(e2 - mu * mu + EPSc);
  }
}

// ---- fused: mid = V A + 1 r^T; LN via analytic stats; +V residual; write V'; XtY partials ----
__global__ __launch_bounds__(256) void k_midapply(
    float* __restrict__ V, const float* __restrict__ A,
    const float* __restrict__ RVv, const float* __restrict__ STAT,
    const float* __restrict__ g, const float* __restrict__ bb,
    const float* __restrict__ Yext,
    float* __restrict__ Gp, float* __restrict__ sp, int nchG) {
  int blk = blockIdx.x, b = blockIdx.y, t = threadIdx.x;
  __shared__ __align__(16) float As[4096];
  __shared__ __align__(16) float Vs[4096];
  __shared__ __align__(16) float Ys[4096];
  __shared__ float rs[64];
  __shared__ float sm[2];
  const float4* A4 = reinterpret_cast<const float4*>(A + (size_t)b * 4096);
#pragma unroll
  for (int k = 0; k < 4; k++) reinterpret_cast<float4*>(As)[t + k * 256] = A4[t + k * 256];
  if (t < 64) rs[t] = RVv[b * 64 + t];
  if (t == 0) { sm[0] = STAT[b * 2]; sm[1] = STAT[b * 2 + 1]; }
  bool doG = (blk < nchG);
  if (Yext != nullptr && doG) {
    size_t yb = (size_t)b * 32768 + (size_t)blk * 1024;
#pragma unroll
    for (int k = 0; k < 4; k++)
      reinterpret_cast<float4*>(Ys)[t + k * 256] = reinterpret_cast<const float4*>(Yext)[yb + t + k * 256];
  }
  __syncthreads();
  float mu = sm[0], is = sm[1];
  int rl = t >> 2, qb = (t & 3) * 16;
  int row = blk * 64 + rl;
  float* vr = V + (size_t)b * 131072 + (size_t)row * 64;
  float4 acc[4];
#pragma unroll
  for (int u = 0; u < 4; u++) {
    acc[u].x = rs[qb + u * 4 + 0]; acc[u].y = rs[qb + u * 4 + 1];
    acc[u].z = rs[qb + u * 4 + 2]; acc[u].w = rs[qb + u * 4 + 3];
  }
  for (int c = 0; c < 64; c++) {
    float vv = vr[c];
    const float4* ar = reinterpret_cast<const float4*>(&As[c * 64 + qb]);
#pragma unroll
    for (int u = 0; u < 4; u++) {
      float4 av = ar[u];
      acc[u].x += vv * av.x; acc[u].y += vv * av.y; acc[u].z += vv * av.z; acc[u].w += vv * av.w;
    }
  }
  const float4* g4 = reinterpret_cast<const float4*>(g + (size_t)row * 64 + qb);
  const float4* b4 = reinterpret_cast<const float4*>(bb + (size_t)row * 64 + qb);
  const float4* vq = reinterpret_cast<const float4*>(vr + qb);
  float4* vo = reinterpret_cast<float4*>(vr + qb);
#pragma unroll
  for (int u = 0; u < 4; u++) {
    float4 gg = g4[u], bv = b4[u], av = vq[u];
    float4 r;
    r.x = (acc[u].x - mu) * is * gg.x + bv.x + av.x;
    r.y = (acc[u].y - mu) * is * gg.y + bv.y + av.y;
    r.z = (acc[u].z - mu) * is * gg.z + bv.z + av.z;
    r.w = (acc[u].w - mu) * is * gg.w + bv.w + av.w;
    vo[u] = r;
    *reinterpret_cast<float4*>(&Vs[rl * 64 + qb + u * 4]) = r;
  }
  __syncthreads();
  if (!doG) return;
  const float* Yp = (Yext != nullptr) ? Ys : Vs;
  int tp = t >> 4, tq = t & 15;
  float a2[4][4] = {};
  for (int k = 0; k < 64; k++) {
    float4 xv = *reinterpret_cast<const float4*>(&Vs[k * 64 + tp * 4]);
    float4 yv = *reinterpret_cast<const float4*>(&Yp[k * 64 + tq * 4]);
    a2[0][0] += xv.x * yv.x; a2[0][1] += xv.x * yv.y; a2[0][2] += xv.x * yv.z; a2[0][3] += xv.x * yv.w;
    a2[1][0] += xv.y * yv.x; a2[1][1] += xv.y * yv.y; a2[1][2] += xv.y * yv.z; a2[1][3] += xv.y * yv.w;
    a2[2][0] += xv.z * yv.x; a2[2][1] += xv.z * yv.y; a2[2][2] += xv.z * yv.z; a2[2][3] += xv.z * yv.w;
    a2[3][0] += xv.w * yv.x; a2[3][1] += xv.w * yv.y; a2[3][2] += xv.w * yv.z; a2[3][3] += xv.w * yv.w;
  }
  float* go = Gp + (size_t)(b * nchG + blk) * 4096;
#pragma unroll
  for (int i = 0; i < 4; i++) {
    float4 w = {a2[i][0], a2[i][1], a2[i][2], a2[i][3]};
    *reinterpret_cast<float4*>(&go[(tp * 4 + i) * 64 + tq * 4]) = w;
  }
  if (t < 64) {
    float s = 0.f;
    for (int k = 0; k < 64; k++) s += Yp[k * 64 + t];
    sp[(size_t)(b * nchG + blk) * 64 + t] = s;
  }
}

// ---- k_y: ZT[b*64+q][z*1024+m] = bf16(V A); LDS-staged coalesced uint4 stores ----
__global__ __launch_bounds__(256) void k_y(const float* __restrict__ V, const float* __restrict__ A,
                                           ushort* __restrict__ ZT) {
  int blk = blockIdx.x, b = blockIdx.y, z = blockIdx.z, t = threadIdx.x;
  __shared__ __align__(16) float As[4096];
  __shared__ ushort Zs[64][36];
  const float4* A4 = reinterpret_cast<const float4*>(A + (size_t)b * 4096);
#pragma unroll
  for (int k = 0; k < 4; k++) reinterpret_cast<float4*>(As)[t + k * 256] = A4[t + k * 256];
  __syncthreads();
  int ml = t >> 3, qb = (t & 7) * 8;
  int m = blk * 32 + ml;
  const float* vr = V + (size_t)b * 131072 + (size_t)(z * 1024 + m) * 64;
  float4 acc[2] = {};
  for (int c = 0; c < 64; c++) {
    float vv = vr[c];
    const float4* ar = reinterpret_cast<const float4*>(&As[c * 64 + qb]);
#pragma unroll
    for (int u = 0; u < 2; u++) {
      float4 av = ar[u];
      acc[u].x += vv * av.x; acc[u].y += vv * av.y; acc[u].z += vv * av.z; acc[u].w += vv * av.w;
    }
  }
  Zs[qb + 0][ml] = f2bf(acc[0].x); Zs[qb + 1][ml] = f2bf(acc[0].y);
  Zs[qb + 2][ml] = f2bf(acc[0].z); Zs[qb + 3][ml] = f2bf(acc[0].w);
  Zs[qb + 4][ml] = f2bf(acc[1].x); Zs[qb + 5][ml] = f2bf(acc[1].y);
  Zs[qb + 6][ml] = f2bf(acc[1].z); Zs[qb + 7][ml] = f2bf(acc[1].w);
  __syncthreads();
  int rowq = t >> 2, seg = t & 3;
  const ushort* srcp = &Zs[rowq][seg * 8];
  uint p0 = (uint)srcp[0] | ((uint)srcp[1] << 16);
  uint p1 = (uint)srcp[2] | ((uint)srcp[3] << 16);
  uint p2 = (uint)srcp[4] | ((uint)srcp[5] << 16);
  uint p3 = (uint)srcp[6] | ((uint)srcp[7] << 16);
  ushort* dp = ZT + (size_t)(b * 64 + rowq) * 2048 + (size_t)z * 1024 + blk * 32 + seg * 8;
  *reinterpret_cast<uint4*>(dp) = make_uint4(p0, p1, p2, p3);
}

// ---- MFMA final GEMM, full-K, fused epilogue: out = CFINAL*(W Z + w1 (x) RV) ----
// w1[n] computed free via ones-MFMA (B=1 => D[n][*] = rowsum over full K).
__global__ __launch_bounds__(256) void k_final_mfma2(const ushort* __restrict__ WTW,
                                                     const ushort* __restrict__ WTF,
                                                     const ushort* __restrict__ ZT,
                                                     const float* __restrict__ RV,
                                                     float* __restrict__ out) {
  int tn = blockIdx.x, tb = blockIdx.y, t = threadIdx.x;
  int lane = t & 63, w = t >> 6;
  int wn = w & 1, wb = w >> 1;
  int r = lane & 15, g = lane >> 4;
  int nrow = tn * 32 + wn * 16 + r;
  int bi0 = tb * 64 + wb * 32 + r;
  bf16x8 ones;
#pragma unroll
  for (int i = 0; i < 8; i++) ones[i] = (__bf16)1.0f;
  f32x4 a0 = {0.f, 0.f, 0.f, 0.f}, a1 = a0, aw = a0;
  for (int kz = 0; kz < 4; kz++) {
    const ushort* wbase = (kz < 2) ? WTW : WTF;
    const ushort* wp = wbase + (size_t)nrow * 1024 + (kz & 1) * 512 + g * 8;
    const ushort* zp0 = ZT + (size_t)bi0 * 2048 + kz * 512 + g * 8;
    const ushort* zp1 = zp0 + 16 * 2048;
#pragma unroll 4
    for (int ks = 0; ks < 512; ks += 32) {
      bf16x8 fa  = *reinterpret_cast<const bf16x8*>(wp + ks);
      bf16x8 fb0 = *reinterpret_cast<const bf16x8*>(zp0 + ks);
      bf16x8 fb1 = *reinterpret_cast<const bf16x8*>(zp1 + ks);
      a0 = __builtin_amdgcn_mfma_f32_16x16x32_bf16(fa, fb0, a0, 0, 0, 0);
      a1 = __builtin_amdgcn_mfma_f32_16x16x32_bf16(fa, fb1, a1, 0, 0, 0);
      aw = __builtin_amdgcn_mfma_f32_16x16x32_bf16(fa, ones, aw, 0, 0, 0);
    }
  }
  int nbase = tn * 32 + wn * 16 + g * 4;
  int i0 = wb * 32 + r;
  float rv0 = RV[tb * 64 + i0];
  float rv1 = RV[tb * 64 + i0 + 16];
  float* op = out + (size_t)tb * 65536;
#pragma unroll
  for (int rr = 0; rr < 4; rr++) {
    float w1v = aw[rr];
    op[(size_t)(nbase + rr) * 64 + i0]      = CFINAL * (a0[rr] + w1v * rv0);
    op[(size_t)(nbase + rr) * 64 + i0 + 16] = CFINAL * (a1[rr] + w1v * rv1);
  }
}

extern "C" void kernel_launch(void* const* d_in, const int* in_sizes, int n_in,
                              void* d_out, int out_size, void* d_ws, size_t ws_size,
                              hipStream_t stream) {
  (void)in_sizes; (void)n_in; (void)out_size;
  const float* xy  = (const float*)d_in[1];
  const float* kW1 = (const float*)d_in[3];
  const float* kb1 = (const float*)d_in[4];
  const float* kW2 = (const float*)d_in[5];
  const float* kb2 = (const float*)d_in[6];
  const float* kW3 = (const float*)d_in[7];
  const float* kb3 = (const float*)d_in[8];
  const float* fW1 = (const float*)d_in[9];
  const float* fb1 = (const float*)d_in[10];
  const float* fW2 = (const float*)d_in[11];
  const float* fb2 = (const float*)d_in[12];
  const float* fW3 = (const float*)d_in[13];
  const float* fb3 = (const float*)d_in[14];
  const float* Wq  = (const float*)d_in[15];
  const float* bq  = (const float*)d_in[16];
  const float* Wk  = (const float*)d_in[17];
  const float* bk  = (const float*)d_in[18];
  const float* lng = (const float*)d_in[19];
  const float* lnb = (const float*)d_in[20];
  float* ws = (float*)d_ws;
  float* out = (float*)d_out;
  if (ws_size < WS_FLOATS * sizeof(float)) return;  // visible failure, no OOB

  float* V   = ws + OFF_V;
  float* U1K = ws + OFF_U1K;
  float* U2K = ws + OFF_U2K;
  float* U1F = ws + OFF_U1F;
  float* U2F = ws + OFF_U2F;
  float* GPb = ws + OFF_GP;
  float* SPb = ws + OFF_SP;
  float* LNP = ws + OFF_LNP;
  // overlays
  float* G    = ws + OFF_U1K;             // 32768 (U tables dead after k_mlp2)
  float* SV   = ws + OFF_U1F;             // 512
  float* A    = ws + OFF_A;
  float* RV   = ws + OFF_RV;
  float* STAT = ws + OFF_LNP;
  ushort* Wbf  = (ushort*)(ws + OFF_W);
  ushort* WTW  = (ushort*)(ws + OFF_W + 524288);
  ushort* Wfbf = (ushort*)(ws + OFF_WF);
  ushort* WTF  = (ushort*)(ws + OFF_WF + 524288);
  ushort* ZT   = (ushort*)(ws + OFF_MID);
  float* Ep   = ws + OFF_ZU;
  float* Fp   = ws + OFF_ZU + 49152;
  float* Gpp  = ws + OFF_ZU + 49920;
  float* Cp   = ws + OFF_ZU + 50688;
  float* LIN  = ws + OFF_ZU + LIN_OFF;    // LINK[32], LINF[32], CSTK, CSTF

  k_prep<<<dim3(272), dim3(256), 0, stream>>>(kW1, kb1, fW1, fb1, U1K, U2K, U1F, U2F,
                                              kW2, kW3, kb2, fW2, fW3, fb2, LIN,
                                              Wq, bq, Wk, bk, Ep, Fp, Gpp, Cp,
                                              xy, LNP);
  k_mlp2<<<dim3(1024, 2), dim3(256), 0, stream>>>(U1K, U2K, kW2, kb2, kW3, kb3,
                                                  U1F, U2F, fW2, fb2, fW3, fb3, LIN, Wbf, Wfbf);
  k_cvtapply<<<dim3(768), dim3(256), 0, stream>>>(Wbf, Wfbf, WTW, WTF,
                                                  xy, lng, lnb, LNP, V, GPb, SPb);

  for (int j = 0; j < 2; j++) {
    k_gred<<<dim3(16, 8), dim3(256), 0, stream>>>(GPb, SPb, G, SV, 32);
    k_headsA2<<<dim3(8), dim3(256), 0, stream>>>(G, SV, Ep, Fp, Gpp, Cp, j, DXDYf * SCALEf, 1,
                                                 A, RV, STAT);
    k_midapply<<<dim3(32, 8), dim3(256), 0, stream>>>(
        V, A, RV, STAT, lng + (size_t)(j + 1) * 131072, lnb + (size_t)(j + 1) * 131072,
        (j == 1) ? xy : nullptr, GPb, SPb, (j == 1) ? 16 : 32);
  }
  k_gred<<<dim3(16, 8), dim3(256), 0, stream>>>(GPb, SPb, G, SV, 16);
  k_headsA2<<<dim3(8), dim3(256), 0, stream>>>(G, SV, Ep, Fp, Gpp, Cp, 2, 1.0f, 0, A, RV, STAT);
  k_y<<<dim3(32, 8, 2), dim3(256), 0, stream>>>(V, A, ZT);
  k_final_mfma2<<<dim3(32, 8), dim3(256), 0, stream>>>(WTW, WTF, ZT, RV, out);
}

// Round 14
// 160.279 us; speedup vs baseline: 2.9586x; 1.1318x over previous
//
#include <hip/hip_runtime.h>

namespace {
constexpr int SD = 1024;           // D
constexpr int TD = 2048;           // 2D
constexpr int BATCH = 8;
constexpr int RH = 4;
constexpr float EPSc = 1e-5f;
constexpr float DXf = 2.0f / 31.0f;
constexpr float DXDYf = DXf * DXf;
constexpr float SCALEf = 0.125f;
constexpr float CFINAL = DXDYf * DXDYf * SCALEf;

// workspace offsets (floats)
constexpr size_t OFF_V   = 0;
constexpr size_t OFF_MID = OFF_V   + (size_t)BATCH * TD * 64;   // 1048576
constexpr size_t OFF_W   = OFF_MID + (size_t)BATCH * TD * 64;
constexpr size_t OFF_WF  = OFF_W   + (size_t)SD * SD;
constexpr size_t OFF_U1K = OFF_WF  + (size_t)SD * SD;
constexpr size_t OFF_U2K = OFF_U1K + SD * 32;
constexpr size_t OFF_U1F = OFF_U2K + SD * 32;
constexpr size_t OFF_U2F = OFF_U1F + SD * 32;
constexpr size_t OFF_GP  = OFF_U2F + SD * 32;                    // 8*32*4096
constexpr size_t OFF_SP  = OFF_GP  + (size_t)BATCH * 32 * 4096;  // 8*32*64
constexpr size_t OFF_A   = OFF_SP  + BATCH * 32 * 64;            // A matrix (8x4096)
constexpr size_t OFF_RV  = OFF_A   + BATCH * 4096;               // RV (8x64)
constexpr size_t OFF_LNP = OFF_RV  + BATCH * 64;                 // LNP; later STAT
constexpr size_t OFF_ZU  = OFF_LNP + BATCH * 32 * 2;             // Ep region
constexpr size_t OFF_ZF  = OFF_ZU  + (size_t)SD * 512;
constexpr size_t OFF_W1  = OFF_ZF  + (size_t)SD * 512;
constexpr size_t OFF_CS  = OFF_W1  + SD;
constexpr size_t WS_FLOATS = OFF_CS + 16 * SD;
// overlays:
//  G->U1K, SV->U1F  (U tables dead after k_mlp2apply)
//  Wbf->OFF_W lo, WTW->OFF_W+524288; Wfbf->OFF_WF lo, WTF->OFF_WF+524288
//  ZT->MID lo
//  Ep/fp/gp/cp/LIN -> OFF_ZU; STAT->OFF_LNP
constexpr size_t LIN_OFF = 50704;  // within ZU region: LINK[32], LINF[32], CSTK, CSTF
} // namespace

typedef __bf16 bf16x8 __attribute__((ext_vector_type(8)));
typedef float f32x4 __attribute__((ext_vector_type(4)));

__device__ __forceinline__ float leaky(float x) { return fmaxf(x, 0.01f * x); }
__device__ __forceinline__ float gxv(int i) { return -1.0f + (2.0f / 31.0f) * (float)i; }
__device__ __forceinline__ ushort f2bf(float x) { union { __bf16 b; ushort u; } v; v.b = (__bf16)x; return v.u; }
__device__ __forceinline__ float bf2f(ushort u) { return __uint_as_float(((uint)u) << 16); }

// ---- merged: blocks 0-3 u-tables(+lin/cst); 4-15 head-collapse; 16-271 xy LN redsum ----
__global__ __launch_bounds__(256) void k_prep(
    const float* __restrict__ kW1, const float* __restrict__ kb1,
    const float* __restrict__ fW1, const float* __restrict__ fb1,
    float* __restrict__ u1k, float* __restrict__ u2k,
    float* __restrict__ u1f, float* __restrict__ u2f,
    const float* __restrict__ kW2, const float* __restrict__ kW3, const float* __restrict__ kb2,
    const float* __restrict__ fW2, const float* __restrict__ fW3, const float* __restrict__ fb2,
    float* __restrict__ LIN,
    const float* __restrict__ Wq, const float* __restrict__ bq,
    const float* __restrict__ Wk, const float* __restrict__ bk,
    float* __restrict__ Ep, float* __restrict__ fp,
    float* __restrict__ gp, float* __restrict__ cp,
    const float* __restrict__ xy, float* __restrict__ part) {
  __shared__ __align__(16) float Wqs[4096];
  __shared__ float Wks[64 * 65];
  __shared__ float bqs[64], bks[64];
  __shared__ float ss4[4], qq4[4];
  int blk = blockIdx.x, t = threadIdx.x;
  if (blk >= 16) {
    int idx = blk - 16;
    int b = idx >> 5, c = idx & 31;
    const float4* X4 = reinterpret_cast<const float4*>(xy + (size_t)b * 131072 + (size_t)c * 4096);
    float s = 0.f, q = 0.f;
#pragma unroll
    for (int k = 0; k < 4; k++) {
      float4 v = X4[t + k * 256];
      s += v.x + v.y + v.z + v.w;
      q += v.x * v.x + v.y * v.y + v.z * v.z + v.w * v.w;
    }
    for (int off = 32; off; off >>= 1) { s += __shfl_down(s, off); q += __shfl_down(q, off); }
    int lane = t & 63, wid = t >> 6;
    if (lane == 0) { ss4[wid] = s; qq4[wid] = q; }
    __syncthreads();
    if (t == 0) {
      part[(size_t)(b * 32 + c) * 2] = ss4[0] + ss4[1] + ss4[2] + ss4[3];
      part[(size_t)(b * 32 + c) * 2 + 1] = qq4[0] + qq4[1] + qq4[2] + qq4[3];
    }
    return;
  }
  if (blk < 4) {
    int n = blk * 256 + t;
    float ga = gxv(n >> 5), gb = gxv(n & 31);
    for (int j = 0; j < 32; j++) {
      u1k[n * 32 + j] = ga * kW1[j] + gb * kW1[32 + j] + kb1[j];
      u2k[n * 32 + j] = gb * kW1[64 + j] + ga * kW1[96 + j];
      u1f[n * 32 + j] = ga * fW1[j] + gb * fW1[32 + j] + fb1[j];
      u2f[n * 32 + j] = gb * fW1[64 + j] + ga * fW1[96 + j];
    }
    if (blk < 2 && t < 33) {
      const float* W2 = blk ? fW2 : kW2;
      const float* W3 = blk ? fW3 : kW3;
      const float* b2 = blk ? fb2 : kb2;
      if (t < 32) {
        float s = 0.f;
        for (int o = 0; o < 64; o++) s += W2[t * 64 + o] * W3[o];
        LIN[blk * 32 + t] = s;
      } else {
        float s = 0.f;
        for (int o = 0; o < 64; o++) s += b2[o] * W3[o];
        LIN[64 + blk] = s;   // cstraw
      }
    }
    return;
  }
  int h = blk - 4;  // 0..11
  const float* wqb = Wq + (size_t)h * 4096;
  const float* wkb = Wk + (size_t)h * 4096;
  for (int idx = t; idx < 4096; idx += 256) {
    Wqs[idx] = wqb[idx];
    Wks[(idx >> 6) * 65 + (idx & 63)] = wkb[idx];
  }
  if (t < 64) { bqs[t] = bq[h * 64 + t]; bks[t] = bk[h * 64 + t]; }
  __syncthreads();
  int cpp = t & 63, cb = (t >> 6) * 16;
  float acc[16];
#pragma unroll
  for (int u = 0; u < 16; u++) acc[u] = 0.f;
  for (int k = 0; k < 64; k++) {
    float wkv = Wks[cpp * 65 + k];
#pragma unroll
    for (int u = 0; u < 16; u++) acc[u] += Wqs[(cb + u) * 64 + k] * wkv;
  }
  float* eo = Ep + (size_t)h * 4096;
#pragma unroll
  for (int u = 0; u < 16; u++) eo[(cb + u) * 64 + cpp] = acc[u];
  if (t < 64) {
    float f = 0.f, gg = 0.f;
    for (int k = 0; k < 64; k++) {
      f  += Wqs[t * 64 + k] * bks[k];
      gg += Wks[t * 65 + k] * bqs[k];
    }
    fp[h * 64 + t] = f;
    gp[h * 64 + t] = gg;
    float ca = bqs[t] * bks[t];
    ca += __shfl_xor(ca, 1, 64);
    ca += __shfl_xor(ca, 2, 64);
    ca += __shfl_xor(ca, 4, 64);
    ca += __shfl_xor(ca, 8, 64);
    ca += __shfl_xor(ca, 16, 64);
    ca += __shfl_xor(ca, 32, 64);
    if (t == 0) cp[h] = ca;
  }
}

// ---- merged: blocks 0-1023 MFMA edge-MLP (4 n-rows x 512 m); 1024-1279 LN-apply + XtY ----
__global__ __launch_bounds__(256) void k_mlp2apply(
    const float* __restrict__ u1k, const float* __restrict__ u2k,
    const float* __restrict__ kW2, const float* __restrict__ kb2,
    const float* __restrict__ kW3, const float* __restrict__ kb3,
    const float* __restrict__ u1f, const float* __restrict__ u2f,
    const float* __restrict__ fW2, const float* __restrict__ fb2,
    const float* __restrict__ fW3, const float* __restrict__ fb3,
    const float* __restrict__ LIN,
    ushort* __restrict__ outK, ushort* __restrict__ outF,
    const float* __restrict__ src, const float* __restrict__ g,
    const float* __restrict__ bb, const float* __restrict__ lnp,
    float* __restrict__ Vout, float* __restrict__ Gp, float* __restrict__ sp) {
  __shared__ __align__(16) float Vs[4096];
  __shared__ float sm[2];
  int blk = blockIdx.x;
  const int t = threadIdx.x;
  if (blk < 1024) {
    const int which = blk >> 9;          // 0..1
    const int nb = blk & 511;
    const float* u1 = which ? u1f : u1k;
    const float* u2 = which ? u2f : u2k;
    const float* W2 = which ? fW2 : kW2;
    const float* b2 = which ? fb2 : kb2;
    const float* W3 = which ? fW3 : kW3;
    const float* b3 = which ? fb3 : kb3;
    ushort* out = which ? outF : outK;
    const int lane = t & 63, wave = t >> 6;
    const int row = lane & 15, grp = lane >> 4;
    const int n0 = (nb >> 1) * 4;
    const int mh = nb & 1;

    bf16x8 wfrag[4];
    float4 b2q[4], w3q[4];
#pragma unroll
    for (int tt = 0; tt < 4; tt++) {
#pragma unroll
      for (int i = 0; i < 8; i++) wfrag[tt][i] = (__bf16)W2[(grp * 8 + i) * 64 + tt * 16 + row];
      b2q[tt] = *reinterpret_cast<const float4*>(b2 + tt * 16 + grp * 4);
      w3q[tt] = *reinterpret_cast<const float4*>(W3 + tt * 16 + grp * 4);
    }
    float4 l0 = *reinterpret_cast<const float4*>(LIN + which * 32 + grp * 8);
    float4 l1 = *reinterpret_cast<const float4*>(LIN + which * 32 + grp * 8 + 4);
    float linp[8] = {l0.x, l0.y, l0.z, l0.w, l1.x, l1.y, l1.z, l1.w};
    const float cst = 0.505f * LIN[64 + which] + b3[0];

    float u1j[4][8];
#pragma unroll
    for (int nn = 0; nn < 4; nn++)
#pragma unroll
      for (int i = 0; i < 8; i++) u1j[nn][i] = u1[(n0 + nn) * 32 + grp * 8 + i];

#pragma unroll
    for (int chunk = 0; chunk < 2; chunk++) {
#pragma unroll
      for (int st = 0; st < 4; st++) {
        int mbase = mh * 512 + chunk * 256 + wave * 64 + st * 16;
        int m = mbase + row;
        const float4* u2p = reinterpret_cast<const float4*>(u2 + (size_t)m * 32 + grp * 8);
        float4 ua = u2p[0], ub = u2p[1];
        float hv[8] = {ua.x, ua.y, ua.z, ua.w, ub.x, ub.y, ub.z, ub.w};
#pragma unroll
        for (int nn = 0; nn < 4; nn++) {
          float h1f[8];
#pragma unroll
          for (int i = 0; i < 8; i++) h1f[i] = leaky(u1j[nn][i] + hv[i]);
          float accLin = 0.f;
#pragma unroll
          for (int i = 0; i < 8; i++) accLin = fmaf(linp[i], h1f[i], accLin);
          bf16x8 pfrag;
#pragma unroll
          for (int i = 0; i < 8; i++) pfrag[i] = (__bf16)h1f[i];
          float accAbs = 0.f;
#pragma unroll
          for (int tt = 0; tt < 4; tt++) {
            f32x4 ci = {b2q[tt].x, b2q[tt].y, b2q[tt].z, b2q[tt].w};
            f32x4 c = __builtin_amdgcn_mfma_f32_16x16x32_bf16(wfrag[tt], pfrag, ci, 0, 0, 0);
            accAbs = fmaf(fabsf(c[0]), w3q[tt].x, accAbs);
            accAbs = fmaf(fabsf(c[1]), w3q[tt].y, accAbs);
            accAbs = fmaf(fabsf(c[2]), w3q[tt].z, accAbs);
            accAbs = fmaf(fabsf(c[3]), w3q[tt].w, accAbs);
          }
          float red = fmaf(0.495f, accAbs, 0.505f * accLin);
          red += __shfl_xor(red, 16, 64);
          red += __shfl_xor(red, 32, 64);
          if (grp == 0) out[(size_t)(n0 + nn) * SD + mbase + row] = f2bf(red + cst);
        }
      }
    }
    return;
  }
  // ---- LN-apply + XtY partials (blocks 1024-1279) ----
  int idx2 = blk - 1024;
  int c = idx2 & 31, b = idx2 >> 5;
  if (t == 0) {
    float s = 0.f, q = 0.f;
    for (int cc = 0; cc < 32; cc++) {
      s += lnp[(size_t)(b * 32 + cc) * 2];
      q += lnp[(size_t)(b * 32 + cc) * 2 + 1];
    }
    float mean = s / 131072.0f;
    sm[0] = mean;
    sm[1] = rsqrtf(q / 131072.0f - mean * mean + EPSc);
  }
  __syncthreads();
  float mean = sm[0], is = sm[1];
  size_t base4 = (size_t)b * 32768 + (size_t)c * 1024;
#pragma unroll
  for (int k = 0; k < 4; k++) {
    int idx = t + k * 256;
    float4 v = reinterpret_cast<const float4*>(src)[base4 + idx];
    float4 gg = reinterpret_cast<const float4*>(g)[c * 1024 + idx];
    float4 bv = reinterpret_cast<const float4*>(bb)[c * 1024 + idx];
    float4 r;
    r.x = (v.x - mean) * is * gg.x + bv.x;
    r.y = (v.y - mean) * is * gg.y + bv.y;
    r.z = (v.z - mean) * is * gg.z + bv.z;
    r.w = (v.w - mean) * is * gg.w + bv.w;
    reinterpret_cast<float4*>(Vout)[base4 + idx] = r;
    reinterpret_cast<float4*>(Vs)[idx] = r;
  }
  __syncthreads();
  int tp = t >> 4, tq = t & 15;
  float a2[4][4] = {};
  for (int k = 0; k < 64; k++) {
    float4 xv = *reinterpret_cast<const float4*>(&Vs[k * 64 + tp * 4]);
    float4 yv = *reinterpret_cast<const float4*>(&Vs[k * 64 + tq * 4]);
    a2[0][0] += xv.x * yv.x; a2[0][1] += xv.x * yv.y; a2[0][2] += xv.x * yv.z; a2[0][3] += xv.x * yv.w;
    a2[1][0] += xv.y * yv.x; a2[1][1] += xv.y * yv.y; a2[1][2] += xv.y * yv.z; a2[1][3] += xv.y * yv.w;
    a2[2][0] += xv.z * yv.x; a2[2][1] += xv.z * yv.y; a2[2][2] += xv.z * yv.z; a2[2][3] += xv.z * yv.w;
    a2[3][0] += xv.w * yv.x; a2[3][1] += xv.w * yv.y; a2[3][2] += xv.w * yv.z; a2[3][3] += xv.w * yv.w;
  }
  float* go = Gp + (size_t)(b * 32 + c) * 4096;
#pragma unroll
  for (int i = 0; i < 4; i++) {
    float4 w = {a2[i][0], a2[i][1], a2[i][2], a2[i][3]};
    *reinterpret_cast<float4*>(&go[(tp * 4 + i) * 64 + tq * 4]) = w;
  }
  if (t < 64) {
    float s = 0.f;
    for (int k = 0; k < 64; k++) s += Vs[k * 64 + t];
    sp[(size_t)(b * 32 + c) * 64 + t] = s;
  }
}

// ---- merged: blocks 0-511 bf16 transpose; 512-639 gred (nch=32) ----
__global__ __launch_bounds__(256) void k_cvtgred(
    const ushort* __restrict__ srcA, const ushort* __restrict__ srcB,
    ushort* __restrict__ dstA, ushort* __restrict__ dstB,
    const float* __restrict__ Gp, const float* __restrict__ sp,
    float* __restrict__ G, float* __restrict__ sv) {
  __shared__ float T[64][65];
  int blk = blockIdx.x, t = threadIdx.x;
  if (blk < 512) {
    int bx = blk & 15, by = (blk >> 4) & 15, bz = blk >> 8;
    const ushort* srcp = bz ? srcB : srcA;
    ushort* dst = bz ? dstB : dstA;
    int c0 = bx * 64, r0 = by * 64;
    int rr = t >> 2, cc = (t & 3) * 16;
    const uint4* s4 = reinterpret_cast<const uint4*>(srcp + (size_t)(r0 + rr) * 1024 + c0 + cc);
    uint4 q0 = s4[0], q1 = s4[1];
    uint qs[8] = {q0.x, q0.y, q0.z, q0.w, q1.x, q1.y, q1.z, q1.w};
#pragma unroll
    for (int j = 0; j < 8; j++) {
      T[rr][cc + 2 * j]     = bf2f((ushort)(qs[j] & 0xffffu));
      T[rr][cc + 2 * j + 1] = bf2f((ushort)(qs[j] >> 16));
    }
    __syncthreads();
    uint pk[8];
#pragma unroll
    for (int j = 0; j < 8; j++) {
      uint lo = (uint)f2bf(T[cc + 2 * j][rr]);
      uint hi = (uint)f2bf(T[cc + 2 * j + 1][rr]);
      pk[j] = lo | (hi << 16);
    }
    ushort* dp = dst + (size_t)(c0 + rr) * 1024 + r0 + cc;
    uint4* dp4 = reinterpret_cast<uint4*>(dp);
    dp4[0] = make_uint4(pk[0], pk[1], pk[2], pk[3]);
    dp4[1] = make_uint4(pk[4], pk[5], pk[6], pk[7]);
    return;
  }
  int idx2 = blk - 512;
  int gblk = idx2 & 15, b = idx2 >> 4;
  int idx = gblk * 256 + t;
  float a = 0.f;
  for (int c = 0; c < 32; c++) a += Gp[(size_t)(b * 32 + c) * 4096 + idx];
  G[(size_t)b * 4096 + idx] = a;
  if (gblk == 0 && t < 64) {
    float s = 0.f;
    for (int c = 0; c < 32; c++) s += sp[(size_t)(b * 32 + c) * 64 + t];
    sv[b * 64 + t] = s;
  }
}

// ---- coalesced partial reduction: G = sum_c Gp[c], sv = sum_c sp[c] (128 blocks) ----
__global__ __launch_bounds__(256) void k_gred(const float* __restrict__ Gp, const float* __restrict__ sp,
                                              float* __restrict__ G, float* __restrict__ sv, int nch) {
  int blk = blockIdx.x, b = blockIdx.y, t = threadIdx.x;
  int idx = blk * 256 + t;
  float a = 0.f;
  for (int c = 0; c < nch; c++) a += Gp[(size_t)(b * nch + c) * 4096 + idx];
  G[(size_t)b * 4096 + idx] = a;
  if (blk == 0 && t < 64) {
    float s = 0.f;
    for (int c = 0; c < nch; c++) s += sp[(size_t)(b * nch + c) * 64 + t];
    sv[b * 64 + t] = s;
  }
}

// ---- A = scale*(E_j G + f_j (x) s); r = scale*(g_j^T G + c_j s); analytic mid-LN stats ----
__global__ __launch_bounds__(256) void k_headsA2(
    const float* __restrict__ G, const float* __restrict__ sv,
    const float* __restrict__ Ep, const float* __restrict__ fp,
    const float* __restrict__ gp, const float* __restrict__ cp,
    int j, float scale, int doStats,
    float* __restrict__ A, float* __restrict__ RVo, float* __restrict__ STAT) {
  int b = blockIdx.x, t = threadIdx.x;
  __shared__ float Es[64 * 65];
  __shared__ __align__(16) float Gs[4096];
  __shared__ __align__(16) float As[4096];
  __shared__ float ss[64], fs[64], gs[64];
  __shared__ float cj;
  __shared__ float redbuf[8];
  const float* e0 = Ep + (size_t)(j * RH) * 4096;
  for (int idx = t; idx < 4096; idx += 256) {
    float e = e0[idx] + e0[idx + 4096] + e0[idx + 8192] + e0[idx + 12288];
    Es[(idx >> 6) * 65 + (idx & 63)] = e;
    Gs[idx] = G[(size_t)b * 4096 + idx];
  }
  if (t < 64) {
    ss[t] = sv[b * 64 + t];
    int h0 = j * RH * 64;
    fs[t] = fp[h0 + t] + fp[h0 + 64 + t] + fp[h0 + 128 + t] + fp[h0 + 192 + t];
    gs[t] = gp[h0 + t] + gp[h0 + 64 + t] + gp[h0 + 128 + t] + gp[h0 + 192 + t];
  }
  if (t == 0) cj = cp[j * RH] + cp[j * RH + 1] + cp[j * RH + 2] + cp[j * RH + 3];
  __syncthreads();
  int c = t >> 2, qb = (t & 3) * 16;
  float fv = fs[c];
  float4 acc[4];
#pragma unroll
  for (int u = 0; u < 4; u++) {
    acc[u].x = fv * ss[qb + u * 4 + 0];
    acc[u].y = fv * ss[qb + u * 4 + 1];
    acc[u].z = fv * ss[qb + u * 4 + 2];
    acc[u].w = fv * ss[qb + u * 4 + 3];
  }
  for (int d = 0; d < 64; d++) {
    float ev = Es[c * 65 + d];
    const float4* gr = reinterpret_cast<const float4*>(&Gs[d * 64 + qb]);
#pragma unroll
    for (int u = 0; u < 4; u++) {
      float4 gv = gr[u];
      acc[u].x += ev * gv.x; acc[u].y += ev * gv.y; acc[u].z += ev * gv.z; acc[u].w += ev * gv.w;
    }
  }
  float* ao = A + (size_t)b * 4096 + c * 64 + qb;
#pragma unroll
  for (int u = 0; u < 4; u++) {
    float4 v = acc[u];
    v.x *= scale; v.y *= scale; v.z *= scale; v.w *= scale;
    reinterpret_cast<float4*>(ao)[u] = v;
    *reinterpret_cast<float4*>(&As[c * 64 + qb + u * 4]) = v;
  }
  float rv_t = 0.f;
  if (t < 64) {
    float r = cj * ss[t];
    for (int d = 0; d < 64; d++) r += gs[d] * Gs[d * 64 + t];
    r *= scale;
    RVo[b * 64 + t] = r;
    rv_t = r;
  }
  if (!doStats) return;
  __syncthreads();
  float4 h[4] = {};
  for (int d = 0; d < 64; d++) {
    float gvv = Gs[c * 64 + d];
    const float4* ar = reinterpret_cast<const float4*>(&As[d * 64 + qb]);
#pragma unroll
    for (int u = 0; u < 4; u++) {
      float4 av = ar[u];
      h[u].x += gvv * av.x; h[u].y += gvv * av.y; h[u].z += gvv * av.z; h[u].w += gvv * av.w;
    }
  }
  float tp_ = 0.f;
#pragma unroll
  for (int u = 0; u < 4; u++) {
    float4 a = *reinterpret_cast<const float4*>(&As[c * 64 + qb + u * 4]);
    tp_ += a.x * h[u].x + a.y * h[u].y + a.z * h[u].z + a.w * h[u].w;
  }
  tp_ += __shfl_xor(tp_, 1, 64);  tp_ += __shfl_xor(tp_, 2, 64);
  tp_ += __shfl_xor(tp_, 4, 64);  tp_ += __shfl_xor(tp_, 8, 64);
  tp_ += __shfl_xor(tp_, 16, 64); tp_ += __shfl_xor(tp_, 32, 64);
  if ((t & 63) == 0) redbuf[t >> 6] = tp_;
  if (t < 64) {
    float t1 = 0.f;
    for (int d = 0; d < 64; d++) t1 += ss[d] * As[d * 64 + t];
    float s1 = t1, sr = rv_t, sr2 = rv_t * rv_t, srt = rv_t * t1;
#pragma unroll
    for (int off = 1; off < 64; off <<= 1) {
      s1  += __shfl_xor(s1, off, 64);
      sr  += __shfl_xor(sr, off, 64);
      sr2 += __shfl_xor(sr2, off, 64);
      srt += __shfl_xor(srt, off, 64);
    }
    if (t == 0) { redbuf[4] = s1; redbuf[5] = sr; redbuf[6] = sr2; redbuf[7] = srt; }
  }
  __syncthreads();
  if (t == 0) {
    float tr = redbuf[0] + redbuf[1] + redbuf[2] + redbuf[3];
    float smid = redbuf[4] + 2048.0f * redbuf[5];
    float mu = smid / 131072.0f;
    float e2 = (tr + 2.0f * redbuf[7] + 2048.0f * redbuf[6]) / 131072.0f;
    STAT[b * 2] = mu;
    STAT[b * 2 + 1] = rsqrtf(e2 - mu * mu + EPSc);
  }
}

// ---- fused: mid = V A + 1 r^T; LN via analytic stats; +V residual; write V'; XtY partials ----
__global__ __launch_bounds__(256) void k_midapply(
    float* __restrict__ V, const float* __restrict__ A,
    const float* __restrict__ RVv, const float* __restrict__ STAT,
    const float* __restrict__ g, const float* __restrict__ bb,
    const float* __restrict__ Yext,
    float* __restrict__ Gp, float* __restrict__ sp, int nchG) {
  int blk = blockIdx.x, b = blockIdx.y, t = threadIdx.x;
  __shared__ __align__(16) float As[4096];
  __shared__ __align__(16) float Vs[4096];
  __shared__ __align__(16) float Ys[4096];
  __shared__ float rs[64];
  __shared__ float sm[2];
  const float4* A4 = reinterpret_cast<const float4*>(A + (size_t)b * 4096);
#pragma unroll
  for (int k = 0; k < 4; k++) reinterpret_cast<float4*>(As)[t + k * 256] = A4[t + k * 256];
  if (t < 64) rs[t] = RVv[b * 64 + t];
  if (t == 0) { sm[0] = STAT[b * 2]; sm[1] = STAT[b * 2 + 1]; }
  bool doG = (blk < nchG);
  if (Yext != nullptr && doG) {
    size_t yb = (size_t)b * 32768 + (size_t)blk * 1024;
#pragma unroll
    for (int k = 0; k < 4; k++)
      reinterpret_cast<float4*>(Ys)[t + k * 256] = reinterpret_cast<const float4*>(Yext)[yb + t + k * 256];
  }
  __syncthreads();
  float mu = sm[0], is = sm[1];
  int rl = t >> 2, qb = (t & 3) * 16;
  int row = blk * 64 + rl;
  float* vr = V + (size_t)b * 131072 + (size_t)row * 64;
  float4 acc[4];
#pragma unroll
  for (int u = 0; u < 4; u++) {
    acc[u].x = rs[qb + u * 4 + 0]; acc[u].y = rs[qb + u * 4 + 1];
    acc[u].z = rs[qb + u * 4 + 2]; acc[u].w = rs[qb + u * 4 + 3];
  }
  for (int c = 0; c < 64; c++) {
    float vv = vr[c];
    const float4* ar = reinterpret_cast<const float4*>(&As[c * 64 + qb]);
#pragma unroll
    for (int u = 0; u < 4; u++) {
      float4 av = ar[u];
      acc[u].x += vv * av.x; acc[u].y += vv * av.y; acc[u].z += vv * av.z; acc[u].w += vv * av.w;
    }
  }
  const float4* g4 = reinterpret_cast<const float4*>(g + (size_t)row * 64 + qb);
  const float4* b4 = reinterpret_cast<const float4*>(bb + (size_t)row * 64 + qb);
  const float4* vq = reinterpret_cast<const float4*>(vr + qb);
  float4* vo = reinterpret_cast<float4*>(vr + qb);
#pragma unroll
  for (int u = 0; u < 4; u++) {
    float4 gg = g4[u], bv = b4[u], av = vq[u];
    float4 r;
    r.x = (acc[u].x - mu) * is * gg.x + bv.x + av.x;
    r.y = (acc[u].y - mu) * is * gg.y + bv.y + av.y;
    r.z = (acc[u].z - mu) * is * gg.z + bv.z + av.z;
    r.w = (acc[u].w - mu) * is * gg.w + bv.w + av.w;
    vo[u] = r;
    *reinterpret_cast<float4*>(&Vs[rl * 64 + qb + u * 4]) = r;
  }
  __syncthreads();
  if (!doG) return;
  const float* Yp = (Yext != nullptr) ? Ys : Vs;
  int tp = t >> 4, tq = t & 15;
  float a2[4][4] = {};
  for (int k = 0; k < 64; k++) {
    float4 xv = *reinterpret_cast<const float4*>(&Vs[k * 64 + tp * 4]);
    float4 yv = *reinterpret_cast<const float4*>(&Yp[k * 64 + tq * 4]);
    a2[0][0] += xv.x * yv.x; a2[0][1] += xv.x * yv.y; a2[0][2] += xv.x * yv.z; a2[0][3] += xv.x * yv.w;
    a2[1][0] += xv.y * yv.x; a2[1][1] += xv.y * yv.y; a2[1][2] += xv.y * yv.z; a2[1][3] += xv.y * yv.w;
    a2[2][0] += xv.z * yv.x; a2[2][1] += xv.z * yv.y; a2[2][2] += xv.z * yv.z; a2[2][3] += xv.z * yv.w;
    a2[3][0] += xv.w * yv.x; a2[3][1] += xv.w * yv.y; a2[3][2] += xv.w * yv.z; a2[3][3] += xv.w * yv.w;
  }
  float* go = Gp + (size_t)(b * nchG + blk) * 4096;
#pragma unroll
  for (int i = 0; i < 4; i++) {
    float4 w = {a2[i][0], a2[i][1], a2[i][2], a2[i][3]};
    *reinterpret_cast<float4*>(&go[(tp * 4 + i) * 64 + tq * 4]) = w;
  }
  if (t < 64) {
    float s = 0.f;
    for (int k = 0; k < 64; k++) s += Yp[k * 64 + t];
    sp[(size_t)(b * nchG + blk) * 64 + t] = s;
  }
}

// ---- k_y: ZT[b*64+q][z*1024+m] = bf16(V A); LDS-staged coalesced uint4 stores ----
__global__ __launch_bounds__(256) void k_y(const float* __restrict__ V, const float* __restrict__ A,
                                           ushort* __restrict__ ZT) {
  int blk = blockIdx.x, b = blockIdx.y, z = blockIdx.z, t = threadIdx.x;
  __shared__ __align__(16) float As[4096];
  __shared__ ushort Zs[64][36];
  const float4* A4 = reinterpret_cast<const float4*>(A + (size_t)b * 4096);
#pragma unroll
  for (int k = 0; k < 4; k++) reinterpret_cast<float4*>(As)[t + k * 256] = A4[t + k * 256];
  __syncthreads();
  int ml = t >> 3, qb = (t & 7) * 8;
  int m = blk * 32 + ml;
  const float* vr = V + (size_t)b * 131072 + (size_t)(z * 1024 + m) * 64;
  float4 acc[2] = {};
  for (int c = 0; c < 64; c++) {
    float vv = vr[c];
    const float4* ar = reinterpret_cast<const float4*>(&As[c * 64 + qb]);
#pragma unroll
    for (int u = 0; u < 2; u++) {
      float4 av = ar[u];
      acc[u].x += vv * av.x; acc[u].y += vv * av.y; acc[u].z += vv * av.z; acc[u].w += vv * av.w;
    }
  }
  Zs[qb + 0][ml] = f2bf(acc[0].x); Zs[qb + 1][ml] = f2bf(acc[0].y);
  Zs[qb + 2][ml] = f2bf(acc[0].z); Zs[qb + 3][ml] = f2bf(acc[0].w);
  Zs[qb + 4][ml] = f2bf(acc[1].x); Zs[qb + 5][ml] = f2bf(acc[1].y);
  Zs[qb + 6][ml] = f2bf(acc[1].z); Zs[qb + 7][ml] = f2bf(acc[1].w);
  __syncthreads();
  int rowq = t >> 2, seg = t & 3;
  const ushort* srcp = &Zs[rowq][seg * 8];
  uint p0 = (uint)srcp[0] | ((uint)srcp[1] << 16);
  uint p1 = (uint)srcp[2] | ((uint)srcp[3] << 16);
  uint p2 = (uint)srcp[4] | ((uint)srcp[5] << 16);
  uint p3 = (uint)srcp[6] | ((uint)srcp[7] << 16);
  ushort* dp = ZT + (size_t)(b * 64 + rowq) * 2048 + (size_t)z * 1024 + blk * 32 + seg * 8;
  *reinterpret_cast<uint4*>(dp) = make_uint4(p0, p1, p2, p3);
}

// ---- MFMA final GEMM, full-K, fused epilogue: out = CFINAL*(W Z + w1 (x) RV) ----
__global__ __launch_bounds__(256) void k_final_mfma2(const ushort* __restrict__ WTW,
                                                     const ushort* __restrict__ WTF,
                                                     const ushort* __restrict__ ZT,
                                                     const float* __restrict__ RV,
                                                     float* __restrict__ out) {
  int tn = blockIdx.x, tb = blockIdx.y, t = threadIdx.x;
  int lane = t & 63, w = t >> 6;
  int wn = w & 1, wb = w >> 1;
  int r = lane & 15, g = lane >> 4;
  int nrow = tn * 32 + wn * 16 + r;
  int bi0 = tb * 64 + wb * 32 + r;
  bf16x8 ones;
#pragma unroll
  for (int i = 0; i < 8; i++) ones[i] = (__bf16)1.0f;
  f32x4 a0 = {0.f, 0.f, 0.f, 0.f}, a1 = a0, aw = a0;
  for (int kz = 0; kz < 4; kz++) {
    const ushort* wbase = (kz < 2) ? WTW : WTF;
    const ushort* wp = wbase + (size_t)nrow * 1024 + (kz & 1) * 512 + g * 8;
    const ushort* zp0 = ZT + (size_t)bi0 * 2048 + kz * 512 + g * 8;
    const ushort* zp1 = zp0 + 16 * 2048;
#pragma unroll 4
    for (int ks = 0; ks < 512; ks += 32) {
      bf16x8 fa  = *reinterpret_cast<const bf16x8*>(wp + ks);
      bf16x8 fb0 = *reinterpret_cast<const bf16x8*>(zp0 + ks);
      bf16x8 fb1 = *reinterpret_cast<const bf16x8*>(zp1 + ks);
      a0 = __builtin_amdgcn_mfma_f32_16x16x32_bf16(fa, fb0, a0, 0, 0, 0);
      a1 = __builtin_amdgcn_mfma_f32_16x16x32_bf16(fa, fb1, a1, 0, 0, 0);
      aw = __builtin_amdgcn_mfma_f32_16x16x32_bf16(fa, ones, aw, 0, 0, 0);
    }
  }
  int nbase = tn * 32 + wn * 16 + g * 4;
  int i0 = wb * 32 + r;
  float rv0 = RV[tb * 64 + i0];
  float rv1 = RV[tb * 64 + i0 + 16];
  float* op = out + (size_t)tb * 65536;
#pragma unroll
  for (int rr = 0; rr < 4; rr++) {
    float w1v = aw[rr];
    op[(size_t)(nbase + rr) * 64 + i0]      = CFINAL * (a0[rr] + w1v * rv0);
    op[(size_t)(nbase + rr) * 64 + i0 + 16] = CFINAL * (a1[rr] + w1v * rv1);
  }
}

extern "C" void kernel_launch(void* const* d_in, const int* in_sizes, int n_in,
                              void* d_out, int out_size, void* d_ws, size_t ws_size,
                              hipStream_t stream) {
  (void)in_sizes; (void)n_in; (void)out_size;
  const float* xy  = (const float*)d_in[1];
  const float* kW1 = (const float*)d_in[3];
  const float* kb1 = (const float*)d_in[4];
  const float* kW2 = (const float*)d_in[5];
  const float* kb2 = (const float*)d_in[6];
  const float* kW3 = (const float*)d_in[7];
  const float* kb3 = (const float*)d_in[8];
  const float* fW1 = (const float*)d_in[9];
  const float* fb1 = (const float*)d_in[10];
  const float* fW2 = (const float*)d_in[11];
  const float* fb2 = (const float*)d_in[12];
  const float* fW3 = (const float*)d_in[13];
  const float* fb3 = (const float*)d_in[14];
  const float* Wq  = (const float*)d_in[15];
  const float* bq  = (const float*)d_in[16];
  const float* Wk  = (const float*)d_in[17];
  const float* bk  = (const float*)d_in[18];
  const float* lng = (const float*)d_in[19];
  const float* lnb = (const float*)d_in[20];
  float* ws = (float*)d_ws;
  float* out = (float*)d_out;
  if (ws_size < WS_FLOATS * sizeof(float)) return;  // visible failure, no OOB

  float* V   = ws + OFF_V;
  float* U1K = ws + OFF_U1K;
  float* U2K = ws + OFF_U2K;
  float* U1F = ws + OFF_U1F;
  float* U2F = ws + OFF_U2F;
  float* GPb = ws + OFF_GP;
  float* SPb = ws + OFF_SP;
  float* LNP = ws + OFF_LNP;
  // overlays
  float* G    = ws + OFF_U1K;             // 32768 (U tables dead after k_mlp2apply)
  float* SV   = ws + OFF_U1F;             // 512
  float* A    = ws + OFF_A;
  float* RV   = ws + OFF_RV;
  float* STAT = ws + OFF_LNP;
  ushort* Wbf  = (ushort*)(ws + OFF_W);
  ushort* WTW  = (ushort*)(ws + OFF_W + 524288);
  ushort* Wfbf = (ushort*)(ws + OFF_WF);
  ushort* WTF  = (ushort*)(ws + OFF_WF + 524288);
  ushort* ZT   = (ushort*)(ws + OFF_MID);
  float* Ep   = ws + OFF_ZU;
  float* Fp   = ws + OFF_ZU + 49152;
  float* Gpp  = ws + OFF_ZU + 49920;
  float* Cp   = ws + OFF_ZU + 50688;
  float* LIN  = ws + OFF_ZU + LIN_OFF;    // LINK[32], LINF[32], CSTK, CSTF

  k_prep<<<dim3(272), dim3(256), 0, stream>>>(kW1, kb1, fW1, fb1, U1K, U2K, U1F, U2F,
                                              kW2, kW3, kb2, fW2, fW3, fb2, LIN,
                                              Wq, bq, Wk, bk, Ep, Fp, Gpp, Cp,
                                              xy, LNP);
  k_mlp2apply<<<dim3(1280), dim3(256), 0, stream>>>(U1K, U2K, kW2, kb2, kW3, kb3,
                                                    U1F, U2F, fW2, fb2, fW3, fb3, LIN, Wbf, Wfbf,
                                                    xy, lng, lnb, LNP, V, GPb, SPb);
  k_cvtgred<<<dim3(640), dim3(256), 0, stream>>>(Wbf, Wfbf, WTW, WTF, GPb, SPb, G, SV);

  for (int j = 0; j < 2; j++) {
    k_headsA2<<<dim3(8), dim3(256), 0, stream>>>(G, SV, Ep, Fp, Gpp, Cp, j, DXDYf * SCALEf, 1,
                                                 A, RV, STAT);
    k_midapply<<<dim3(32, 8), dim3(256), 0, stream>>>(
        V, A, RV, STAT, lng + (size_t)(j + 1) * 131072, lnb + (size_t)(j + 1) * 131072,
        (j == 1) ? xy : nullptr, GPb, SPb, (j == 1) ? 16 : 32);
    k_gred<<<dim3(16, 8), dim3(256), 0, stream>>>(GPb, SPb, G, SV, (j == 1) ? 16 : 32);
  }
  k_headsA2<<<dim3(8), dim3(256), 0, stream>>>(G, SV, Ep, Fp, Gpp, Cp, 2, 1.0f, 0, A, RV, STAT);
  k_y<<<dim3(32, 8, 2), dim3(256), 0, stream>>>(V, A, ZT);
  k_final_mfma2<<<dim3(32, 8), dim3(256), 0, stream>>>(WTW, WTF, ZT, RV, out);
}